// Round 1
// baseline (892.274 us; speedup 1.0000x reference)
//
#include <hip/hip_runtime.h>
#include <hip/hip_bf16.h>
#include <math.h>

#define NNODES 50000
#define NPAD   50176              // 392*128, padded rows for MFMA tile overrun
#define NEDGES 800000
#define NHOPS  4
#define NF     256
#define NH     128
#define NO     64

#define CONVX_BLOCKS 12500        // NNODES*NF/4/256
#define CONVW_BLOCKS 512          // NHOPS*NH*NF/256
#define HIST_BLOCKS  12500        // (NEDGES/256)*NHOPS
#define LIN_PER_HOP  391          // ceil(NNODES/128)
#define LIN_BLOCKS   (LIN_PER_HOP * NHOPS)     // 1564

typedef __attribute__((ext_vector_type(8))) short bfrag_t;   // 8 x bf16
typedef __attribute__((ext_vector_type(4))) float facc_t;    // 4 x f32

static __device__ __forceinline__ unsigned short f2bf(float f) {
  unsigned int u = __float_as_uint(f);
  unsigned int r = (u + 0x7fffu + ((u >> 16) & 1u)) >> 16;
  return (unsigned short)r;
}
static __device__ __forceinline__ float bf2f_lo(unsigned int u) {
  return __uint_as_float(u << 16);
}
static __device__ __forceinline__ float bf2f_hi(unsigned int u) {
  return __uint_as_float(u & 0xffff0000u);
}

// ---------------------------------------------------------------------------
// Phase A (fused): convx | convw | hist. All independent.
// hist atomics are fire-and-forget (result unused -> no-return form).
// ---------------------------------------------------------------------------
__global__ __launch_bounds__(256) void phaseA_kernel(
    const float* __restrict__ x, unsigned short* __restrict__ xb,
    const float* __restrict__ W, unsigned short* __restrict__ Wt,
    const int* __restrict__ erows, int* __restrict__ counts) {
  const int bx = blockIdx.x;
  const int t  = threadIdx.x;
  if (bx < CONVX_BLOCKS) {
    const size_t i = ((size_t)bx * 256 + t) * 4;
    float4 v = *(const float4*)&x[i];
    ushort4 o;
    o.x = f2bf(v.x); o.y = f2bf(v.y); o.z = f2bf(v.z); o.w = f2bf(v.w);
    *(ushort4*)&xb[i] = o;
  } else if (bx < CONVX_BLOCKS + CONVW_BLOCKS) {
    const int i = (bx - CONVX_BLOCKS) * 256 + t;
    const int k = i / (NH * NF);
    const int rem = i - k * NH * NF;
    const int n = rem / NF;
    const int f = rem - n * NF;
    Wt[i] = f2bf(W[(size_t)k * NF * NH + (size_t)f * NH + n]);
  } else {
    const int id  = bx - (CONVX_BLOCKS + CONVW_BLOCKS);
    const int hop = id / 3125;
    const int e   = (id - hop * 3125) * 256 + t;
    const int r = erows[(size_t)hop * NEDGES + e];
    atomicAdd(&counts[hop * NNODES + r], 1);
  }
}

// ---------------------------------------------------------------------------
// CSR build step 2: exclusive scan per hop. 8 items/thread -> 7 chunk iters.
// ---------------------------------------------------------------------------
__global__ __launch_bounds__(1024) void scan_kernel(
    const int* __restrict__ counts, int* __restrict__ offs,
    int* __restrict__ cursor) {
  const int hop  = blockIdx.x;
  const int t    = threadIdx.x;
  const int lane = t & 63;
  const int wid  = t >> 6;
  __shared__ int wsum[16];
  __shared__ int carry_s;
  if (t == 0) carry_s = 0;
  __syncthreads();
  const int CH  = 8192;
  const int nch = (NNODES + CH - 1) / CH;     // 7
  for (int ch = 0; ch < nch; ++ch) {
    const int i0 = ch * CH + t * 8;
    int v[8];
    if (i0 + 7 < NNODES) {
      int4 a = *(const int4*)&counts[hop * NNODES + i0];
      int4 b = *(const int4*)&counts[hop * NNODES + i0 + 4];
      v[0]=a.x; v[1]=a.y; v[2]=a.z; v[3]=a.w;
      v[4]=b.x; v[5]=b.y; v[6]=b.z; v[7]=b.w;
    } else {
#pragma unroll
      for (int j = 0; j < 8; ++j)
        v[j] = (i0 + j < NNODES) ? counts[hop * NNODES + i0 + j] : 0;
    }
    int l[8];
    int run = 0;
#pragma unroll
    for (int j = 0; j < 8; ++j) { run += v[j]; l[j] = run; }   // inclusive
    int s = run;
#pragma unroll
    for (int d = 1; d < 64; d <<= 1) {
      int n = __shfl_up(s, d, 64);
      if (lane >= d) s += n;
    }
    if (lane == 63) wsum[wid] = s;
    __syncthreads();
    if (t < 16) {
      int ws = wsum[t];
#pragma unroll
      for (int d = 1; d < 16; d <<= 1) {
        int n = __shfl_up(ws, d, 16);
        if (t >= d) ws += n;
      }
      wsum[t] = ws;
    }
    __syncthreads();
    const int base = carry_s + (wid ? wsum[wid - 1] : 0) + (s - run);
    if (i0 + 7 < NNODES) {
      int4 o0 = make_int4(base, base + l[0], base + l[1], base + l[2]);
      int4 o1 = make_int4(base + l[3], base + l[4], base + l[5], base + l[6]);
      *(int4*)&offs[hop * (NNODES + 1) + i0]     = o0;
      *(int4*)&offs[hop * (NNODES + 1) + i0 + 4] = o1;
      *(int4*)&cursor[hop * NNODES + i0]     = o0;
      *(int4*)&cursor[hop * NNODES + i0 + 4] = o1;
    } else {
#pragma unroll
      for (int j = 0; j < 8; ++j) {
        if (i0 + j < NNODES) {
          const int excl = base + (l[j] - v[j]);
          offs[hop * (NNODES + 1) + i0 + j] = excl;
          cursor[hop * NNODES + i0 + j]     = excl;
        }
      }
    }
    __syncthreads();
    if (t == 0) carry_s += wsum[15];
    __syncthreads();
  }
  if (t == 0) offs[hop * (NNODES + 1) + NNODES] = carry_s;
}

// ---------------------------------------------------------------------------
// Linear via MFMA, all 4 hops in one dispatch (1564 blocks).
// Block = 256 thr = 4 waves (2x2), each wave 64x64 via 4x4 16x16x32 tiles.
// (R6 lesson: do NOT interleave with scatter — heterogeneous block mix
//  halves resident scatter waves and regresses 2x.)
// ---------------------------------------------------------------------------
__global__ __launch_bounds__(256) void linear_kernel(
    const unsigned short* __restrict__ xb, const unsigned short* __restrict__ Wt,
    const float* __restrict__ b, unsigned short* __restrict__ slots) {
  const int lb  = blockIdx.x;
  const int hop = lb / LIN_PER_HOP;
  const int mb  = lb - hop * LIN_PER_HOP;
  const unsigned short* Wk = Wt + (size_t)hop * NH * NF;
  const float* bk = b + hop * NH;
  unsigned short* hb = slots + (size_t)(hop + 1) * NNODES * NH;

  const int t    = threadIdx.x;
  const int lane = t & 63;
  const int wave = t >> 6;
  const int wm   = (wave >> 1) * 64;
  const int wn   = (wave & 1) * 64;
  const int m0   = mb * 128;
  const int l15  = lane & 15;
  const int quad = lane >> 4;

  facc_t acc[4][4];
#pragma unroll
  for (int i = 0; i < 4; ++i)
#pragma unroll
    for (int j = 0; j < 4; ++j) {
      facc_t z = {0.f, 0.f, 0.f, 0.f};
      acc[i][j] = z;
    }

#pragma unroll
  for (int k0 = 0; k0 < NF; k0 += 32) {
    bfrag_t a[4], bb[4];
#pragma unroll
    for (int mi = 0; mi < 4; ++mi) {
      const int m = m0 + wm + mi * 16 + l15;
      a[mi] = *(const bfrag_t*)&xb[(size_t)m * NF + k0 + quad * 8];
    }
#pragma unroll
    for (int ni = 0; ni < 4; ++ni) {
      const int n = wn + ni * 16 + l15;
      bb[ni] = *(const bfrag_t*)&Wk[(size_t)n * NF + k0 + quad * 8];
    }
#pragma unroll
    for (int mi = 0; mi < 4; ++mi)
#pragma unroll
      for (int ni = 0; ni < 4; ++ni)
        acc[mi][ni] = __builtin_amdgcn_mfma_f32_16x16x32_bf16(
            a[mi], bb[ni], acc[mi][ni], 0, 0, 0);
  }

#pragma unroll
  for (int ni = 0; ni < 4; ++ni) {
    const int n = wn + ni * 16 + l15;
    const float bias = bk[n];
#pragma unroll
    for (int mi = 0; mi < 4; ++mi) {
#pragma unroll
      for (int r = 0; r < 4; ++r) {
        const int m = m0 + wm + mi * 16 + quad * 4 + r;
        if (m < NNODES) hb[(size_t)m * NH + n] = f2bf(acc[mi][ni][r] + bias);
      }
    }
  }
}

// ---------------------------------------------------------------------------
// CSR scatter: 4 edges per thread (int4/float4 loads) -> 4 independent
// atomic->store chains in flight per thread (4x MLP vs R4's 1/thread).
// Nontemporal 8B stores (no L2 line churn). grid = (782, NHOPS).
// ---------------------------------------------------------------------------
__global__ __launch_bounds__(256) void scatter_kernel(
    const int* __restrict__ erows, const int* __restrict__ ecols,
    const float* __restrict__ evals, int* __restrict__ cursor,
    unsigned long long* __restrict__ ecsr) {
  const int hop  = blockIdx.y;
  const int base = (blockIdx.x * 256 + threadIdx.x) * 4;
  if (base >= NEDGES) return;
  const size_t g0 = (size_t)hop * NEDGES + base;
  int* cur = cursor + hop * NNODES;
  unsigned long long* dst = ecsr + (size_t)hop * NEDGES;

  if (base + 3 < NEDGES) {
    const int4   rr = *(const int4*)&erows[g0];
    const int4   cc = *(const int4*)&ecols[g0];
    const float4 vv = *(const float4*)&evals[g0];
    const int r[4] = {rr.x, rr.y, rr.z, rr.w};
    const int c[4] = {cc.x, cc.y, cc.z, cc.w};
    const float v[4] = {vv.x, vv.y, vv.z, vv.w};
    int pos[4];
#pragma unroll
    for (int j = 0; j < 4; ++j) pos[j] = atomicAdd(&cur[r[j]], 1);
#pragma unroll
    for (int j = 0; j < 4; ++j) {
      const unsigned long long pk =
          ((unsigned long long)__float_as_uint(v[j]) << 32) | (unsigned int)c[j];
      __builtin_nontemporal_store(pk, &dst[pos[j]]);
    }
  } else {
    for (int j = 0; j < 4 && base + j < NEDGES; ++j) {
      const int r = erows[g0 + j];
      const int pos = atomicAdd(&cur[r], 1);
      const unsigned long long pk =
          ((unsigned long long)__float_as_uint(evals[g0 + j]) << 32) |
          (unsigned int)ecols[g0 + j];
      __builtin_nontemporal_store(pk, &dst[pos]);
    }
  }
}

// ---------------------------------------------------------------------------
// Gather SpMM (ONE HOP per dispatch — sequential dispatches enforce the
// hb[k]/agg[k] slot-aliasing dependency; fusing hops raced in R5).
// 1 wave/row; wave = 4 edge-groups x 16 lanes x 16B; 16 edges in flight.
// ---------------------------------------------------------------------------
__global__ __launch_bounds__(256) void gather_kernel(
    const int* __restrict__ offs, const int2* __restrict__ ecsr,
    const unsigned short* __restrict__ hb, unsigned short* __restrict__ aggb) {
  const int t    = threadIdx.x;
  const int lane = t & 63;
  const int wid  = t >> 6;
  const int r = blockIdx.x * 4 + wid;
  const int g  = lane >> 4;    // edge subgroup 0..3
  const int sl = lane & 15;    // feature slice: feats sl*8 .. sl*8+7
  const int s = offs[r];
  const int e = offs[r + 1];

  float acc[8];
#pragma unroll
  for (int j = 0; j < 8; ++j) acc[j] = 0.f;

  for (int p = s; p < e; p += 16) {
    int2 ed[4];
#pragma unroll
    for (int q = 0; q < 4; ++q) {
      const int idx = p + q * 4 + g;
      ed[q] = (idx < e) ? ecsr[idx] : make_int2(0, 0);
    }
    uint4 hv[4];
#pragma unroll
    for (int q = 0; q < 4; ++q)
      hv[q] = *(const uint4*)&hb[(size_t)ed[q].x * NH + sl * 8];
#pragma unroll
    for (int q = 0; q < 4; ++q) {
      const float v = __int_as_float(ed[q].y);
      acc[0] += v * bf2f_lo(hv[q].x);
      acc[1] += v * bf2f_hi(hv[q].x);
      acc[2] += v * bf2f_lo(hv[q].y);
      acc[3] += v * bf2f_hi(hv[q].y);
      acc[4] += v * bf2f_lo(hv[q].z);
      acc[5] += v * bf2f_hi(hv[q].z);
      acc[6] += v * bf2f_lo(hv[q].w);
      acc[7] += v * bf2f_hi(hv[q].w);
    }
  }

#pragma unroll
  for (int j = 0; j < 8; ++j) {
    acc[j] += __shfl_xor(acc[j], 16, 64);
    acc[j] += __shfl_xor(acc[j], 32, 64);
  }

  if (g == 0) {
    uint4 o;
    o.x = (unsigned)f2bf(acc[0]) | ((unsigned)f2bf(acc[1]) << 16);
    o.y = (unsigned)f2bf(acc[2]) | ((unsigned)f2bf(acc[3]) << 16);
    o.z = (unsigned)f2bf(acc[4]) | ((unsigned)f2bf(acc[5]) << 16);
    o.w = (unsigned)f2bf(acc[6]) | ((unsigned)f2bf(acc[7]) << 16);
    *(uint4*)&aggb[(size_t)r * NH + sl * 8] = o;
  }
}

// ---------------------------------------------------------------------------
// Output: out[n][o] = b_out[o] + sum_f elu(concat[n][f]) * W_out[f][o]
// ---------------------------------------------------------------------------
__global__ __launch_bounds__(64) void out_kernel(
    const unsigned short* __restrict__ aggb, const float* __restrict__ Wout,
    const float* __restrict__ bout, float* __restrict__ out) {
  __shared__ float zs[16 * 516];
  const int t  = threadIdx.x;
  const int n0 = blockIdx.x * 16;

#pragma unroll
  for (int cch = 0; cch < 32; ++cch) {
    const int flat = cch * 256 + t * 4;
    const int n_l  = flat >> 9;
    const int f    = flat & 511;
    const int k    = f >> 7;
    const int j    = f & 127;
    const uint2 u = *(const uint2*)&aggb[((size_t)k * NNODES + n0 + n_l) * NH + j];
    float4 v = make_float4(bf2f_lo(u.x), bf2f_hi(u.x), bf2f_lo(u.y), bf2f_hi(u.y));
    v.x = v.x > 0.f ? v.x : (expf(v.x) - 1.f);
    v.y = v.y > 0.f ? v.y : (expf(v.y) - 1.f);
    v.z = v.z > 0.f ? v.z : (expf(v.z) - 1.f);
    v.w = v.w > 0.f ? v.w : (expf(v.w) - 1.f);
    *(float4*)&zs[n_l * 516 + f] = v;
  }
  __syncthreads();

  const int og = t & 15;
  const int ng = t >> 4;
  float acc[4][4];
#pragma unroll
  for (int i = 0; i < 4; ++i)
#pragma unroll
    for (int o = 0; o < 4; ++o) acc[i][o] = 0.f;

  for (int fq = 0; fq < 128; ++fq) {
    const int f = fq * 4;
    float4 z[4], w[4];
#pragma unroll
    for (int i = 0; i < 4; ++i)
      z[i] = *(float4*)&zs[(ng * 4 + i) * 516 + f];
#pragma unroll
    for (int u = 0; u < 4; ++u)
      w[u] = *(const float4*)&Wout[(size_t)(f + u) * NO + og * 4];
    float zv[4][4] = {{z[0].x, z[0].y, z[0].z, z[0].w},
                      {z[1].x, z[1].y, z[1].z, z[1].w},
                      {z[2].x, z[2].y, z[2].z, z[2].w},
                      {z[3].x, z[3].y, z[3].z, z[3].w}};
    float wv[4][4] = {{w[0].x, w[0].y, w[0].z, w[0].w},
                      {w[1].x, w[1].y, w[1].z, w[1].w},
                      {w[2].x, w[2].y, w[2].z, w[2].w},
                      {w[3].x, w[3].y, w[3].z, w[3].w}};
#pragma unroll
    for (int i = 0; i < 4; ++i)
#pragma unroll
      for (int u = 0; u < 4; ++u)
#pragma unroll
        for (int o = 0; o < 4; ++o) acc[i][o] += zv[i][u] * wv[u][o];
  }

  float bo[4];
#pragma unroll
  for (int o = 0; o < 4; ++o) bo[o] = bout[og * 4 + o];
#pragma unroll
  for (int i = 0; i < 4; ++i) {
    const int n = n0 + ng * 4 + i;
    float4 r = make_float4(acc[i][0] + bo[0], acc[i][1] + bo[1],
                           acc[i][2] + bo[2], acc[i][3] + bo[3]);
    *(float4*)&out[(size_t)n * NO + og * 4] = r;
  }
}

// ---------------------------------------------------------------------------
extern "C" void kernel_launch(void* const* d_in, const int* in_sizes, int n_in,
                              void* d_out, int out_size, void* d_ws, size_t ws_size,
                              hipStream_t stream) {
  const float* x     = (const float*)d_in[0];
  const float* W     = (const float*)d_in[1];
  const float* b     = (const float*)d_in[2];
  const float* W_out = (const float*)d_in[3];
  const float* b_out = (const float*)d_in[4];
  const int*   erows = (const int*)d_in[5];
  const int*   ecols = (const int*)d_in[6];
  const float* evals = (const float*)d_in[7];
  float* out = (float*)d_out;

  // ws layout (bytes), total ~118e6 (<128e6 known-safe):
  //   slots: 5 x NNODES*NH bf16 = 64.0e6   (agg[k]=slot k, hb[k]=slot k+1;
  //          aliasing is safe ONLY because gathers are sequential dispatches)
  //   xb: NPAD*NF bf16 = 25.7e6 | Wt: 0.26e6 | ecsr: 25.6e6 | ints 2.4e6
  unsigned short* slots = (unsigned short*)d_ws;
  unsigned short* xb = slots + (size_t)(NHOPS + 1) * NNODES * NH;
  unsigned short* Wt = xb + (size_t)NPAD * NF;
  unsigned long long* ecsr = (unsigned long long*)(Wt + (size_t)NHOPS * NH * NF);
  int* counts = (int*)(ecsr + (size_t)NHOPS * NEDGES);
  int* offs   = counts + NHOPS * NNODES;
  int* cursor = offs + NHOPS * (NNODES + 1);

  hipMemsetAsync(counts, 0, (size_t)NHOPS * NNODES * sizeof(int), stream);

  phaseA_kernel<<<CONVX_BLOCKS + CONVW_BLOCKS + HIST_BLOCKS, 256, 0, stream>>>(
      x, xb, W, Wt, erows, counts);
  scan_kernel<<<NHOPS, 1024, 0, stream>>>(counts, offs, cursor);
  linear_kernel<<<LIN_BLOCKS, 256, 0, stream>>>(xb, Wt, b, slots);
  scatter_kernel<<<dim3(782, NHOPS), 256, 0, stream>>>(
      erows, ecols, evals, cursor, ecsr);

  for (int k = 0; k < NHOPS; ++k) {
    gather_kernel<<<NNODES / 4, 256, 0, stream>>>(
        offs + (size_t)k * (NNODES + 1), (const int2*)(ecsr + (size_t)k * NEDGES),
        slots + (size_t)(k + 1) * NNODES * NH,   // hb[k]
        slots + (size_t)k * NNODES * NH);        // agg[k]
  }

  out_kernel<<<NNODES / 16, 64, 0, stream>>>(slots, W_out, b_out, out);
}

// Round 2
// 859.570 us; speedup vs baseline: 1.0380x; 1.0380x over previous
//
#include <hip/hip_runtime.h>
#include <hip/hip_bf16.h>
#include <math.h>

#define NNODES 50000
#define NPAD   50176              // 392*128, padded rows for MFMA tile overrun
#define NEDGES 800000
#define NHOPS  4
#define NF     256
#define NH     128
#define NO     64

#define CONVX_BLOCKS 12500        // NNODES*NF/4/256
#define CONVW_BLOCKS 512          // NHOPS*NH*NF/256
#define HIST_BLOCKS  12500        // (NEDGES/256)*NHOPS
#define LIN_PER_HOP  391          // ceil(NNODES/128)
#define LIN_BLOCKS   (LIN_PER_HOP * NHOPS)     // 1564

typedef __attribute__((ext_vector_type(8))) short bfrag_t;   // 8 x bf16
typedef __attribute__((ext_vector_type(4))) float facc_t;    // 4 x f32

static __device__ __forceinline__ unsigned short f2bf(float f) {
  unsigned int u = __float_as_uint(f);
  unsigned int r = (u + 0x7fffu + ((u >> 16) & 1u)) >> 16;
  return (unsigned short)r;
}
static __device__ __forceinline__ float bf2f_lo(unsigned int u) {
  return __uint_as_float(u << 16);
}
static __device__ __forceinline__ float bf2f_hi(unsigned int u) {
  return __uint_as_float(u & 0xffff0000u);
}

// ---------------------------------------------------------------------------
// Phase A (fused): convx | convw | hist. All independent.
// hist atomics are fire-and-forget (result unused -> no-return form).
// ---------------------------------------------------------------------------
__global__ __launch_bounds__(256) void phaseA_kernel(
    const float* __restrict__ x, unsigned short* __restrict__ xb,
    const float* __restrict__ W, unsigned short* __restrict__ Wt,
    const int* __restrict__ erows, int* __restrict__ counts) {
  const int bx = blockIdx.x;
  const int t  = threadIdx.x;
  if (bx < CONVX_BLOCKS) {
    const size_t i = ((size_t)bx * 256 + t) * 4;
    float4 v = *(const float4*)&x[i];
    ushort4 o;
    o.x = f2bf(v.x); o.y = f2bf(v.y); o.z = f2bf(v.z); o.w = f2bf(v.w);
    *(ushort4*)&xb[i] = o;
  } else if (bx < CONVX_BLOCKS + CONVW_BLOCKS) {
    const int i = (bx - CONVX_BLOCKS) * 256 + t;
    const int k = i / (NH * NF);
    const int rem = i - k * NH * NF;
    const int n = rem / NF;
    const int f = rem - n * NF;
    Wt[i] = f2bf(W[(size_t)k * NF * NH + (size_t)f * NH + n]);
  } else {
    const int id  = bx - (CONVX_BLOCKS + CONVW_BLOCKS);
    const int hop = id / 3125;
    const int e   = (id - hop * 3125) * 256 + t;
    const int r = erows[(size_t)hop * NEDGES + e];
    atomicAdd(&counts[hop * NNODES + r], 1);
  }
}

// ---------------------------------------------------------------------------
// CSR build step 2: exclusive scan per hop. 8 items/thread -> 7 chunk iters.
// ---------------------------------------------------------------------------
__global__ __launch_bounds__(1024) void scan_kernel(
    const int* __restrict__ counts, int* __restrict__ offs,
    int* __restrict__ cursor) {
  const int hop  = blockIdx.x;
  const int t    = threadIdx.x;
  const int lane = t & 63;
  const int wid  = t >> 6;
  __shared__ int wsum[16];
  __shared__ int carry_s;
  if (t == 0) carry_s = 0;
  __syncthreads();
  const int CH  = 8192;
  const int nch = (NNODES + CH - 1) / CH;     // 7
  for (int ch = 0; ch < nch; ++ch) {
    const int i0 = ch * CH + t * 8;
    int v[8];
    if (i0 + 7 < NNODES) {
      int4 a = *(const int4*)&counts[hop * NNODES + i0];
      int4 b = *(const int4*)&counts[hop * NNODES + i0 + 4];
      v[0]=a.x; v[1]=a.y; v[2]=a.z; v[3]=a.w;
      v[4]=b.x; v[5]=b.y; v[6]=b.z; v[7]=b.w;
    } else {
#pragma unroll
      for (int j = 0; j < 8; ++j)
        v[j] = (i0 + j < NNODES) ? counts[hop * NNODES + i0 + j] : 0;
    }
    int l[8];
    int run = 0;
#pragma unroll
    for (int j = 0; j < 8; ++j) { run += v[j]; l[j] = run; }   // inclusive
    int s = run;
#pragma unroll
    for (int d = 1; d < 64; d <<= 1) {
      int n = __shfl_up(s, d, 64);
      if (lane >= d) s += n;
    }
    if (lane == 63) wsum[wid] = s;
    __syncthreads();
    if (t < 16) {
      int ws = wsum[t];
#pragma unroll
      for (int d = 1; d < 16; d <<= 1) {
        int n = __shfl_up(ws, d, 16);
        if (t >= d) ws += n;
      }
      wsum[t] = ws;
    }
    __syncthreads();
    const int base = carry_s + (wid ? wsum[wid - 1] : 0) + (s - run);
    if (i0 + 7 < NNODES) {
      int4 o0 = make_int4(base, base + l[0], base + l[1], base + l[2]);
      int4 o1 = make_int4(base + l[3], base + l[4], base + l[5], base + l[6]);
      *(int4*)&offs[hop * (NNODES + 1) + i0]     = o0;
      *(int4*)&offs[hop * (NNODES + 1) + i0 + 4] = o1;
      *(int4*)&cursor[hop * NNODES + i0]     = o0;
      *(int4*)&cursor[hop * NNODES + i0 + 4] = o1;
    } else {
#pragma unroll
      for (int j = 0; j < 8; ++j) {
        if (i0 + j < NNODES) {
          const int excl = base + (l[j] - v[j]);
          offs[hop * (NNODES + 1) + i0 + j] = excl;
          cursor[hop * NNODES + i0 + j]     = excl;
        }
      }
    }
    __syncthreads();
    if (t == 0) carry_s += wsum[15];
    __syncthreads();
  }
  if (t == 0) offs[hop * (NNODES + 1) + NNODES] = carry_s;
}

// ---------------------------------------------------------------------------
// Linear via MFMA, all 4 hops in one dispatch (1564 blocks).
// Block = 256 thr = 4 waves (2x2), each wave 64x64 via 4x4 16x16x32 tiles.
// (R6 lesson: do NOT interleave with scatter — heterogeneous block mix
//  halves resident scatter waves and regresses 2x.)
// ---------------------------------------------------------------------------
__global__ __launch_bounds__(256) void linear_kernel(
    const unsigned short* __restrict__ xb, const unsigned short* __restrict__ Wt,
    const float* __restrict__ b, unsigned short* __restrict__ slots) {
  const int lb  = blockIdx.x;
  const int hop = lb / LIN_PER_HOP;
  const int mb  = lb - hop * LIN_PER_HOP;
  const unsigned short* Wk = Wt + (size_t)hop * NH * NF;
  const float* bk = b + hop * NH;
  unsigned short* hb = slots + (size_t)(hop + 1) * NNODES * NH;

  const int t    = threadIdx.x;
  const int lane = t & 63;
  const int wave = t >> 6;
  const int wm   = (wave >> 1) * 64;
  const int wn   = (wave & 1) * 64;
  const int m0   = mb * 128;
  const int l15  = lane & 15;
  const int quad = lane >> 4;

  facc_t acc[4][4];
#pragma unroll
  for (int i = 0; i < 4; ++i)
#pragma unroll
    for (int j = 0; j < 4; ++j) {
      facc_t z = {0.f, 0.f, 0.f, 0.f};
      acc[i][j] = z;
    }

#pragma unroll
  for (int k0 = 0; k0 < NF; k0 += 32) {
    bfrag_t a[4], bb[4];
#pragma unroll
    for (int mi = 0; mi < 4; ++mi) {
      const int m = m0 + wm + mi * 16 + l15;
      a[mi] = *(const bfrag_t*)&xb[(size_t)m * NF + k0 + quad * 8];
    }
#pragma unroll
    for (int ni = 0; ni < 4; ++ni) {
      const int n = wn + ni * 16 + l15;
      bb[ni] = *(const bfrag_t*)&Wk[(size_t)n * NF + k0 + quad * 8];
    }
#pragma unroll
    for (int mi = 0; mi < 4; ++mi)
#pragma unroll
      for (int ni = 0; ni < 4; ++ni)
        acc[mi][ni] = __builtin_amdgcn_mfma_f32_16x16x32_bf16(
            a[mi], bb[ni], acc[mi][ni], 0, 0, 0);
  }

#pragma unroll
  for (int ni = 0; ni < 4; ++ni) {
    const int n = wn + ni * 16 + l15;
    const float bias = bk[n];
#pragma unroll
    for (int mi = 0; mi < 4; ++mi) {
#pragma unroll
      for (int r = 0; r < 4; ++r) {
        const int m = m0 + wm + mi * 16 + quad * 4 + r;
        if (m < NNODES) hb[(size_t)m * NH + n] = f2bf(acc[mi][ni][r] + bias);
      }
    }
  }
}

// ---------------------------------------------------------------------------
// CSR scatter: 4 edges per thread (int4/float4 loads) -> 4 independent
// atomic->store chains in flight per thread.
// R1 CHANGE: plain (cached) 8B stores instead of nontemporal. Theory: nt
// bypassed L2+LLC -> 3.2M random 64B masked DRAM writes -> row-thrash
// ceiling ~850 GB/s -> 206MB/850GBps ~= the measured 270us. Through-L2
// write-back lets the 256MB memory-side LLC merge the ~8 partial writes
// per line and absorb the whole 25.6MB ecsr region.
// grid = (782, NHOPS).
// ---------------------------------------------------------------------------
__global__ __launch_bounds__(256) void scatter_kernel(
    const int* __restrict__ erows, const int* __restrict__ ecols,
    const float* __restrict__ evals, int* __restrict__ cursor,
    unsigned long long* __restrict__ ecsr) {
  const int hop  = blockIdx.y;
  const int base = (blockIdx.x * 256 + threadIdx.x) * 4;
  if (base >= NEDGES) return;
  const size_t g0 = (size_t)hop * NEDGES + base;
  int* cur = cursor + hop * NNODES;
  unsigned long long* dst = ecsr + (size_t)hop * NEDGES;

  if (base + 3 < NEDGES) {
    const int4   rr = *(const int4*)&erows[g0];
    const int4   cc = *(const int4*)&ecols[g0];
    const float4 vv = *(const float4*)&evals[g0];
    const int r[4] = {rr.x, rr.y, rr.z, rr.w};
    const int c[4] = {cc.x, cc.y, cc.z, cc.w};
    const float v[4] = {vv.x, vv.y, vv.z, vv.w};
    int pos[4];
#pragma unroll
    for (int j = 0; j < 4; ++j) pos[j] = atomicAdd(&cur[r[j]], 1);
#pragma unroll
    for (int j = 0; j < 4; ++j) {
      const unsigned long long pk =
          ((unsigned long long)__float_as_uint(v[j]) << 32) | (unsigned int)c[j];
      dst[pos[j]] = pk;
    }
  } else {
    for (int j = 0; j < 4 && base + j < NEDGES; ++j) {
      const int r = erows[g0 + j];
      const int pos = atomicAdd(&cur[r], 1);
      const unsigned long long pk =
          ((unsigned long long)__float_as_uint(evals[g0 + j]) << 32) |
          (unsigned int)ecols[g0 + j];
      dst[pos] = pk;
    }
  }
}

// ---------------------------------------------------------------------------
// Gather SpMM (ONE HOP per dispatch — sequential dispatches enforce the
// hb[k]/agg[k] slot-aliasing dependency; fusing hops raced in R5).
// 1 wave/row; wave = 4 edge-groups x 16 lanes x 16B; 16 edges in flight.
// ---------------------------------------------------------------------------
__global__ __launch_bounds__(256) void gather_kernel(
    const int* __restrict__ offs, const int2* __restrict__ ecsr,
    const unsigned short* __restrict__ hb, unsigned short* __restrict__ aggb) {
  const int t    = threadIdx.x;
  const int lane = t & 63;
  const int wid  = t >> 6;
  const int r = blockIdx.x * 4 + wid;
  const int g  = lane >> 4;    // edge subgroup 0..3
  const int sl = lane & 15;    // feature slice: feats sl*8 .. sl*8+7
  const int s = offs[r];
  const int e = offs[r + 1];

  float acc[8];
#pragma unroll
  for (int j = 0; j < 8; ++j) acc[j] = 0.f;

  for (int p = s; p < e; p += 16) {
    int2 ed[4];
#pragma unroll
    for (int q = 0; q < 4; ++q) {
      const int idx = p + q * 4 + g;
      ed[q] = (idx < e) ? ecsr[idx] : make_int2(0, 0);
    }
    uint4 hv[4];
#pragma unroll
    for (int q = 0; q < 4; ++q)
      hv[q] = *(const uint4*)&hb[(size_t)ed[q].x * NH + sl * 8];
#pragma unroll
    for (int q = 0; q < 4; ++q) {
      const float v = __int_as_float(ed[q].y);
      acc[0] += v * bf2f_lo(hv[q].x);
      acc[1] += v * bf2f_hi(hv[q].x);
      acc[2] += v * bf2f_lo(hv[q].y);
      acc[3] += v * bf2f_hi(hv[q].y);
      acc[4] += v * bf2f_lo(hv[q].z);
      acc[5] += v * bf2f_hi(hv[q].z);
      acc[6] += v * bf2f_lo(hv[q].w);
      acc[7] += v * bf2f_hi(hv[q].w);
    }
  }

#pragma unroll
  for (int j = 0; j < 8; ++j) {
    acc[j] += __shfl_xor(acc[j], 16, 64);
    acc[j] += __shfl_xor(acc[j], 32, 64);
  }

  if (g == 0) {
    uint4 o;
    o.x = (unsigned)f2bf(acc[0]) | ((unsigned)f2bf(acc[1]) << 16);
    o.y = (unsigned)f2bf(acc[2]) | ((unsigned)f2bf(acc[3]) << 16);
    o.z = (unsigned)f2bf(acc[4]) | ((unsigned)f2bf(acc[5]) << 16);
    o.w = (unsigned)f2bf(acc[6]) | ((unsigned)f2bf(acc[7]) << 16);
    *(uint4*)&aggb[(size_t)r * NH + sl * 8] = o;
  }
}

// ---------------------------------------------------------------------------
// Output: out[n][o] = b_out[o] + sum_f elu(concat[n][f]) * W_out[f][o]
// ---------------------------------------------------------------------------
__global__ __launch_bounds__(64) void out_kernel(
    const unsigned short* __restrict__ aggb, const float* __restrict__ Wout,
    const float* __restrict__ bout, float* __restrict__ out) {
  __shared__ float zs[16 * 516];
  const int t  = threadIdx.x;
  const int n0 = blockIdx.x * 16;

#pragma unroll
  for (int cch = 0; cch < 32; ++cch) {
    const int flat = cch * 256 + t * 4;
    const int n_l  = flat >> 9;
    const int f    = flat & 511;
    const int k    = f >> 7;
    const int j    = f & 127;
    const uint2 u = *(const uint2*)&aggb[((size_t)k * NNODES + n0 + n_l) * NH + j];
    float4 v = make_float4(bf2f_lo(u.x), bf2f_hi(u.x), bf2f_lo(u.y), bf2f_hi(u.y));
    v.x = v.x > 0.f ? v.x : (expf(v.x) - 1.f);
    v.y = v.y > 0.f ? v.y : (expf(v.y) - 1.f);
    v.z = v.z > 0.f ? v.z : (expf(v.z) - 1.f);
    v.w = v.w > 0.f ? v.w : (expf(v.w) - 1.f);
    *(float4*)&zs[n_l * 516 + f] = v;
  }
  __syncthreads();

  const int og = t & 15;
  const int ng = t >> 4;
  float acc[4][4];
#pragma unroll
  for (int i = 0; i < 4; ++i)
#pragma unroll
    for (int o = 0; o < 4; ++o) acc[i][o] = 0.f;

  for (int fq = 0; fq < 128; ++fq) {
    const int f = fq * 4;
    float4 z[4], w[4];
#pragma unroll
    for (int i = 0; i < 4; ++i)
      z[i] = *(float4*)&zs[(ng * 4 + i) * 516 + f];
#pragma unroll
    for (int u = 0; u < 4; ++u)
      w[u] = *(const float4*)&Wout[(size_t)(f + u) * NO + og * 4];
    float zv[4][4] = {{z[0].x, z[0].y, z[0].z, z[0].w},
                      {z[1].x, z[1].y, z[1].z, z[1].w},
                      {z[2].x, z[2].y, z[2].z, z[2].w},
                      {z[3].x, z[3].y, z[3].z, z[3].w}};
    float wv[4][4] = {{w[0].x, w[0].y, w[0].z, w[0].w},
                      {w[1].x, w[1].y, w[1].z, w[1].w},
                      {w[2].x, w[2].y, w[2].z, w[2].w},
                      {w[3].x, w[3].y, w[3].z, w[3].w}};
#pragma unroll
    for (int i = 0; i < 4; ++i)
#pragma unroll
      for (int u = 0; u < 4; ++u)
#pragma unroll
        for (int o = 0; o < 4; ++o) acc[i][o] += zv[i][u] * wv[u][o];
  }

  float bo[4];
#pragma unroll
  for (int o = 0; o < 4; ++o) bo[o] = bout[og * 4 + o];
#pragma unroll
  for (int i = 0; i < 4; ++i) {
    const int n = n0 + ng * 4 + i;
    float4 r = make_float4(acc[i][0] + bo[0], acc[i][1] + bo[1],
                           acc[i][2] + bo[2], acc[i][3] + bo[3]);
    *(float4*)&out[(size_t)n * NO + og * 4] = r;
  }
}

// ---------------------------------------------------------------------------
extern "C" void kernel_launch(void* const* d_in, const int* in_sizes, int n_in,
                              void* d_out, int out_size, void* d_ws, size_t ws_size,
                              hipStream_t stream) {
  const float* x     = (const float*)d_in[0];
  const float* W     = (const float*)d_in[1];
  const float* b     = (const float*)d_in[2];
  const float* W_out = (const float*)d_in[3];
  const float* b_out = (const float*)d_in[4];
  const int*   erows = (const int*)d_in[5];
  const int*   ecols = (const int*)d_in[6];
  const float* evals = (const float*)d_in[7];
  float* out = (float*)d_out;

  // ws layout (bytes), total ~118e6 (<128e6 known-safe):
  //   slots: 5 x NNODES*NH bf16 = 64.0e6   (agg[k]=slot k, hb[k]=slot k+1;
  //          aliasing is safe ONLY because gathers are sequential dispatches)
  //   xb: NPAD*NF bf16 = 25.7e6 | Wt: 0.26e6 | ecsr: 25.6e6 | ints 2.4e6
  unsigned short* slots = (unsigned short*)d_ws;
  unsigned short* xb = slots + (size_t)(NHOPS + 1) * NNODES * NH;
  unsigned short* Wt = xb + (size_t)NPAD * NF;
  unsigned long long* ecsr = (unsigned long long*)(Wt + (size_t)NHOPS * NH * NF);
  int* counts = (int*)(ecsr + (size_t)NHOPS * NEDGES);
  int* offs   = counts + NHOPS * NNODES;
  int* cursor = offs + NHOPS * (NNODES + 1);

  hipMemsetAsync(counts, 0, (size_t)NHOPS * NNODES * sizeof(int), stream);

  phaseA_kernel<<<CONVX_BLOCKS + CONVW_BLOCKS + HIST_BLOCKS, 256, 0, stream>>>(
      x, xb, W, Wt, erows, counts);
  scan_kernel<<<NHOPS, 1024, 0, stream>>>(counts, offs, cursor);
  linear_kernel<<<LIN_BLOCKS, 256, 0, stream>>>(xb, Wt, b, slots);
  scatter_kernel<<<dim3(782, NHOPS), 256, 0, stream>>>(
      erows, ecols, evals, cursor, ecsr);

  for (int k = 0; k < NHOPS; ++k) {
    gather_kernel<<<NNODES / 4, 256, 0, stream>>>(
        offs + (size_t)k * (NNODES + 1), (const int2*)(ecsr + (size_t)k * NEDGES),
        slots + (size_t)(k + 1) * NNODES * NH,   // hb[k]
        slots + (size_t)k * NNODES * NH);        // agg[k]
  }

  out_kernel<<<NNODES / 16, 64, 0, stream>>>(slots, W_out, b_out, out);
}

// Round 5
// 680.391 us; speedup vs baseline: 1.3114x; 1.2633x over previous
//
#include <hip/hip_runtime.h>
#include <hip/hip_bf16.h>
#include <math.h>

#define NNODES 50000
#define NPAD   50176              // 392*128, padded rows for MFMA tile overrun
#define NEDGES 800000
#define NHOPS  4
#define NF     256
#define NH     128
#define NO     64
#define NB     196                // row buckets of 256 rows (50000/256 -> 196)
#define EPB    4096               // edges per bin block (256 thr x 16)

#define CONVX_BLOCKS 12500        // NNODES*NF/4/256
#define CONVW_BLOCKS 512          // NHOPS*NH*NF/256
#define HIST_BLOCKS  12500        // (NEDGES/256)*NHOPS
#define LIN_PER_HOP  391          // ceil(NNODES/128)
#define LIN_BLOCKS   (LIN_PER_HOP * NHOPS)     // 1564

typedef __attribute__((ext_vector_type(8))) short bfrag_t;   // 8 x bf16
typedef __attribute__((ext_vector_type(4))) float facc_t;    // 4 x f32

static __device__ __forceinline__ unsigned short f2bf(float f) {
  unsigned int u = __float_as_uint(f);
  unsigned int r = (u + 0x7fffu + ((u >> 16) & 1u)) >> 16;
  return (unsigned short)r;
}
static __device__ __forceinline__ float bf2f_lo(unsigned int u) {
  return __uint_as_float(u << 16);
}
static __device__ __forceinline__ float bf2f_hi(unsigned int u) {
  return __uint_as_float(u & 0xffff0000u);
}

// ---------------------------------------------------------------------------
// Phase A (fused): convx | convw | hist. All independent.
// ---------------------------------------------------------------------------
__global__ __launch_bounds__(256) void phaseA_kernel(
    const float* __restrict__ x, unsigned short* __restrict__ xb,
    const float* __restrict__ W, unsigned short* __restrict__ Wt,
    const int* __restrict__ erows, int* __restrict__ counts) {
  const int bx = blockIdx.x;
  const int t  = threadIdx.x;
  if (bx < CONVX_BLOCKS) {
    const size_t i = ((size_t)bx * 256 + t) * 4;
    float4 v = *(const float4*)&x[i];
    ushort4 o;
    o.x = f2bf(v.x); o.y = f2bf(v.y); o.z = f2bf(v.z); o.w = f2bf(v.w);
    *(ushort4*)&xb[i] = o;
  } else if (bx < CONVX_BLOCKS + CONVW_BLOCKS) {
    const int i = (bx - CONVX_BLOCKS) * 256 + t;
    const int k = i / (NH * NF);
    const int rem = i - k * NH * NF;
    const int n = rem / NF;
    const int f = rem - n * NF;
    Wt[i] = f2bf(W[(size_t)k * NF * NH + (size_t)f * NH + n]);
  } else {
    const int id  = bx - (CONVX_BLOCKS + CONVW_BLOCKS);
    const int hop = id / 3125;
    const int e   = (id - hop * 3125) * 256 + t;
    const int r = erows[(size_t)hop * NEDGES + e];
    atomicAdd(&counts[hop * NNODES + r], 1);
  }
}

// ---------------------------------------------------------------------------
// CSR build step 2: exclusive scan per hop. Also initializes the 196
// per-bucket staging cursors (bucket b base = offs[b*256]).
// ---------------------------------------------------------------------------
__global__ __launch_bounds__(1024) void scan_kernel(
    const int* __restrict__ counts, int* __restrict__ offs,
    int* __restrict__ bucketCur) {
  const int hop  = blockIdx.x;
  const int t    = threadIdx.x;
  const int lane = t & 63;
  const int wid  = t >> 6;
  __shared__ int wsum[16];
  __shared__ int carry_s;
  if (t == 0) carry_s = 0;
  __syncthreads();
  const int CH  = 8192;
  const int nch = (NNODES + CH - 1) / CH;     // 7
  for (int ch = 0; ch < nch; ++ch) {
    const int i0 = ch * CH + t * 8;
    int v[8];
    if (i0 + 7 < NNODES) {
      int4 a = *(const int4*)&counts[hop * NNODES + i0];
      int4 b = *(const int4*)&counts[hop * NNODES + i0 + 4];
      v[0]=a.x; v[1]=a.y; v[2]=a.z; v[3]=a.w;
      v[4]=b.x; v[5]=b.y; v[6]=b.z; v[7]=b.w;
    } else {
#pragma unroll
      for (int j = 0; j < 8; ++j)
        v[j] = (i0 + j < NNODES) ? counts[hop * NNODES + i0 + j] : 0;
    }
    int l[8];
    int run = 0;
#pragma unroll
    for (int j = 0; j < 8; ++j) { run += v[j]; l[j] = run; }   // inclusive
    int s = run;
#pragma unroll
    for (int d = 1; d < 64; d <<= 1) {
      int n = __shfl_up(s, d, 64);
      if (lane >= d) s += n;
    }
    if (lane == 63) wsum[wid] = s;
    __syncthreads();
    if (t < 16) {
      int ws = wsum[t];
#pragma unroll
      for (int d = 1; d < 16; d <<= 1) {
        int n = __shfl_up(ws, d, 16);
        if (t >= d) ws += n;
      }
      wsum[t] = ws;
    }
    __syncthreads();
    const int base = carry_s + (wid ? wsum[wid - 1] : 0) + (s - run);
    if (i0 + 7 < NNODES) {
      int4 o0 = make_int4(base, base + l[0], base + l[1], base + l[2]);
      int4 o1 = make_int4(base + l[3], base + l[4], base + l[5], base + l[6]);
      *(int4*)&offs[hop * (NNODES + 1) + i0]     = o0;
      *(int4*)&offs[hop * (NNODES + 1) + i0 + 4] = o1;
    } else {
#pragma unroll
      for (int j = 0; j < 8; ++j) {
        if (i0 + j < NNODES) {
          const int excl = base + (l[j] - v[j]);
          offs[hop * (NNODES + 1) + i0 + j] = excl;
        }
      }
    }
    // bucket cursor init: rows at multiples of 256 (i0 % 8 == 0, so only j=0)
    if ((i0 & 255) == 0 && i0 < NNODES)
      bucketCur[hop * NB + (i0 >> 8)] = base;
    __syncthreads();
    if (t == 0) carry_s += wsum[15];
    __syncthreads();
  }
  if (t == 0) offs[hop * (NNODES + 1) + NNODES] = carry_s;
}

// ---------------------------------------------------------------------------
// Linear via MFMA, all 4 hops in one dispatch (1564 blocks).
// ---------------------------------------------------------------------------
__global__ __launch_bounds__(256) void linear_kernel(
    const unsigned short* __restrict__ xb, const unsigned short* __restrict__ Wt,
    const float* __restrict__ b, unsigned short* __restrict__ slots) {
  const int lb  = blockIdx.x;
  const int hop = lb / LIN_PER_HOP;
  const int mb  = lb - hop * LIN_PER_HOP;
  const unsigned short* Wk = Wt + (size_t)hop * NH * NF;
  const float* bk = b + hop * NH;
  unsigned short* hb = slots + (size_t)(hop + 1) * NNODES * NH;

  const int t    = threadIdx.x;
  const int lane = t & 63;
  const int wave = t >> 6;
  const int wm   = (wave >> 1) * 64;
  const int wn   = (wave & 1) * 64;
  const int m0   = mb * 128;
  const int l15  = lane & 15;
  const int quad = lane >> 4;

  facc_t acc[4][4];
#pragma unroll
  for (int i = 0; i < 4; ++i)
#pragma unroll
    for (int j = 0; j < 4; ++j) {
      facc_t z = {0.f, 0.f, 0.f, 0.f};
      acc[i][j] = z;
    }

#pragma unroll
  for (int k0 = 0; k0 < NF; k0 += 32) {
    bfrag_t a[4], bb[4];
#pragma unroll
    for (int mi = 0; mi < 4; ++mi) {
      const int m = m0 + wm + mi * 16 + l15;
      a[mi] = *(const bfrag_t*)&xb[(size_t)m * NF + k0 + quad * 8];
    }
#pragma unroll
    for (int ni = 0; ni < 4; ++ni) {
      const int n = wn + ni * 16 + l15;
      bb[ni] = *(const bfrag_t*)&Wk[(size_t)n * NF + k0 + quad * 8];
    }
#pragma unroll
    for (int mi = 0; mi < 4; ++mi)
#pragma unroll
      for (int ni = 0; ni < 4; ++ni)
        acc[mi][ni] = __builtin_amdgcn_mfma_f32_16x16x32_bf16(
            a[mi], bb[ni], acc[mi][ni], 0, 0, 0);
  }

#pragma unroll
  for (int ni = 0; ni < 4; ++ni) {
    const int n = wn + ni * 16 + l15;
    const float bias = bk[n];
#pragma unroll
    for (int mi = 0; mi < 4; ++mi) {
#pragma unroll
      for (int r = 0; r < 4; ++r) {
        const int m = m0 + wm + mi * 16 + quad * 4 + r;
        if (m < NNODES) hb[(size_t)m * NH + n] = f2bf(acc[mi][ni][r] + bias);
      }
    }
  }
}

// ---------------------------------------------------------------------------
// Bin pass: rank 4096 edges per block into 196 row-buckets via LDS hist;
// ONE global atomicAdd per (block,bucket) reserves space; edges written in
// ~21-entry contiguous runs into bucket-partitioned staging (aliases dead
// xb). pack: val(hi32) | rowlo<<16 | col. grid (196, NHOPS).
// ---------------------------------------------------------------------------
__global__ __launch_bounds__(256) void bin_kernel(
    const int* __restrict__ erows, const int* __restrict__ ecols,
    const float* __restrict__ evals, int* __restrict__ bucketCur,
    unsigned long long* __restrict__ staging) {
  const int hop = blockIdx.y;
  const int t   = threadIdx.x;
  const int bb  = blockIdx.x * EPB;
  __shared__ int lhist[NB];
  __shared__ int gbase[NB];
  for (int i = t; i < NB; i += 256) lhist[i] = 0;
  __syncthreads();

  unsigned long long pk[16];
  int bkt[16], rnk[16];
  const size_t g0 = (size_t)hop * NEDGES;
#pragma unroll
  for (int k = 0; k < 4; ++k) {
    const int e0 = bb + t * 4 + k * 1024;
    if (e0 + 3 < NEDGES) {
      const int4   rr = *(const int4*)&erows[g0 + e0];
      const int4   cc = *(const int4*)&ecols[g0 + e0];
      const float4 vv = *(const float4*)&evals[g0 + e0];
      const int r4[4] = {rr.x, rr.y, rr.z, rr.w};
      const int c4[4] = {cc.x, cc.y, cc.z, cc.w};
      const float v4[4] = {vv.x, vv.y, vv.z, vv.w};
#pragma unroll
      for (int j = 0; j < 4; ++j) {
        const int b = r4[j] >> 8;
        bkt[k * 4 + j] = b;
        rnk[k * 4 + j] = atomicAdd(&lhist[b], 1);
        pk[k * 4 + j] =
            ((unsigned long long)__float_as_uint(v4[j]) << 32) |
            ((unsigned)(r4[j] & 255) << 16) | (unsigned)c4[j];
      }
    } else {
#pragma unroll
      for (int j = 0; j < 4; ++j) {
        const int e = e0 + j;
        if (e < NEDGES) {
          const int r = erows[g0 + e];
          const int b = r >> 8;
          bkt[k * 4 + j] = b;
          rnk[k * 4 + j] = atomicAdd(&lhist[b], 1);
          pk[k * 4 + j] =
              ((unsigned long long)__float_as_uint(evals[g0 + e]) << 32) |
              ((unsigned)(r & 255) << 16) | (unsigned)ecols[g0 + e];
        } else {
          bkt[k * 4 + j] = -1;
        }
      }
    }
  }
  __syncthreads();
  for (int i = t; i < NB; i += 256) {
    const int c = lhist[i];
    gbase[i] = c ? atomicAdd(&bucketCur[hop * NB + i], c) : 0;
  }
  __syncthreads();
  unsigned long long* dst = staging + (size_t)hop * NEDGES;
#pragma unroll
  for (int q = 0; q < 16; ++q)
    if (bkt[q] >= 0) dst[gbase[bkt[q]] + rnk[q]] = pk[q];
}

// ---------------------------------------------------------------------------
// Place pass: one block per (bucket,hop). Sequential read of the bucket's
// staging segment; exact CSR position via LDS row cursors (no global
// atomics). All writes land in this block's own 32KB window.
// R3 FIX: cur[nr] (nr=256 for full buckets) was never initialized — t only
// reaches 255 -> e was garbage -> OOB -> abort. Strided init covers i=256.
// ---------------------------------------------------------------------------
__global__ __launch_bounds__(256) void place_kernel(
    const int* __restrict__ offs, const unsigned long long* __restrict__ staging,
    unsigned long long* __restrict__ ecsr) {
  const int hop = blockIdx.y;
  const int bk  = blockIdx.x;
  const int t   = threadIdx.x;
  const int r0  = bk * 256;
  const int nr  = (NNODES - r0 < 256) ? (NNODES - r0) : 256;
  const int* o = offs + (size_t)hop * (NNODES + 1);
  __shared__ int cur[257];
  for (int i = t; i <= nr; i += 256) cur[i] = o[r0 + i];   // R3 FIX
  __syncthreads();
  const int s = cur[0];
  const int e = cur[nr];          // never touched by atomics (rowlo < nr)
  __syncthreads();                // snapshot s,e before any cursor bumps
  const unsigned long long* src = staging + (size_t)hop * NEDGES;
  unsigned long long* dst       = ecsr + (size_t)hop * NEDGES;
  for (int i = s + t; i < e; i += 256) {
    const unsigned long long v = src[i];
    const unsigned lo = (unsigned)v;
    const int rl = (lo >> 16) & 255;
    const int d = atomicAdd(&cur[rl], 1);
    dst[d] = (v & 0xFFFFFFFF00000000ull) | (unsigned long long)(lo & 0xFFFFu);
  }
}

// ---------------------------------------------------------------------------
// Gather SpMM (ONE HOP per dispatch — sequential dispatches enforce the
// hb[k]/agg[k] slot-aliasing dependency).
// ---------------------------------------------------------------------------
__global__ __launch_bounds__(256) void gather_kernel(
    const int* __restrict__ offs, const int2* __restrict__ ecsr,
    const unsigned short* __restrict__ hb, unsigned short* __restrict__ aggb) {
  const int t    = threadIdx.x;
  const int lane = t & 63;
  const int wid  = t >> 6;
  const int r = blockIdx.x * 4 + wid;
  const int g  = lane >> 4;    // edge subgroup 0..3
  const int sl = lane & 15;    // feature slice: feats sl*8 .. sl*8+7
  const int s = offs[r];
  const int e = offs[r + 1];

  float acc[8];
#pragma unroll
  for (int j = 0; j < 8; ++j) acc[j] = 0.f;

  for (int p = s; p < e; p += 16) {
    int2 ed[4];
#pragma unroll
    for (int q = 0; q < 4; ++q) {
      const int idx = p + q * 4 + g;
      ed[q] = (idx < e) ? ecsr[idx] : make_int2(0, 0);
    }
    uint4 hv[4];
#pragma unroll
    for (int q = 0; q < 4; ++q)
      hv[q] = *(const uint4*)&hb[(size_t)ed[q].x * NH + sl * 8];
#pragma unroll
    for (int q = 0; q < 4; ++q) {
      const float v = __int_as_float(ed[q].y);
      acc[0] += v * bf2f_lo(hv[q].x);
      acc[1] += v * bf2f_hi(hv[q].x);
      acc[2] += v * bf2f_lo(hv[q].y);
      acc[3] += v * bf2f_hi(hv[q].y);
      acc[4] += v * bf2f_lo(hv[q].z);
      acc[5] += v * bf2f_hi(hv[q].z);
      acc[6] += v * bf2f_lo(hv[q].w);
      acc[7] += v * bf2f_hi(hv[q].w);
    }
  }

#pragma unroll
  for (int j = 0; j < 8; ++j) {
    acc[j] += __shfl_xor(acc[j], 16, 64);
    acc[j] += __shfl_xor(acc[j], 32, 64);
  }

  if (g == 0) {
    uint4 o;
    o.x = (unsigned)f2bf(acc[0]) | ((unsigned)f2bf(acc[1]) << 16);
    o.y = (unsigned)f2bf(acc[2]) | ((unsigned)f2bf(acc[3]) << 16);
    o.z = (unsigned)f2bf(acc[4]) | ((unsigned)f2bf(acc[5]) << 16);
    o.w = (unsigned)f2bf(acc[6]) | ((unsigned)f2bf(acc[7]) << 16);
    *(uint4*)&aggb[(size_t)r * NH + sl * 8] = o;
  }
}

// ---------------------------------------------------------------------------
// Output: out[n][o] = b_out[o] + sum_f elu(concat[n][f]) * W_out[f][o]
// ---------------------------------------------------------------------------
__global__ __launch_bounds__(64) void out_kernel(
    const unsigned short* __restrict__ aggb, const float* __restrict__ Wout,
    const float* __restrict__ bout, float* __restrict__ out) {
  __shared__ float zs[16 * 516];
  const int t  = threadIdx.x;
  const int n0 = blockIdx.x * 16;

#pragma unroll
  for (int cch = 0; cch < 32; ++cch) {
    const int flat = cch * 256 + t * 4;
    const int n_l  = flat >> 9;
    const int f    = flat & 511;
    const int k    = f >> 7;
    const int j    = f & 127;
    const uint2 u = *(const uint2*)&aggb[((size_t)k * NNODES + n0 + n_l) * NH + j];
    float4 v = make_float4(bf2f_lo(u.x), bf2f_hi(u.x), bf2f_lo(u.y), bf2f_hi(u.y));
    v.x = v.x > 0.f ? v.x : (expf(v.x) - 1.f);
    v.y = v.y > 0.f ? v.y : (expf(v.y) - 1.f);
    v.z = v.z > 0.f ? v.z : (expf(v.z) - 1.f);
    v.w = v.w > 0.f ? v.w : (expf(v.w) - 1.f);
    *(float4*)&zs[n_l * 516 + f] = v;
  }
  __syncthreads();

  const int og = t & 15;
  const int ng = t >> 4;
  float acc[4][4];
#pragma unroll
  for (int i = 0; i < 4; ++i)
#pragma unroll
    for (int o = 0; o < 4; ++o) acc[i][o] = 0.f;

  for (int fq = 0; fq < 128; ++fq) {
    const int f = fq * 4;
    float4 z[4], w[4];
#pragma unroll
    for (int i = 0; i < 4; ++i)
      z[i] = *(float4*)&zs[(ng * 4 + i) * 516 + f];
#pragma unroll
    for (int u = 0; u < 4; ++u)
      w[u] = *(const float4*)&Wout[(size_t)(f + u) * NO + og * 4];
    float zv[4][4] = {{z[0].x, z[0].y, z[0].z, z[0].w},
                      {z[1].x, z[1].y, z[1].z, z[1].w},
                      {z[2].x, z[2].y, z[2].z, z[2].w},
                      {z[3].x, z[3].y, z[3].z, z[3].w}};
    float wv[4][4] = {{w[0].x, w[0].y, w[0].z, w[0].w},
                      {w[1].x, w[1].y, w[1].z, w[1].w},
                      {w[2].x, w[2].y, w[2].z, w[2].w},
                      {w[3].x, w[3].y, w[3].z, w[3].w}};
#pragma unroll
    for (int i = 0; i < 4; ++i)
#pragma unroll
      for (int u = 0; u < 4; ++u)
#pragma unroll
        for (int o = 0; o < 4; ++o) acc[i][o] += zv[i][u] * wv[u][o];
  }

  float bo[4];
#pragma unroll
  for (int o = 0; o < 4; ++o) bo[o] = bout[og * 4 + o];
#pragma unroll
  for (int i = 0; i < 4; ++i) {
    const int n = n0 + ng * 4 + i;
    float4 r = make_float4(acc[i][0] + bo[0], acc[i][1] + bo[1],
                           acc[i][2] + bo[2], acc[i][3] + bo[3]);
    *(float4*)&out[(size_t)n * NO + og * 4] = r;
  }
}

// ---------------------------------------------------------------------------
extern "C" void kernel_launch(void* const* d_in, const int* in_sizes, int n_in,
                              void* d_out, int out_size, void* d_ws, size_t ws_size,
                              hipStream_t stream) {
  const float* x     = (const float*)d_in[0];
  const float* W     = (const float*)d_in[1];
  const float* b     = (const float*)d_in[2];
  const float* W_out = (const float*)d_in[3];
  const float* b_out = (const float*)d_in[4];
  const int*   erows = (const int*)d_in[5];
  const int*   ecols = (const int*)d_in[6];
  const float* evals = (const float*)d_in[7];
  float* out = (float*)d_out;

  // ws layout (bytes), total ~117e6 (<128e6 known-safe):
  //   slots: 5 x NNODES*NH bf16 = 64.0e6
  //   xb: NPAD*NF bf16 = 25.7e6  (REUSED as 25.6e6 staging after linear)
  //   Wt: 0.26e6 | ecsr: 25.6e6 | ints 1.6e6 (counts/offs/bucketCur)
  unsigned short* slots = (unsigned short*)d_ws;
  unsigned short* xb = slots + (size_t)(NHOPS + 1) * NNODES * NH;
  unsigned short* Wt = xb + (size_t)NPAD * NF;
  unsigned long long* ecsr = (unsigned long long*)(Wt + (size_t)NHOPS * NH * NF);
  int* counts    = (int*)(ecsr + (size_t)NHOPS * NEDGES);
  int* offs      = counts + NHOPS * NNODES;
  int* bucketCur = offs + NHOPS * (NNODES + 1);
  // staging aliases xb: xb is dead once linear_kernel has run.
  unsigned long long* staging = (unsigned long long*)xb;

  hipMemsetAsync(counts, 0, (size_t)NHOPS * NNODES * sizeof(int), stream);

  phaseA_kernel<<<CONVX_BLOCKS + CONVW_BLOCKS + HIST_BLOCKS, 256, 0, stream>>>(
      x, xb, W, Wt, erows, counts);
  scan_kernel<<<NHOPS, 1024, 0, stream>>>(counts, offs, bucketCur);
  linear_kernel<<<LIN_BLOCKS, 256, 0, stream>>>(xb, Wt, b, slots);
  bin_kernel<<<dim3(NB, NHOPS), 256, 0, stream>>>(
      erows, ecols, evals, bucketCur, staging);
  place_kernel<<<dim3(NB, NHOPS), 256, 0, stream>>>(offs, staging, ecsr);

  for (int k = 0; k < NHOPS; ++k) {
    gather_kernel<<<NNODES / 4, 256, 0, stream>>>(
        offs + (size_t)k * (NNODES + 1), (const int2*)(ecsr + (size_t)k * NEDGES),
        slots + (size_t)(k + 1) * NNODES * NH,   // hb[k]
        slots + (size_t)k * NNODES * NH);        // agg[k]
  }

  out_kernel<<<NNODES / 16, 64, 0, stream>>>(slots, W_out, b_out, out);
}

// Round 7
// 571.088 us; speedup vs baseline: 1.5624x; 1.1914x over previous
//
#include <hip/hip_runtime.h>
#include <hip/hip_bf16.h>
#include <math.h>

#define NNODES 50000
#define NPAD   50176              // 392*128, padded rows for MFMA tile overrun
#define NEDGES 800000
#define NHOPS  4
#define NF     256
#define NH     128
#define NO     64
#define NB     196                // row buckets of 256 rows (50000/256 -> 196)
#define EPB    4096               // edges per bin block (256 thr x 16)

#define CONVX_BLOCKS 12500        // NNODES*NF/4/256
#define CONVW_BLOCKS 512          // NHOPS*NH*NF/256
#define HIST_BLOCKS  12500        // (NEDGES/256)*NHOPS
#define WOT_BLOCKS   128          // 64*512/256 (Wout^T -> bf16)
#define LIN_PER_HOP  391          // ceil(NNODES/128)
#define LIN_BLOCKS   (LIN_PER_HOP * NHOPS)     // 1564

typedef __attribute__((ext_vector_type(8))) short bfrag_t;   // 8 x bf16
typedef __attribute__((ext_vector_type(4))) float facc_t;    // 4 x f32

static __device__ __forceinline__ unsigned short f2bf(float f) {
  unsigned int u = __float_as_uint(f);
  unsigned int r = (u + 0x7fffu + ((u >> 16) & 1u)) >> 16;
  return (unsigned short)r;
}
static __device__ __forceinline__ float bf2f_lo(unsigned int u) {
  return __uint_as_float(u << 16);
}
static __device__ __forceinline__ float bf2f_hi(unsigned int u) {
  return __uint_as_float(u & 0xffff0000u);
}

// ---------------------------------------------------------------------------
// Phase A (fused): convx | convw | hist | wot. All independent.
// ---------------------------------------------------------------------------
__global__ __launch_bounds__(256) void phaseA_kernel(
    const float* __restrict__ x, unsigned short* __restrict__ xb,
    const float* __restrict__ W, unsigned short* __restrict__ Wt,
    const int* __restrict__ erows, int* __restrict__ counts,
    const float* __restrict__ Wout, unsigned short* __restrict__ wot) {
  const int bx = blockIdx.x;
  const int t  = threadIdx.x;
  if (bx < CONVX_BLOCKS) {
    const size_t i = ((size_t)bx * 256 + t) * 4;
    float4 v = *(const float4*)&x[i];
    ushort4 o;
    o.x = f2bf(v.x); o.y = f2bf(v.y); o.z = f2bf(v.z); o.w = f2bf(v.w);
    *(ushort4*)&xb[i] = o;
  } else if (bx < CONVX_BLOCKS + CONVW_BLOCKS) {
    const int i = (bx - CONVX_BLOCKS) * 256 + t;
    const int k = i / (NH * NF);
    const int rem = i - k * NH * NF;
    const int n = rem / NF;
    const int f = rem - n * NF;
    Wt[i] = f2bf(W[(size_t)k * NF * NH + (size_t)f * NH + n]);
  } else if (bx < CONVX_BLOCKS + CONVW_BLOCKS + HIST_BLOCKS) {
    const int id  = bx - (CONVX_BLOCKS + CONVW_BLOCKS);
    const int hop = id / 3125;
    const int e   = (id - hop * 3125) * 256 + t;
    const int r = erows[(size_t)hop * NEDGES + e];
    atomicAdd(&counts[hop * NNODES + r], 1);
  } else {
    // Wout^T -> bf16: wot[o][f] = bf16(Wout[f][o]); reads coalesced.
    const int i = (bx - (CONVX_BLOCKS + CONVW_BLOCKS + HIST_BLOCKS)) * 256 + t;
    const int o = i & 63;
    const int f = i >> 6;
    wot[(size_t)o * 512 + f] = f2bf(Wout[(size_t)f * NO + o]);
  }
}

// ---------------------------------------------------------------------------
// CSR build step 2: exclusive scan per hop. Also initializes the 196
// per-bucket staging cursors (bucket b base = offs[b*256]).
// ---------------------------------------------------------------------------
__global__ __launch_bounds__(1024) void scan_kernel(
    const int* __restrict__ counts, int* __restrict__ offs,
    int* __restrict__ bucketCur) {
  const int hop  = blockIdx.x;
  const int t    = threadIdx.x;
  const int lane = t & 63;
  const int wid  = t >> 6;
  __shared__ int wsum[16];
  __shared__ int carry_s;
  if (t == 0) carry_s = 0;
  __syncthreads();
  const int CH  = 8192;
  const int nch = (NNODES + CH - 1) / CH;     // 7
  for (int ch = 0; ch < nch; ++ch) {
    const int i0 = ch * CH + t * 8;
    int v[8];
    if (i0 + 7 < NNODES) {
      int4 a = *(const int4*)&counts[hop * NNODES + i0];
      int4 b = *(const int4*)&counts[hop * NNODES + i0 + 4];
      v[0]=a.x; v[1]=a.y; v[2]=a.z; v[3]=a.w;
      v[4]=b.x; v[5]=b.y; v[6]=b.z; v[7]=b.w;
    } else {
#pragma unroll
      for (int j = 0; j < 8; ++j)
        v[j] = (i0 + j < NNODES) ? counts[hop * NNODES + i0 + j] : 0;
    }
    int l[8];
    int run = 0;
#pragma unroll
    for (int j = 0; j < 8; ++j) { run += v[j]; l[j] = run; }   // inclusive
    int s = run;
#pragma unroll
    for (int d = 1; d < 64; d <<= 1) {
      int n = __shfl_up(s, d, 64);
      if (lane >= d) s += n;
    }
    if (lane == 63) wsum[wid] = s;
    __syncthreads();
    if (t < 16) {
      int ws = wsum[t];
#pragma unroll
      for (int d = 1; d < 16; d <<= 1) {
        int n = __shfl_up(ws, d, 16);
        if (t >= d) ws += n;
      }
      wsum[t] = ws;
    }
    __syncthreads();
    const int base = carry_s + (wid ? wsum[wid - 1] : 0) + (s - run);
    if (i0 + 7 < NNODES) {
      int4 o0 = make_int4(base, base + l[0], base + l[1], base + l[2]);
      int4 o1 = make_int4(base + l[3], base + l[4], base + l[5], base + l[6]);
      *(int4*)&offs[hop * (NNODES + 1) + i0]     = o0;
      *(int4*)&offs[hop * (NNODES + 1) + i0 + 4] = o1;
    } else {
#pragma unroll
      for (int j = 0; j < 8; ++j) {
        if (i0 + j < NNODES) {
          const int excl = base + (l[j] - v[j]);
          offs[hop * (NNODES + 1) + i0 + j] = excl;
        }
      }
    }
    // bucket cursor init: rows at multiples of 256 (i0 % 8 == 0, so only j=0)
    if ((i0 & 255) == 0 && i0 < NNODES)
      bucketCur[hop * NB + (i0 >> 8)] = base;
    __syncthreads();
    if (t == 0) carry_s += wsum[15];
    __syncthreads();
  }
  if (t == 0) offs[hop * (NNODES + 1) + NNODES] = carry_s;
}

// ---------------------------------------------------------------------------
// Linear via MFMA, all 4 hops in one dispatch (1564 blocks).
// ---------------------------------------------------------------------------
__global__ __launch_bounds__(256) void linear_kernel(
    const unsigned short* __restrict__ xb, const unsigned short* __restrict__ Wt,
    const float* __restrict__ b, unsigned short* __restrict__ slots) {
  const int lb  = blockIdx.x;
  const int hop = lb / LIN_PER_HOP;
  const int mb  = lb - hop * LIN_PER_HOP;
  const unsigned short* Wk = Wt + (size_t)hop * NH * NF;
  const float* bk = b + hop * NH;
  unsigned short* hb = slots + (size_t)(hop + 1) * NNODES * NH;

  const int t    = threadIdx.x;
  const int lane = t & 63;
  const int wave = t >> 6;
  const int wm   = (wave >> 1) * 64;
  const int wn   = (wave & 1) * 64;
  const int m0   = mb * 128;
  const int l15  = lane & 15;
  const int quad = lane >> 4;

  facc_t acc[4][4];
#pragma unroll
  for (int i = 0; i < 4; ++i)
#pragma unroll
    for (int j = 0; j < 4; ++j) {
      facc_t z = {0.f, 0.f, 0.f, 0.f};
      acc[i][j] = z;
    }

#pragma unroll
  for (int k0 = 0; k0 < NF; k0 += 32) {
    bfrag_t a[4], bb[4];
#pragma unroll
    for (int mi = 0; mi < 4; ++mi) {
      const int m = m0 + wm + mi * 16 + l15;
      a[mi] = *(const bfrag_t*)&xb[(size_t)m * NF + k0 + quad * 8];
    }
#pragma unroll
    for (int ni = 0; ni < 4; ++ni) {
      const int n = wn + ni * 16 + l15;
      bb[ni] = *(const bfrag_t*)&Wk[(size_t)n * NF + k0 + quad * 8];
    }
#pragma unroll
    for (int mi = 0; mi < 4; ++mi)
#pragma unroll
      for (int ni = 0; ni < 4; ++ni)
        acc[mi][ni] = __builtin_amdgcn_mfma_f32_16x16x32_bf16(
            a[mi], bb[ni], acc[mi][ni], 0, 0, 0);
  }

#pragma unroll
  for (int ni = 0; ni < 4; ++ni) {
    const int n = wn + ni * 16 + l15;
    const float bias = bk[n];
#pragma unroll
    for (int mi = 0; mi < 4; ++mi) {
#pragma unroll
      for (int r = 0; r < 4; ++r) {
        const int m = m0 + wm + mi * 16 + quad * 4 + r;
        if (m < NNODES) hb[(size_t)m * NH + n] = f2bf(acc[mi][ni][r] + bias);
      }
    }
  }
}

// ---------------------------------------------------------------------------
// Bin pass: rank 4096 edges per block into 196 row-buckets via LDS hist;
// ONE global atomicAdd per (block,bucket) reserves space; edges written in
// ~21-entry contiguous runs into bucket-partitioned staging (aliases dead
// xb). pack: val(hi32) | rowlo<<16 | col. grid (196, NHOPS).
// ---------------------------------------------------------------------------
__global__ __launch_bounds__(256) void bin_kernel(
    const int* __restrict__ erows, const int* __restrict__ ecols,
    const float* __restrict__ evals, int* __restrict__ bucketCur,
    unsigned long long* __restrict__ staging) {
  const int hop = blockIdx.y;
  const int t   = threadIdx.x;
  const int bb  = blockIdx.x * EPB;
  __shared__ int lhist[NB];
  __shared__ int gbase[NB];
  for (int i = t; i < NB; i += 256) lhist[i] = 0;
  __syncthreads();

  unsigned long long pk[16];
  int bkt[16], rnk[16];
  const size_t g0 = (size_t)hop * NEDGES;
#pragma unroll
  for (int k = 0; k < 4; ++k) {
    const int e0 = bb + t * 4 + k * 1024;
    if (e0 + 3 < NEDGES) {
      const int4   rr = *(const int4*)&erows[g0 + e0];
      const int4   cc = *(const int4*)&ecols[g0 + e0];
      const float4 vv = *(const float4*)&evals[g0 + e0];
      const int r4[4] = {rr.x, rr.y, rr.z, rr.w};
      const int c4[4] = {cc.x, cc.y, cc.z, cc.w};
      const float v4[4] = {vv.x, vv.y, vv.z, vv.w};
#pragma unroll
      for (int j = 0; j < 4; ++j) {
        const int b = r4[j] >> 8;
        bkt[k * 4 + j] = b;
        rnk[k * 4 + j] = atomicAdd(&lhist[b], 1);
        pk[k * 4 + j] =
            ((unsigned long long)__float_as_uint(v4[j]) << 32) |
            ((unsigned)(r4[j] & 255) << 16) | (unsigned)c4[j];
      }
    } else {
#pragma unroll
      for (int j = 0; j < 4; ++j) {
        const int e = e0 + j;
        if (e < NEDGES) {
          const int r = erows[g0 + e];
          const int b = r >> 8;
          bkt[k * 4 + j] = b;
          rnk[k * 4 + j] = atomicAdd(&lhist[b], 1);
          pk[k * 4 + j] =
              ((unsigned long long)__float_as_uint(evals[g0 + e]) << 32) |
              ((unsigned)(r & 255) << 16) | (unsigned)ecols[g0 + e];
        } else {
          bkt[k * 4 + j] = -1;
        }
      }
    }
  }
  __syncthreads();
  for (int i = t; i < NB; i += 256) {
    const int c = lhist[i];
    gbase[i] = c ? atomicAdd(&bucketCur[hop * NB + i], c) : 0;
  }
  __syncthreads();
  unsigned long long* dst = staging + (size_t)hop * NEDGES;
#pragma unroll
  for (int q = 0; q < 16; ++q)
    if (bkt[q] >= 0) dst[gbase[bkt[q]] + rnk[q]] = pk[q];
}

// ---------------------------------------------------------------------------
// Place pass: one block per (bucket,hop). Sequential read of the bucket's
// staging segment; exact CSR position via LDS row cursors (no global
// atomics). All writes land in this block's own 32KB window.
// ---------------------------------------------------------------------------
__global__ __launch_bounds__(256) void place_kernel(
    const int* __restrict__ offs, const unsigned long long* __restrict__ staging,
    unsigned long long* __restrict__ ecsr) {
  const int hop = blockIdx.y;
  const int bk  = blockIdx.x;
  const int t   = threadIdx.x;
  const int r0  = bk * 256;
  const int nr  = (NNODES - r0 < 256) ? (NNODES - r0) : 256;
  const int* o = offs + (size_t)hop * (NNODES + 1);
  __shared__ int cur[257];
  for (int i = t; i <= nr; i += 256) cur[i] = o[r0 + i];
  __syncthreads();
  const int s = cur[0];
  const int e = cur[nr];          // never touched by atomics (rowlo < nr)
  __syncthreads();                // snapshot s,e before any cursor bumps
  const unsigned long long* src = staging + (size_t)hop * NEDGES;
  unsigned long long* dst       = ecsr + (size_t)hop * NEDGES;
  for (int i = s + t; i < e; i += 256) {
    const unsigned long long v = src[i];
    const unsigned lo = (unsigned)v;
    const int rl = (lo >> 16) & 255;
    const int d = atomicAdd(&cur[rl], 1);
    dst[d] = (v & 0xFFFFFFFF00000000ull) | (unsigned long long)(lo & 0xFFFFu);
  }
}

// ---------------------------------------------------------------------------
// Gather SpMM (ONE HOP per dispatch — sequential dispatches enforce the
// hb[k]/agg[k] slot-aliasing dependency).
// ---------------------------------------------------------------------------
__global__ __launch_bounds__(256) void gather_kernel(
    const int* __restrict__ offs, const int2* __restrict__ ecsr,
    const unsigned short* __restrict__ hb, unsigned short* __restrict__ aggb) {
  const int t    = threadIdx.x;
  const int lane = t & 63;
  const int wid  = t >> 6;
  const int r = blockIdx.x * 4 + wid;
  const int g  = lane >> 4;    // edge subgroup 0..3
  const int sl = lane & 15;    // feature slice: feats sl*8 .. sl*8+7
  const int s = offs[r];
  const int e = offs[r + 1];

  float acc[8];
#pragma unroll
  for (int j = 0; j < 8; ++j) acc[j] = 0.f;

  for (int p = s; p < e; p += 16) {
    int2 ed[4];
#pragma unroll
    for (int q = 0; q < 4; ++q) {
      const int idx = p + q * 4 + g;
      ed[q] = (idx < e) ? ecsr[idx] : make_int2(0, 0);
    }
    uint4 hv[4];
#pragma unroll
    for (int q = 0; q < 4; ++q)
      hv[q] = *(const uint4*)&hb[(size_t)ed[q].x * NH + sl * 8];
#pragma unroll
    for (int q = 0; q < 4; ++q) {
      const float v = __int_as_float(ed[q].y);
      acc[0] += v * bf2f_lo(hv[q].x);
      acc[1] += v * bf2f_hi(hv[q].x);
      acc[2] += v * bf2f_lo(hv[q].y);
      acc[3] += v * bf2f_hi(hv[q].y);
      acc[4] += v * bf2f_lo(hv[q].z);
      acc[5] += v * bf2f_hi(hv[q].z);
      acc[6] += v * bf2f_lo(hv[q].w);
      acc[7] += v * bf2f_hi(hv[q].w);
    }
  }

#pragma unroll
  for (int j = 0; j < 8; ++j) {
    acc[j] += __shfl_xor(acc[j], 16, 64);
    acc[j] += __shfl_xor(acc[j], 32, 64);
  }

  if (g == 0) {
    uint4 o;
    o.x = (unsigned)f2bf(acc[0]) | ((unsigned)f2bf(acc[1]) << 16);
    o.y = (unsigned)f2bf(acc[2]) | ((unsigned)f2bf(acc[3]) << 16);
    o.z = (unsigned)f2bf(acc[4]) | ((unsigned)f2bf(acc[5]) << 16);
    o.w = (unsigned)f2bf(acc[6]) | ((unsigned)f2bf(acc[7]) << 16);
    *(uint4*)&aggb[(size_t)r * NH + sl * 8] = o;
  }
}

// ---------------------------------------------------------------------------
// Output GEMM via MFMA: out[50000,64] = elu(concat) @ Wout + bout.
// Old f32 out_kernel: 64-thr blocks + 33KB LDS -> 9% occupancy, 159us.
// Here: 782 blocks x 4 waves, each wave 16 rows x 64 cols (1x4 16x16x32
// tiles, K=512 in 16 steps). A = aggb (bf16) with ELU applied in-register
// (positive bf16 values round-trip exactly; negatives get expf-1 with
// <=2^-9 rounding). B = Wout^T pre-converted to bf16 (wot, from phaseA).
// Bias added in f32 epilogue. No LDS.
// ---------------------------------------------------------------------------
__global__ __launch_bounds__(256) void out2_kernel(
    const unsigned short* __restrict__ aggb,   // slots base; concat slots 0..3
    const unsigned short* __restrict__ wot,    // [64][512] bf16 Wout^T
    const float* __restrict__ bout, float* __restrict__ out) {
  const int t    = threadIdx.x;
  const int lane = t & 63;
  const int wave = t >> 6;
  const int l15  = lane & 15;
  const int quad = lane >> 4;
  const int m0   = blockIdx.x * 64 + wave * 16;   // 16 rows per wave

  facc_t acc[4];
#pragma unroll
  for (int ni = 0; ni < 4; ++ni) { facc_t z = {0.f,0.f,0.f,0.f}; acc[ni] = z; }

  const int mrow  = m0 + l15;
  const int mload = mrow < NNODES ? mrow : NNODES - 1;  // clamp; masked at store

#pragma unroll
  for (int ks = 0; ks < 16; ++ks) {
    const int f0  = ks * 32 + quad * 8;            // feature index 0..511
    const int hop = f0 >> 7;
    const int j0  = f0 & 127;
    uint4 ua = *(const uint4*)&aggb[((size_t)hop * NNODES + mload) * NH + j0];
    const unsigned uu[4] = {ua.x, ua.y, ua.z, ua.w};
    unsigned pr[4];
#pragma unroll
    for (int q = 0; q < 4; ++q) {
      float lo = bf2f_lo(uu[q]);
      float hi = bf2f_hi(uu[q]);
      lo = lo > 0.f ? lo : (expf(lo) - 1.f);
      hi = hi > 0.f ? hi : (expf(hi) - 1.f);
      pr[q] = (unsigned)f2bf(lo) | ((unsigned)f2bf(hi) << 16);
    }
    uint4 ra; ra.x = pr[0]; ra.y = pr[1]; ra.z = pr[2]; ra.w = pr[3];
    bfrag_t af = *(bfrag_t*)&ra;
    bfrag_t bf[4];
#pragma unroll
    for (int ni = 0; ni < 4; ++ni) {
      const int n = ni * 16 + l15;
      bf[ni] = *(const bfrag_t*)&wot[(size_t)n * 512 + f0];
    }
#pragma unroll
    for (int ni = 0; ni < 4; ++ni)
      acc[ni] = __builtin_amdgcn_mfma_f32_16x16x32_bf16(af, bf[ni], acc[ni], 0, 0, 0);
  }

#pragma unroll
  for (int ni = 0; ni < 4; ++ni) {
    const int o = ni * 16 + l15;
    const float bo = bout[o];
#pragma unroll
    for (int r = 0; r < 4; ++r) {
      const int m = m0 + quad * 4 + r;
      if (m < NNODES) out[(size_t)m * NO + o] = acc[ni][r] + bo;
    }
  }
}

// ---------------------------------------------------------------------------
extern "C" void kernel_launch(void* const* d_in, const int* in_sizes, int n_in,
                              void* d_out, int out_size, void* d_ws, size_t ws_size,
                              hipStream_t stream) {
  const float* x     = (const float*)d_in[0];
  const float* W     = (const float*)d_in[1];
  const float* b     = (const float*)d_in[2];
  const float* W_out = (const float*)d_in[3];
  const float* b_out = (const float*)d_in[4];
  const int*   erows = (const int*)d_in[5];
  const int*   ecols = (const int*)d_in[6];
  const float* evals = (const float*)d_in[7];
  float* out = (float*)d_out;

  // ws layout (bytes), total ~117e6 (<128e6 known-safe):
  //   slots: 5 x NNODES*NH bf16 = 64.0e6
  //   xb: NPAD*NF bf16 = 25.7e6  (REUSED as 25.6e6 staging after linear)
  //   Wt: 0.26e6 | ecsr: 25.6e6 | ints 1.6e6 | wot: 65.5e3
  unsigned short* slots = (unsigned short*)d_ws;
  unsigned short* xb = slots + (size_t)(NHOPS + 1) * NNODES * NH;
  unsigned short* Wt = xb + (size_t)NPAD * NF;
  unsigned long long* ecsr = (unsigned long long*)(Wt + (size_t)NHOPS * NH * NF);
  int* counts    = (int*)(ecsr + (size_t)NHOPS * NEDGES);
  int* offs      = counts + NHOPS * NNODES;
  int* bucketCur = offs + NHOPS * (NNODES + 1);
  unsigned short* wot = (unsigned short*)(bucketCur + NHOPS * NB);
  // staging aliases xb: xb is dead once linear_kernel has run.
  unsigned long long* staging = (unsigned long long*)xb;

  hipMemsetAsync(counts, 0, (size_t)NHOPS * NNODES * sizeof(int), stream);

  phaseA_kernel<<<CONVX_BLOCKS + CONVW_BLOCKS + HIST_BLOCKS + WOT_BLOCKS,
                  256, 0, stream>>>(x, xb, W, Wt, erows, counts, W_out, wot);
  scan_kernel<<<NHOPS, 1024, 0, stream>>>(counts, offs, bucketCur);
  linear_kernel<<<LIN_BLOCKS, 256, 0, stream>>>(xb, Wt, b, slots);
  bin_kernel<<<dim3(NB, NHOPS), 256, 0, stream>>>(
      erows, ecols, evals, bucketCur, staging);
  place_kernel<<<dim3(NB, NHOPS), 256, 0, stream>>>(offs, staging, ecsr);

  for (int k = 0; k < NHOPS; ++k) {
    gather_kernel<<<NNODES / 4, 256, 0, stream>>>(
        offs + (size_t)k * (NNODES + 1), (const int2*)(ecsr + (size_t)k * NEDGES),
        slots + (size_t)(k + 1) * NNODES * NH,   // hb[k]
        slots + (size_t)k * NNODES * NH);        // agg[k]
  }

  out2_kernel<<<782, 256, 0, stream>>>(slots, wot, b_out, out);
}

// Round 9
// 462.486 us; speedup vs baseline: 1.9293x; 1.2348x over previous
//
#include <hip/hip_runtime.h>
#include <hip/hip_bf16.h>
#include <math.h>

#define NNODES 50000
#define NPAD   50176              // 392*128, padded rows for MFMA tile overrun
#define NEDGES 800000
#define NHOPS  4
#define NF     256
#define NH     128
#define NO     64
#define NB     196                // row buckets of 256 rows (50000/256 -> 196)
#define EPB    4096               // edges per bin block (256 thr x 16)

#define CONVX_BLOCKS 12500        // NNODES*NF/4/256
#define CONVW_BLOCKS 512          // NHOPS*NH*NF/256
#define HIST1_BLOCKS (NB * NHOPS) // 784: bucket-level LDS hist (R7)
#define WOT_BLOCKS   128          // 64*512/256 (Wout^T -> bf16)
#define LIN_PER_HOP  391          // ceil(NNODES/128)
#define LIN_BLOCKS   (LIN_PER_HOP * NHOPS)     // 1564

typedef __attribute__((ext_vector_type(8))) short bfrag_t;   // 8 x bf16
typedef __attribute__((ext_vector_type(4))) float facc_t;    // 4 x f32

static __device__ __forceinline__ unsigned short f2bf(float f) {
  unsigned int u = __float_as_uint(f);
  unsigned int r = (u + 0x7fffu + ((u >> 16) & 1u)) >> 16;
  return (unsigned short)r;
}
static __device__ __forceinline__ float bf2f_lo(unsigned int u) {
  return __uint_as_float(u << 16);
}
static __device__ __forceinline__ float bf2f_hi(unsigned int u) {
  return __uint_as_float(u & 0xffff0000u);
}

// ---------------------------------------------------------------------------
// Phase A (fused): convx | convw | hist1 | wot. All independent.
// R7: hist branch replaced by BUCKET-level LDS histogram. Old version did
// 3.2M device-scope atomicAdds into counts[200K] -> each a random 32B RMW
// at HBM (8 XCD L2s can't merge) -> ~100MB of the measured 125MB WRITE_SIZE
// and ~120us of phaseA's 148us. Now: 196-bin LDS hist per block, one global
// atomic per (block,bucket) = 154K atomics into a 3KB hot region.
// Per-ROW counts are derived later from staged edges (countscan_kernel).
// ---------------------------------------------------------------------------
__global__ __launch_bounds__(256) void phaseA_kernel(
    const float* __restrict__ x, unsigned short* __restrict__ xb,
    const float* __restrict__ W, unsigned short* __restrict__ Wt,
    const int* __restrict__ erows, int* __restrict__ bucketCur,
    const float* __restrict__ Wout, unsigned short* __restrict__ wot) {
  const int bx = blockIdx.x;
  const int t  = threadIdx.x;
  if (bx < CONVX_BLOCKS) {
    const size_t i = ((size_t)bx * 256 + t) * 4;
    float4 v = *(const float4*)&x[i];
    ushort4 o;
    o.x = f2bf(v.x); o.y = f2bf(v.y); o.z = f2bf(v.z); o.w = f2bf(v.w);
    *(ushort4*)&xb[i] = o;
  } else if (bx < CONVX_BLOCKS + CONVW_BLOCKS) {
    const int i = (bx - CONVX_BLOCKS) * 256 + t;
    const int k = i / (NH * NF);
    const int rem = i - k * NH * NF;
    const int n = rem / NF;
    const int f = rem - n * NF;
    Wt[i] = f2bf(W[(size_t)k * NF * NH + (size_t)f * NH + n]);
  } else if (bx < CONVX_BLOCKS + CONVW_BLOCKS + HIST1_BLOCKS) {
    const int id  = bx - (CONVX_BLOCKS + CONVW_BLOCKS);
    const int hop = id / NB;
    const int bb  = (id - hop * NB) * EPB;
    __shared__ int bh[NB];
    for (int i = t; i < NB; i += 256) bh[i] = 0;
    __syncthreads();
    const size_t g0 = (size_t)hop * NEDGES;
#pragma unroll
    for (int k = 0; k < 4; ++k) {
      const int e0 = bb + t * 4 + k * 1024;
      if (e0 + 3 < NEDGES) {
        const int4 rr = *(const int4*)&erows[g0 + e0];
        atomicAdd(&bh[rr.x >> 8], 1);
        atomicAdd(&bh[rr.y >> 8], 1);
        atomicAdd(&bh[rr.z >> 8], 1);
        atomicAdd(&bh[rr.w >> 8], 1);
      } else {
        for (int j = 0; j < 4; ++j)
          if (e0 + j < NEDGES) atomicAdd(&bh[erows[g0 + e0 + j] >> 8], 1);
      }
    }
    __syncthreads();
    for (int i = t; i < NB; i += 256)
      if (bh[i]) atomicAdd(&bucketCur[hop * NB + i], bh[i]);
  } else {
    // Wout^T -> bf16: wot[o][f] = bf16(Wout[f][o]); reads coalesced.
    const int i = (bx - (CONVX_BLOCKS + CONVW_BLOCKS + HIST1_BLOCKS)) * 256 + t;
    const int o = i & 63;
    const int f = i >> 6;
    wot[(size_t)o * 512 + f] = f2bf(Wout[(size_t)f * NO + o]);
  }
}

// ---------------------------------------------------------------------------
// Per-hop exclusive scan of 196 bucket totals (in bucketCur after hist1).
// Rewrites bucketCur to bases (for bin's allocator) and writes the
// immutable bucketBase[NB+1] (for countscan). Invariant: bucketBase[b] ==
// offs[b*256] (CSR offset at bucket boundary) -> place_kernel unchanged.
// ---------------------------------------------------------------------------
__global__ __launch_bounds__(256) void scanB_kernel(
    int* __restrict__ bucketCur, int* __restrict__ bucketBase) {
  const int hop = blockIdx.x;
  const int t   = threadIdx.x;
  __shared__ int tot[NB];
  for (int i = t; i < NB; i += 256) tot[i] = bucketCur[hop * NB + i];
  __syncthreads();
  if (t == 0) {
    int run = 0;
    for (int i = 0; i < NB; ++i) { const int c = tot[i]; tot[i] = run; run += c; }
  }
  __syncthreads();
  for (int i = t; i < NB; i += 256) {
    bucketCur[hop * NB + i]        = tot[i];
    bucketBase[hop * (NB + 1) + i] = tot[i];
  }
  if (t == 0) bucketBase[hop * (NB + 1) + NB] = NEDGES;
}

// ---------------------------------------------------------------------------
// Linear via MFMA, all 4 hops in one dispatch (1564 blocks).
// ---------------------------------------------------------------------------
__global__ __launch_bounds__(256) void linear_kernel(
    const unsigned short* __restrict__ xb, const unsigned short* __restrict__ Wt,
    const float* __restrict__ b, unsigned short* __restrict__ slots) {
  const int lb  = blockIdx.x;
  const int hop = lb / LIN_PER_HOP;
  const int mb  = lb - hop * LIN_PER_HOP;
  const unsigned short* Wk = Wt + (size_t)hop * NH * NF;
  const float* bk = b + hop * NH;
  unsigned short* hb = slots + (size_t)(hop + 1) * NNODES * NH;

  const int t    = threadIdx.x;
  const int lane = t & 63;
  const int wave = t >> 6;
  const int wm   = (wave >> 1) * 64;
  const int wn   = (wave & 1) * 64;
  const int m0   = mb * 128;
  const int l15  = lane & 15;
  const int quad = lane >> 4;

  facc_t acc[4][4];
#pragma unroll
  for (int i = 0; i < 4; ++i)
#pragma unroll
    for (int j = 0; j < 4; ++j) {
      facc_t z = {0.f, 0.f, 0.f, 0.f};
      acc[i][j] = z;
    }

#pragma unroll
  for (int k0 = 0; k0 < NF; k0 += 32) {
    bfrag_t a[4], bb[4];
#pragma unroll
    for (int mi = 0; mi < 4; ++mi) {
      const int m = m0 + wm + mi * 16 + l15;
      a[mi] = *(const bfrag_t*)&xb[(size_t)m * NF + k0 + quad * 8];
    }
#pragma unroll
    for (int ni = 0; ni < 4; ++ni) {
      const int n = wn + ni * 16 + l15;
      bb[ni] = *(const bfrag_t*)&Wk[(size_t)n * NF + k0 + quad * 8];
    }
#pragma unroll
    for (int mi = 0; mi < 4; ++mi)
#pragma unroll
      for (int ni = 0; ni < 4; ++ni)
        acc[mi][ni] = __builtin_amdgcn_mfma_f32_16x16x32_bf16(
            a[mi], bb[ni], acc[mi][ni], 0, 0, 0);
  }

#pragma unroll
  for (int ni = 0; ni < 4; ++ni) {
    const int n = wn + ni * 16 + l15;
    const float bias = bk[n];
#pragma unroll
    for (int mi = 0; mi < 4; ++mi) {
#pragma unroll
      for (int r = 0; r < 4; ++r) {
        const int m = m0 + wm + mi * 16 + quad * 4 + r;
        if (m < NNODES) hb[(size_t)m * NH + n] = f2bf(acc[mi][ni][r] + bias);
      }
    }
  }
}

// ---------------------------------------------------------------------------
// Bin pass: rank 4096 edges per block into 196 row-buckets via LDS hist;
// ONE global atomicAdd per (block,bucket) reserves space; edges written in
// ~21-entry contiguous runs into bucket-partitioned staging (aliases dead
// xb). pack: val(hi32) | rowlo<<16 | col. grid (196, NHOPS).
// ---------------------------------------------------------------------------
__global__ __launch_bounds__(256) void bin_kernel(
    const int* __restrict__ erows, const int* __restrict__ ecols,
    const float* __restrict__ evals, int* __restrict__ bucketCur,
    unsigned long long* __restrict__ staging) {
  const int hop = blockIdx.y;
  const int t   = threadIdx.x;
  const int bb  = blockIdx.x * EPB;
  __shared__ int lhist[NB];
  __shared__ int gbase[NB];
  for (int i = t; i < NB; i += 256) lhist[i] = 0;
  __syncthreads();

  unsigned long long pk[16];
  int bkt[16], rnk[16];
  const size_t g0 = (size_t)hop * NEDGES;
#pragma unroll
  for (int k = 0; k < 4; ++k) {
    const int e0 = bb + t * 4 + k * 1024;
    if (e0 + 3 < NEDGES) {
      const int4   rr = *(const int4*)&erows[g0 + e0];
      const int4   cc = *(const int4*)&ecols[g0 + e0];
      const float4 vv = *(const float4*)&evals[g0 + e0];
      const int r4[4] = {rr.x, rr.y, rr.z, rr.w};
      const int c4[4] = {cc.x, cc.y, cc.z, cc.w};
      const float v4[4] = {vv.x, vv.y, vv.z, vv.w};
#pragma unroll
      for (int j = 0; j < 4; ++j) {
        const int b = r4[j] >> 8;
        bkt[k * 4 + j] = b;
        rnk[k * 4 + j] = atomicAdd(&lhist[b], 1);
        pk[k * 4 + j] =
            ((unsigned long long)__float_as_uint(v4[j]) << 32) |
            ((unsigned)(r4[j] & 255) << 16) | (unsigned)c4[j];
      }
    } else {
#pragma unroll
      for (int j = 0; j < 4; ++j) {
        const int e = e0 + j;
        if (e < NEDGES) {
          const int r = erows[g0 + e];
          const int b = r >> 8;
          bkt[k * 4 + j] = b;
          rnk[k * 4 + j] = atomicAdd(&lhist[b], 1);
          pk[k * 4 + j] =
              ((unsigned long long)__float_as_uint(evals[g0 + e]) << 32) |
              ((unsigned)(r & 255) << 16) | (unsigned)ecols[g0 + e];
        } else {
          bkt[k * 4 + j] = -1;
        }
      }
    }
  }
  __syncthreads();
  for (int i = t; i < NB; i += 256) {
    const int c = lhist[i];
    gbase[i] = c ? atomicAdd(&bucketCur[hop * NB + i], c) : 0;
  }
  __syncthreads();
  unsigned long long* dst = staging + (size_t)hop * NEDGES;
#pragma unroll
  for (int q = 0; q < 16; ++q)
    if (bkt[q] >= 0) dst[gbase[bkt[q]] + rnk[q]] = pk[q];
}

// ---------------------------------------------------------------------------
// Per-row counts from staged edges: one block per (bucket,hop), LDS 256-bin
// histogram of rowlo, coalesced write to counts. Replaces the old
// 3.2M-global-atomic hist.
// ---------------------------------------------------------------------------
__global__ __launch_bounds__(256) void countscan_kernel(
    const int* __restrict__ bucketBase,
    const unsigned long long* __restrict__ staging, int* __restrict__ counts) {
  const int hop = blockIdx.y;
  const int b   = blockIdx.x;
  const int t   = threadIdx.x;
  const int s = bucketBase[hop * (NB + 1) + b];
  const int e = bucketBase[hop * (NB + 1) + b + 1];
  __shared__ int h[256];
  h[t] = 0;
  __syncthreads();
  const unsigned long long* src = staging + (size_t)hop * NEDGES;
  for (int i = s + t; i < e; i += 256) {
    const int rl = ((unsigned)src[i] >> 16) & 255;
    atomicAdd(&h[rl], 1);
  }
  __syncthreads();
  const int r0 = b * 256;
  if (r0 + t < NNODES) counts[hop * NNODES + r0 + t] = h[t];
}

// ---------------------------------------------------------------------------
// CSR build: exclusive scan per hop over per-row counts.
// ---------------------------------------------------------------------------
__global__ __launch_bounds__(1024) void scan_kernel(
    const int* __restrict__ counts, int* __restrict__ offs) {
  const int hop  = blockIdx.x;
  const int t    = threadIdx.x;
  const int lane = t & 63;
  const int wid  = t >> 6;
  __shared__ int wsum[16];
  __shared__ int carry_s;
  if (t == 0) carry_s = 0;
  __syncthreads();
  const int CH  = 8192;
  const int nch = (NNODES + CH - 1) / CH;     // 7
  for (int ch = 0; ch < nch; ++ch) {
    const int i0 = ch * CH + t * 8;
    int v[8];
    if (i0 + 7 < NNODES) {
      int4 a = *(const int4*)&counts[hop * NNODES + i0];
      int4 b = *(const int4*)&counts[hop * NNODES + i0 + 4];
      v[0]=a.x; v[1]=a.y; v[2]=a.z; v[3]=a.w;
      v[4]=b.x; v[5]=b.y; v[6]=b.z; v[7]=b.w;
    } else {
#pragma unroll
      for (int j = 0; j < 8; ++j)
        v[j] = (i0 + j < NNODES) ? counts[hop * NNODES + i0 + j] : 0;
    }
    int l[8];
    int run = 0;
#pragma unroll
    for (int j = 0; j < 8; ++j) { run += v[j]; l[j] = run; }   // inclusive
    int s = run;
#pragma unroll
    for (int d = 1; d < 64; d <<= 1) {
      int n = __shfl_up(s, d, 64);
      if (lane >= d) s += n;
    }
    if (lane == 63) wsum[wid] = s;
    __syncthreads();
    if (t < 16) {
      int ws = wsum[t];
#pragma unroll
      for (int d = 1; d < 16; d <<= 1) {
        int n = __shfl_up(ws, d, 16);
        if (t >= d) ws += n;
      }
      wsum[t] = ws;
    }
    __syncthreads();
    const int base = carry_s + (wid ? wsum[wid - 1] : 0) + (s - run);
    if (i0 + 7 < NNODES) {
      int4 o0 = make_int4(base, base + l[0], base + l[1], base + l[2]);
      int4 o1 = make_int4(base + l[3], base + l[4], base + l[5], base + l[6]);
      *(int4*)&offs[hop * (NNODES + 1) + i0]     = o0;
      *(int4*)&offs[hop * (NNODES + 1) + i0 + 4] = o1;
    } else {
#pragma unroll
      for (int j = 0; j < 8; ++j) {
        if (i0 + j < NNODES) {
          const int excl = base + (l[j] - v[j]);
          offs[hop * (NNODES + 1) + i0 + j] = excl;
        }
      }
    }
    __syncthreads();
    if (t == 0) carry_s += wsum[15];
    __syncthreads();
  }
  if (t == 0) offs[hop * (NNODES + 1) + NNODES] = carry_s;
}

// ---------------------------------------------------------------------------
// Place pass: one block per (bucket,hop). Sequential read of the bucket's
// staging segment; exact CSR position via LDS row cursors (no global
// atomics). All writes land in this block's own 32KB window.
// ---------------------------------------------------------------------------
__global__ __launch_bounds__(256) void place_kernel(
    const int* __restrict__ offs, const unsigned long long* __restrict__ staging,
    unsigned long long* __restrict__ ecsr) {
  const int hop = blockIdx.y;
  const int bk  = blockIdx.x;
  const int t   = threadIdx.x;
  const int r0  = bk * 256;
  const int nr  = (NNODES - r0 < 256) ? (NNODES - r0) : 256;
  const int* o = offs + (size_t)hop * (NNODES + 1);
  __shared__ int cur[257];
  for (int i = t; i <= nr; i += 256) cur[i] = o[r0 + i];
  __syncthreads();
  const int s = cur[0];
  const int e = cur[nr];          // never touched by atomics (rowlo < nr)
  __syncthreads();                // snapshot s,e before any cursor bumps
  const unsigned long long* src = staging + (size_t)hop * NEDGES;
  unsigned long long* dst       = ecsr + (size_t)hop * NEDGES;
  for (int i = s + t; i < e; i += 256) {
    const unsigned long long v = src[i];
    const unsigned lo = (unsigned)v;
    const int rl = (lo >> 16) & 255;
    const int d = atomicAdd(&cur[rl], 1);
    dst[d] = (v & 0xFFFFFFFF00000000ull) | (unsigned long long)(lo & 0xFFFFu);
  }
}

// ---------------------------------------------------------------------------
// Gather SpMM (ONE HOP per dispatch — sequential dispatches enforce the
// hb[k]/agg[k] slot-aliasing dependency).
// ---------------------------------------------------------------------------
__global__ __launch_bounds__(256) void gather_kernel(
    const int* __restrict__ offs, const int2* __restrict__ ecsr,
    const unsigned short* __restrict__ hb, unsigned short* __restrict__ aggb) {
  const int t    = threadIdx.x;
  const int lane = t & 63;
  const int wid  = t >> 6;
  const int r = blockIdx.x * 4 + wid;
  const int g  = lane >> 4;    // edge subgroup 0..3
  const int sl = lane & 15;    // feature slice: feats sl*8 .. sl*8+7
  const int s = offs[r];
  const int e = offs[r + 1];

  float acc[8];
#pragma unroll
  for (int j = 0; j < 8; ++j) acc[j] = 0.f;

  for (int p = s; p < e; p += 16) {
    int2 ed[4];
#pragma unroll
    for (int q = 0; q < 4; ++q) {
      const int idx = p + q * 4 + g;
      ed[q] = (idx < e) ? ecsr[idx] : make_int2(0, 0);
    }
    uint4 hv[4];
#pragma unroll
    for (int q = 0; q < 4; ++q)
      hv[q] = *(const uint4*)&hb[(size_t)ed[q].x * NH + sl * 8];
#pragma unroll
    for (int q = 0; q < 4; ++q) {
      const float v = __int_as_float(ed[q].y);
      acc[0] += v * bf2f_lo(hv[q].x);
      acc[1] += v * bf2f_hi(hv[q].x);
      acc[2] += v * bf2f_lo(hv[q].y);
      acc[3] += v * bf2f_hi(hv[q].y);
      acc[4] += v * bf2f_lo(hv[q].z);
      acc[5] += v * bf2f_hi(hv[q].z);
      acc[6] += v * bf2f_lo(hv[q].w);
      acc[7] += v * bf2f_hi(hv[q].w);
    }
  }

#pragma unroll
  for (int j = 0; j < 8; ++j) {
    acc[j] += __shfl_xor(acc[j], 16, 64);
    acc[j] += __shfl_xor(acc[j], 32, 64);
  }

  if (g == 0) {
    uint4 o;
    o.x = (unsigned)f2bf(acc[0]) | ((unsigned)f2bf(acc[1]) << 16);
    o.y = (unsigned)f2bf(acc[2]) | ((unsigned)f2bf(acc[3]) << 16);
    o.z = (unsigned)f2bf(acc[4]) | ((unsigned)f2bf(acc[5]) << 16);
    o.w = (unsigned)f2bf(acc[6]) | ((unsigned)f2bf(acc[7]) << 16);
    *(uint4*)&aggb[(size_t)r * NH + sl * 8] = o;
  }
}

// ---------------------------------------------------------------------------
// Output GEMM via MFMA: out[50000,64] = elu(concat) @ Wout + bout.
// 782 blocks x 4 waves, each wave 16 rows x 64 cols, K=512 in 16 steps.
// ELU applied in-register on bf16 A; B = wot (bf16 Wout^T). No LDS.
// ---------------------------------------------------------------------------
__global__ __launch_bounds__(256) void out2_kernel(
    const unsigned short* __restrict__ aggb,   // slots base; concat slots 0..3
    const unsigned short* __restrict__ wot,    // [64][512] bf16 Wout^T
    const float* __restrict__ bout, float* __restrict__ out) {
  const int t    = threadIdx.x;
  const int lane = t & 63;
  const int wave = t >> 6;
  const int l15  = lane & 15;
  const int quad = lane >> 4;
  const int m0   = blockIdx.x * 64 + wave * 16;   // 16 rows per wave

  facc_t acc[4];
#pragma unroll
  for (int ni = 0; ni < 4; ++ni) { facc_t z = {0.f,0.f,0.f,0.f}; acc[ni] = z; }

  const int mrow  = m0 + l15;
  const int mload = mrow < NNODES ? mrow : NNODES - 1;  // clamp; masked at store

#pragma unroll
  for (int ks = 0; ks < 16; ++ks) {
    const int f0  = ks * 32 + quad * 8;            // feature index 0..511
    const int hop = f0 >> 7;
    const int j0  = f0 & 127;
    uint4 ua = *(const uint4*)&aggb[((size_t)hop * NNODES + mload) * NH + j0];
    const unsigned uu[4] = {ua.x, ua.y, ua.z, ua.w};
    unsigned pr[4];
#pragma unroll
    for (int q = 0; q < 4; ++q) {
      float lo = bf2f_lo(uu[q]);
      float hi = bf2f_hi(uu[q]);
      lo = lo > 0.f ? lo : (expf(lo) - 1.f);
      hi = hi > 0.f ? hi : (expf(hi) - 1.f);
      pr[q] = (unsigned)f2bf(lo) | ((unsigned)f2bf(hi) << 16);
    }
    uint4 ra; ra.x = pr[0]; ra.y = pr[1]; ra.z = pr[2]; ra.w = pr[3];
    bfrag_t af = *(bfrag_t*)&ra;
    bfrag_t bf[4];
#pragma unroll
    for (int ni = 0; ni < 4; ++ni) {
      const int n = ni * 16 + l15;
      bf[ni] = *(const bfrag_t*)&wot[(size_t)n * 512 + f0];
    }
#pragma unroll
    for (int ni = 0; ni < 4; ++ni)
      acc[ni] = __builtin_amdgcn_mfma_f32_16x16x32_bf16(af, bf[ni], acc[ni], 0, 0, 0);
  }

#pragma unroll
  for (int ni = 0; ni < 4; ++ni) {
    const int o = ni * 16 + l15;
    const float bo = bout[o];
#pragma unroll
    for (int r = 0; r < 4; ++r) {
      const int m = m0 + quad * 4 + r;
      if (m < NNODES) out[(size_t)m * NO + o] = acc[ni][r] + bo;
    }
  }
}

// ---------------------------------------------------------------------------
extern "C" void kernel_launch(void* const* d_in, const int* in_sizes, int n_in,
                              void* d_out, int out_size, void* d_ws, size_t ws_size,
                              hipStream_t stream) {
  const float* x     = (const float*)d_in[0];
  const float* W     = (const float*)d_in[1];
  const float* b     = (const float*)d_in[2];
  const float* W_out = (const float*)d_in[3];
  const float* b_out = (const float*)d_in[4];
  const int*   erows = (const int*)d_in[5];
  const int*   ecols = (const int*)d_in[6];
  const float* evals = (const float*)d_in[7];
  float* out = (float*)d_out;

  // ws layout (bytes), total ~117e6 (<128e6 known-safe):
  //   slots: 5 x NNODES*NH bf16 = 64.0e6
  //   xb: NPAD*NF bf16 = 25.7e6  (REUSED as 25.6e6 staging after linear)
  //   Wt: 0.26e6 | ecsr: 25.6e6 | ints 1.6e6 | wot: 65.5e3
  unsigned short* slots = (unsigned short*)d_ws;
  unsigned short* xb = slots + (size_t)(NHOPS + 1) * NNODES * NH;
  unsigned short* Wt = xb + (size_t)NPAD * NF;
  unsigned long long* ecsr = (unsigned long long*)(Wt + (size_t)NHOPS * NH * NF);
  int* counts     = (int*)(ecsr + (size_t)NHOPS * NEDGES);
  int* offs       = counts + NHOPS * NNODES;
  int* bucketCur  = offs + NHOPS * (NNODES + 1);
  int* bucketBase = bucketCur + NHOPS * NB;
  unsigned short* wot = (unsigned short*)(bucketBase + NHOPS * (NB + 1));
  // staging aliases xb: xb is dead once linear_kernel has run.
  unsigned long long* staging = (unsigned long long*)xb;

  // bucketCur doubles as bucket-total accumulator for phaseA's hist1.
  hipMemsetAsync(bucketCur, 0, (size_t)NHOPS * NB * sizeof(int), stream);

  phaseA_kernel<<<CONVX_BLOCKS + CONVW_BLOCKS + HIST1_BLOCKS + WOT_BLOCKS,
                  256, 0, stream>>>(x, xb, W, Wt, erows, bucketCur, W_out, wot);
  scanB_kernel<<<NHOPS, 256, 0, stream>>>(bucketCur, bucketBase);
  linear_kernel<<<LIN_BLOCKS, 256, 0, stream>>>(xb, Wt, b, slots);
  bin_kernel<<<dim3(NB, NHOPS), 256, 0, stream>>>(
      erows, ecols, evals, bucketCur, staging);
  countscan_kernel<<<dim3(NB, NHOPS), 256, 0, stream>>>(
      bucketBase, staging, counts);
  scan_kernel<<<NHOPS, 1024, 0, stream>>>(counts, offs);
  place_kernel<<<dim3(NB, NHOPS), 256, 0, stream>>>(offs, staging, ecsr);

  for (int k = 0; k < NHOPS; ++k) {
    gather_kernel<<<NNODES / 4, 256, 0, stream>>>(
        offs + (size_t)k * (NNODES + 1), (const int2*)(ecsr + (size_t)k * NEDGES),
        slots + (size_t)(k + 1) * NNODES * NH,   // hb[k]
        slots + (size_t)k * NNODES * NH);        // agg[k]
  }

  out2_kernel<<<782, 256, 0, stream>>>(slots, wot, b_out, out);
}

// Round 10
// 441.867 us; speedup vs baseline: 2.0193x; 1.0467x over previous
//
#include <hip/hip_runtime.h>
#include <hip/hip_bf16.h>
#include <math.h>

#define NNODES 50000
#define NPAD   50176              // 392*128, padded rows for MFMA tile overrun
#define NEDGES 800000
#define NHOPS  4
#define NF     256
#define NH     128
#define NO     64
#define NB     196                // row buckets of 256 rows (50000/256 -> 196)
#define EPB    4096               // edges per bin block (256 thr x 16)

#define CONVX_BLOCKS 12500        // NNODES*NF/4/256
#define CONVW_BLOCKS 512          // NHOPS*NH*NF/256
#define HIST1_BLOCKS (NB * NHOPS) // 784: bucket-level LDS hist (R7)
#define WOT_BLOCKS   128          // 64*512/256 (Wout^T -> bf16)
#define LIN_PER_HOP  391          // ceil(NNODES/128)
#define LIN_BLOCKS   (LIN_PER_HOP * NHOPS)     // 1564
#define CPAD 132                  // LDS row stride (ushorts): quads 8 banks apart

typedef __attribute__((ext_vector_type(8))) short bfrag_t;   // 8 x bf16
typedef __attribute__((ext_vector_type(4))) float facc_t;    // 4 x f32

static __device__ __forceinline__ unsigned short f2bf(float f) {
  unsigned int u = __float_as_uint(f);
  unsigned int r = (u + 0x7fffu + ((u >> 16) & 1u)) >> 16;
  return (unsigned short)r;
}
static __device__ __forceinline__ float bf2f_lo(unsigned int u) {
  return __uint_as_float(u << 16);
}
static __device__ __forceinline__ float bf2f_hi(unsigned int u) {
  return __uint_as_float(u & 0xffff0000u);
}

// ---------------------------------------------------------------------------
// Phase A (fused): convx | convw | hist1 | wot. All independent.
// hist1: bucket-level LDS histogram (R7) — 154K global atomics into 3KB.
// ---------------------------------------------------------------------------
__global__ __launch_bounds__(256) void phaseA_kernel(
    const float* __restrict__ x, unsigned short* __restrict__ xb,
    const float* __restrict__ W, unsigned short* __restrict__ Wt,
    const int* __restrict__ erows, int* __restrict__ bucketCur,
    const float* __restrict__ Wout, unsigned short* __restrict__ wot) {
  const int bx = blockIdx.x;
  const int t  = threadIdx.x;
  if (bx < CONVX_BLOCKS) {
    const size_t i = ((size_t)bx * 256 + t) * 4;
    float4 v = *(const float4*)&x[i];
    ushort4 o;
    o.x = f2bf(v.x); o.y = f2bf(v.y); o.z = f2bf(v.z); o.w = f2bf(v.w);
    *(ushort4*)&xb[i] = o;
  } else if (bx < CONVX_BLOCKS + CONVW_BLOCKS) {
    const int i = (bx - CONVX_BLOCKS) * 256 + t;
    const int k = i / (NH * NF);
    const int rem = i - k * NH * NF;
    const int n = rem / NF;
    const int f = rem - n * NF;
    Wt[i] = f2bf(W[(size_t)k * NF * NH + (size_t)f * NH + n]);
  } else if (bx < CONVX_BLOCKS + CONVW_BLOCKS + HIST1_BLOCKS) {
    const int id  = bx - (CONVX_BLOCKS + CONVW_BLOCKS);
    const int hop = id / NB;
    const int bb  = (id - hop * NB) * EPB;
    __shared__ int bh[NB];
    for (int i = t; i < NB; i += 256) bh[i] = 0;
    __syncthreads();
    const size_t g0 = (size_t)hop * NEDGES;
#pragma unroll
    for (int k = 0; k < 4; ++k) {
      const int e0 = bb + t * 4 + k * 1024;
      if (e0 + 3 < NEDGES) {
        const int4 rr = *(const int4*)&erows[g0 + e0];
        atomicAdd(&bh[rr.x >> 8], 1);
        atomicAdd(&bh[rr.y >> 8], 1);
        atomicAdd(&bh[rr.z >> 8], 1);
        atomicAdd(&bh[rr.w >> 8], 1);
      } else {
        for (int j = 0; j < 4; ++j)
          if (e0 + j < NEDGES) atomicAdd(&bh[erows[g0 + e0 + j] >> 8], 1);
      }
    }
    __syncthreads();
    for (int i = t; i < NB; i += 256)
      if (bh[i]) atomicAdd(&bucketCur[hop * NB + i], bh[i]);
  } else {
    // Wout^T -> bf16: wot[o][f] = bf16(Wout[f][o]); reads coalesced.
    const int i = (bx - (CONVX_BLOCKS + CONVW_BLOCKS + HIST1_BLOCKS)) * 256 + t;
    const int o = i & 63;
    const int f = i >> 6;
    wot[(size_t)o * 512 + f] = f2bf(Wout[(size_t)f * NO + o]);
  }
}

// ---------------------------------------------------------------------------
// Per-hop exclusive scan of 196 bucket totals. bucketCur -> bases (bin's
// allocator); bucketBase immutable (countscan). bucketBase[b] == offs[b*256].
// ---------------------------------------------------------------------------
__global__ __launch_bounds__(256) void scanB_kernel(
    int* __restrict__ bucketCur, int* __restrict__ bucketBase) {
  const int hop = blockIdx.x;
  const int t   = threadIdx.x;
  __shared__ int tot[NB];
  for (int i = t; i < NB; i += 256) tot[i] = bucketCur[hop * NB + i];
  __syncthreads();
  if (t == 0) {
    int run = 0;
    for (int i = 0; i < NB; ++i) { const int c = tot[i]; tot[i] = run; run += c; }
  }
  __syncthreads();
  for (int i = t; i < NB; i += 256) {
    bucketCur[hop * NB + i]        = tot[i];
    bucketBase[hop * (NB + 1) + i] = tot[i];
  }
  if (t == 0) bucketBase[hop * (NB + 1) + NB] = NEDGES;
}

// ---------------------------------------------------------------------------
// Linear via MFMA, all 4 hops in one dispatch (1564 blocks).
// R9: LDS-staged coalesced epilogue. Old: scalar 2B stores -> 32B chunks
// per quad -> sub-line writes -> WRITE_SIZE 118MB (2.3x of the 51.2MB
// payload) + 26MB write-allocate refetch; kernel at 23% BW / 5% MfmaUtil.
// Now: acc -> bf16 -> LDS[128][132] (write phase bank-conflict-free:
// quads 8 banks apart), sync, then 16 threads/row stream uint4 stores —
// a wave writes 4 full 256B rows per instruction, all lines fully covered.
// ---------------------------------------------------------------------------
__global__ __launch_bounds__(256) void linear_kernel(
    const unsigned short* __restrict__ xb, const unsigned short* __restrict__ Wt,
    const float* __restrict__ b, unsigned short* __restrict__ slots) {
  const int lb  = blockIdx.x;
  const int hop = lb / LIN_PER_HOP;
  const int mb  = lb - hop * LIN_PER_HOP;
  const unsigned short* Wk = Wt + (size_t)hop * NH * NF;
  const float* bk = b + hop * NH;
  unsigned short* hb = slots + (size_t)(hop + 1) * NNODES * NH;

  const int t    = threadIdx.x;
  const int lane = t & 63;
  const int wave = t >> 6;
  const int wm   = (wave >> 1) * 64;
  const int wn   = (wave & 1) * 64;
  const int m0   = mb * 128;
  const int l15  = lane & 15;
  const int quad = lane >> 4;

  __shared__ unsigned short cs[128 * CPAD];

  facc_t acc[4][4];
#pragma unroll
  for (int i = 0; i < 4; ++i)
#pragma unroll
    for (int j = 0; j < 4; ++j) {
      facc_t z = {0.f, 0.f, 0.f, 0.f};
      acc[i][j] = z;
    }

#pragma unroll
  for (int k0 = 0; k0 < NF; k0 += 32) {
    bfrag_t a[4], bb[4];
#pragma unroll
    for (int mi = 0; mi < 4; ++mi) {
      const int m = m0 + wm + mi * 16 + l15;
      a[mi] = *(const bfrag_t*)&xb[(size_t)m * NF + k0 + quad * 8];
    }
#pragma unroll
    for (int ni = 0; ni < 4; ++ni) {
      const int n = wn + ni * 16 + l15;
      bb[ni] = *(const bfrag_t*)&Wk[(size_t)n * NF + k0 + quad * 8];
    }
#pragma unroll
    for (int mi = 0; mi < 4; ++mi)
#pragma unroll
      for (int ni = 0; ni < 4; ++ni)
        acc[mi][ni] = __builtin_amdgcn_mfma_f32_16x16x32_bf16(
            a[mi], bb[ni], acc[mi][ni], 0, 0, 0);
  }

  // ---- epilogue phase 1: bias + bf16 into LDS (conflict-free pattern) ----
#pragma unroll
  for (int ni = 0; ni < 4; ++ni) {
    const int nl = wn + ni * 16 + l15;
    const float bias = bk[nl];
#pragma unroll
    for (int mi = 0; mi < 4; ++mi) {
#pragma unroll
      for (int r = 0; r < 4; ++r) {
        const int ml = wm + mi * 16 + quad * 4 + r;
        cs[ml * CPAD + nl] = f2bf(acc[mi][ni][r] + bias);
      }
    }
  }
  __syncthreads();

  // ---- epilogue phase 2: coalesced full-line stores ----
  const int chunk = t & 15;          // 16B chunk within a 256B row
  const int rowb  = t >> 4;          // 16 rows per iteration
#pragma unroll
  for (int it = 0; it < 8; ++it) {
    const int row = it * 16 + rowb;
    const int m   = m0 + row;
    const uint4 v = *(const uint4*)&cs[row * CPAD + chunk * 8];
    if (m < NNODES) *(uint4*)&hb[(size_t)m * NH + chunk * 8] = v;
  }
}

// ---------------------------------------------------------------------------
// Bin pass: rank 4096 edges per block into 196 row-buckets via LDS hist;
// ONE global atomicAdd per (block,bucket) reserves space; edges written in
// ~21-entry contiguous runs into bucket-partitioned staging (aliases dead
// xb). pack: val(hi32) | rowlo<<16 | col. grid (196, NHOPS).
// ---------------------------------------------------------------------------
__global__ __launch_bounds__(256) void bin_kernel(
    const int* __restrict__ erows, const int* __restrict__ ecols,
    const float* __restrict__ evals, int* __restrict__ bucketCur,
    unsigned long long* __restrict__ staging) {
  const int hop = blockIdx.y;
  const int t   = threadIdx.x;
  const int bb  = blockIdx.x * EPB;
  __shared__ int lhist[NB];
  __shared__ int gbase[NB];
  for (int i = t; i < NB; i += 256) lhist[i] = 0;
  __syncthreads();

  unsigned long long pk[16];
  int bkt[16], rnk[16];
  const size_t g0 = (size_t)hop * NEDGES;
#pragma unroll
  for (int k = 0; k < 4; ++k) {
    const int e0 = bb + t * 4 + k * 1024;
    if (e0 + 3 < NEDGES) {
      const int4   rr = *(const int4*)&erows[g0 + e0];
      const int4   cc = *(const int4*)&ecols[g0 + e0];
      const float4 vv = *(const float4*)&evals[g0 + e0];
      const int r4[4] = {rr.x, rr.y, rr.z, rr.w};
      const int c4[4] = {cc.x, cc.y, cc.z, cc.w};
      const float v4[4] = {vv.x, vv.y, vv.z, vv.w};
#pragma unroll
      for (int j = 0; j < 4; ++j) {
        const int b = r4[j] >> 8;
        bkt[k * 4 + j] = b;
        rnk[k * 4 + j] = atomicAdd(&lhist[b], 1);
        pk[k * 4 + j] =
            ((unsigned long long)__float_as_uint(v4[j]) << 32) |
            ((unsigned)(r4[j] & 255) << 16) | (unsigned)c4[j];
      }
    } else {
#pragma unroll
      for (int j = 0; j < 4; ++j) {
        const int e = e0 + j;
        if (e < NEDGES) {
          const int r = erows[g0 + e];
          const int b = r >> 8;
          bkt[k * 4 + j] = b;
          rnk[k * 4 + j] = atomicAdd(&lhist[b], 1);
          pk[k * 4 + j] =
              ((unsigned long long)__float_as_uint(evals[g0 + e]) << 32) |
              ((unsigned)(r & 255) << 16) | (unsigned)ecols[g0 + e];
        } else {
          bkt[k * 4 + j] = -1;
        }
      }
    }
  }
  __syncthreads();
  for (int i = t; i < NB; i += 256) {
    const int c = lhist[i];
    gbase[i] = c ? atomicAdd(&bucketCur[hop * NB + i], c) : 0;
  }
  __syncthreads();
  unsigned long long* dst = staging + (size_t)hop * NEDGES;
#pragma unroll
  for (int q = 0; q < 16; ++q)
    if (bkt[q] >= 0) dst[gbase[bkt[q]] + rnk[q]] = pk[q];
}

// ---------------------------------------------------------------------------
// Per-row counts from staged edges: one block per (bucket,hop), LDS 256-bin
// histogram of rowlo, coalesced write to counts.
// ---------------------------------------------------------------------------
__global__ __launch_bounds__(256) void countscan_kernel(
    const int* __restrict__ bucketBase,
    const unsigned long long* __restrict__ staging, int* __restrict__ counts) {
  const int hop = blockIdx.y;
  const int b   = blockIdx.x;
  const int t   = threadIdx.x;
  const int s = bucketBase[hop * (NB + 1) + b];
  const int e = bucketBase[hop * (NB + 1) + b + 1];
  __shared__ int h[256];
  h[t] = 0;
  __syncthreads();
  const unsigned long long* src = staging + (size_t)hop * NEDGES;
  for (int i = s + t; i < e; i += 256) {
    const int rl = ((unsigned)src[i] >> 16) & 255;
    atomicAdd(&h[rl], 1);
  }
  __syncthreads();
  const int r0 = b * 256;
  if (r0 + t < NNODES) counts[hop * NNODES + r0 + t] = h[t];
}

// ---------------------------------------------------------------------------
// CSR build: exclusive scan per hop over per-row counts.
// ---------------------------------------------------------------------------
__global__ __launch_bounds__(1024) void scan_kernel(
    const int* __restrict__ counts, int* __restrict__ offs) {
  const int hop  = blockIdx.x;
  const int t    = threadIdx.x;
  const int lane = t & 63;
  const int wid  = t >> 6;
  __shared__ int wsum[16];
  __shared__ int carry_s;
  if (t == 0) carry_s = 0;
  __syncthreads();
  const int CH  = 8192;
  const int nch = (NNODES + CH - 1) / CH;     // 7
  for (int ch = 0; ch < nch; ++ch) {
    const int i0 = ch * CH + t * 8;
    int v[8];
    if (i0 + 7 < NNODES) {
      int4 a = *(const int4*)&counts[hop * NNODES + i0];
      int4 b = *(const int4*)&counts[hop * NNODES + i0 + 4];
      v[0]=a.x; v[1]=a.y; v[2]=a.z; v[3]=a.w;
      v[4]=b.x; v[5]=b.y; v[6]=b.z; v[7]=b.w;
    } else {
#pragma unroll
      for (int j = 0; j < 8; ++j)
        v[j] = (i0 + j < NNODES) ? counts[hop * NNODES + i0 + j] : 0;
    }
    int l[8];
    int run = 0;
#pragma unroll
    for (int j = 0; j < 8; ++j) { run += v[j]; l[j] = run; }   // inclusive
    int s = run;
#pragma unroll
    for (int d = 1; d < 64; d <<= 1) {
      int n = __shfl_up(s, d, 64);
      if (lane >= d) s += n;
    }
    if (lane == 63) wsum[wid] = s;
    __syncthreads();
    if (t < 16) {
      int ws = wsum[t];
#pragma unroll
      for (int d = 1; d < 16; d <<= 1) {
        int n = __shfl_up(ws, d, 16);
        if (t >= d) ws += n;
      }
      wsum[t] = ws;
    }
    __syncthreads();
    const int base = carry_s + (wid ? wsum[wid - 1] : 0) + (s - run);
    if (i0 + 7 < NNODES) {
      int4 o0 = make_int4(base, base + l[0], base + l[1], base + l[2]);
      int4 o1 = make_int4(base + l[3], base + l[4], base + l[5], base + l[6]);
      *(int4*)&offs[hop * (NNODES + 1) + i0]     = o0;
      *(int4*)&offs[hop * (NNODES + 1) + i0 + 4] = o1;
    } else {
#pragma unroll
      for (int j = 0; j < 8; ++j) {
        if (i0 + j < NNODES) {
          const int excl = base + (l[j] - v[j]);
          offs[hop * (NNODES + 1) + i0 + j] = excl;
        }
      }
    }
    __syncthreads();
    if (t == 0) carry_s += wsum[15];
    __syncthreads();
  }
  if (t == 0) offs[hop * (NNODES + 1) + NNODES] = carry_s;
}

// ---------------------------------------------------------------------------
// Place pass: one block per (bucket,hop). Sequential read of the bucket's
// staging segment; exact CSR position via LDS row cursors (no global
// atomics). All writes land in this block's own 32KB window.
// ---------------------------------------------------------------------------
__global__ __launch_bounds__(256) void place_kernel(
    const int* __restrict__ offs, const unsigned long long* __restrict__ staging,
    unsigned long long* __restrict__ ecsr) {
  const int hop = blockIdx.y;
  const int bk  = blockIdx.x;
  const int t   = threadIdx.x;
  const int r0  = bk * 256;
  const int nr  = (NNODES - r0 < 256) ? (NNODES - r0) : 256;
  const int* o = offs + (size_t)hop * (NNODES + 1);
  __shared__ int cur[257];
  for (int i = t; i <= nr; i += 256) cur[i] = o[r0 + i];
  __syncthreads();
  const int s = cur[0];
  const int e = cur[nr];          // never touched by atomics (rowlo < nr)
  __syncthreads();                // snapshot s,e before any cursor bumps
  const unsigned long long* src = staging + (size_t)hop * NEDGES;
  unsigned long long* dst       = ecsr + (size_t)hop * NEDGES;
  for (int i = s + t; i < e; i += 256) {
    const unsigned long long v = src[i];
    const unsigned lo = (unsigned)v;
    const int rl = (lo >> 16) & 255;
    const int d = atomicAdd(&cur[rl], 1);
    dst[d] = (v & 0xFFFFFFFF00000000ull) | (unsigned long long)(lo & 0xFFFFu);
  }
}

// ---------------------------------------------------------------------------
// Gather SpMM (ONE HOP per dispatch — sequential dispatches enforce the
// hb[k]/agg[k] slot-aliasing dependency).
// ---------------------------------------------------------------------------
__global__ __launch_bounds__(256) void gather_kernel(
    const int* __restrict__ offs, const int2* __restrict__ ecsr,
    const unsigned short* __restrict__ hb, unsigned short* __restrict__ aggb) {
  const int t    = threadIdx.x;
  const int lane = t & 63;
  const int wid  = t >> 6;
  const int r = blockIdx.x * 4 + wid;
  const int g  = lane >> 4;    // edge subgroup 0..3
  const int sl = lane & 15;    // feature slice: feats sl*8 .. sl*8+7
  const int s = offs[r];
  const int e = offs[r + 1];

  float acc[8];
#pragma unroll
  for (int j = 0; j < 8; ++j) acc[j] = 0.f;

  for (int p = s; p < e; p += 16) {
    int2 ed[4];
#pragma unroll
    for (int q = 0; q < 4; ++q) {
      const int idx = p + q * 4 + g;
      ed[q] = (idx < e) ? ecsr[idx] : make_int2(0, 0);
    }
    uint4 hv[4];
#pragma unroll
    for (int q = 0; q < 4; ++q)
      hv[q] = *(const uint4*)&hb[(size_t)ed[q].x * NH + sl * 8];
#pragma unroll
    for (int q = 0; q < 4; ++q) {
      const float v = __int_as_float(ed[q].y);
      acc[0] += v * bf2f_lo(hv[q].x);
      acc[1] += v * bf2f_hi(hv[q].x);
      acc[2] += v * bf2f_lo(hv[q].y);
      acc[3] += v * bf2f_hi(hv[q].y);
      acc[4] += v * bf2f_lo(hv[q].z);
      acc[5] += v * bf2f_hi(hv[q].z);
      acc[6] += v * bf2f_lo(hv[q].w);
      acc[7] += v * bf2f_hi(hv[q].w);
    }
  }

#pragma unroll
  for (int j = 0; j < 8; ++j) {
    acc[j] += __shfl_xor(acc[j], 16, 64);
    acc[j] += __shfl_xor(acc[j], 32, 64);
  }

  if (g == 0) {
    uint4 o;
    o.x = (unsigned)f2bf(acc[0]) | ((unsigned)f2bf(acc[1]) << 16);
    o.y = (unsigned)f2bf(acc[2]) | ((unsigned)f2bf(acc[3]) << 16);
    o.z = (unsigned)f2bf(acc[4]) | ((unsigned)f2bf(acc[5]) << 16);
    o.w = (unsigned)f2bf(acc[6]) | ((unsigned)f2bf(acc[7]) << 16);
    *(uint4*)&aggb[(size_t)r * NH + sl * 8] = o;
  }
}

// ---------------------------------------------------------------------------
// Output GEMM via MFMA: out[50000,64] = elu(concat) @ Wout + bout.
// 782 blocks x 4 waves, each wave 16 rows x 64 cols, K=512 in 16 steps.
// ---------------------------------------------------------------------------
__global__ __launch_bounds__(256) void out2_kernel(
    const unsigned short* __restrict__ aggb,   // slots base; concat slots 0..3
    const unsigned short* __restrict__ wot,    // [64][512] bf16 Wout^T
    const float* __restrict__ bout, float* __restrict__ out) {
  const int t    = threadIdx.x;
  const int lane = t & 63;
  const int wave = t >> 6;
  const int l15  = lane & 15;
  const int quad = lane >> 4;
  const int m0   = blockIdx.x * 64 + wave * 16;   // 16 rows per wave

  facc_t acc[4];
#pragma unroll
  for (int ni = 0; ni < 4; ++ni) { facc_t z = {0.f,0.f,0.f,0.f}; acc[ni] = z; }

  const int mrow  = m0 + l15;
  const int mload = mrow < NNODES ? mrow : NNODES - 1;  // clamp; masked at store

#pragma unroll
  for (int ks = 0; ks < 16; ++ks) {
    const int f0  = ks * 32 + quad * 8;            // feature index 0..511
    const int hop = f0 >> 7;
    const int j0  = f0 & 127;
    uint4 ua = *(const uint4*)&aggb[((size_t)hop * NNODES + mload) * NH + j0];
    const unsigned uu[4] = {ua.x, ua.y, ua.z, ua.w};
    unsigned pr[4];
#pragma unroll
    for (int q = 0; q < 4; ++q) {
      float lo = bf2f_lo(uu[q]);
      float hi = bf2f_hi(uu[q]);
      lo = lo > 0.f ? lo : (expf(lo) - 1.f);
      hi = hi > 0.f ? hi : (expf(hi) - 1.f);
      pr[q] = (unsigned)f2bf(lo) | ((unsigned)f2bf(hi) << 16);
    }
    uint4 ra; ra.x = pr[0]; ra.y = pr[1]; ra.z = pr[2]; ra.w = pr[3];
    bfrag_t af = *(bfrag_t*)&ra;
    bfrag_t bf[4];
#pragma unroll
    for (int ni = 0; ni < 4; ++ni) {
      const int n = ni * 16 + l15;
      bf[ni] = *(const bfrag_t*)&wot[(size_t)n * 512 + f0];
    }
#pragma unroll
    for (int ni = 0; ni < 4; ++ni)
      acc[ni] = __builtin_amdgcn_mfma_f32_16x16x32_bf16(af, bf[ni], acc[ni], 0, 0, 0);
  }

#pragma unroll
  for (int ni = 0; ni < 4; ++ni) {
    const int o = ni * 16 + l15;
    const float bo = bout[o];
#pragma unroll
    for (int r = 0; r < 4; ++r) {
      const int m = m0 + quad * 4 + r;
      if (m < NNODES) out[(size_t)m * NO + o] = acc[ni][r] + bo;
    }
  }
}

// ---------------------------------------------------------------------------
extern "C" void kernel_launch(void* const* d_in, const int* in_sizes, int n_in,
                              void* d_out, int out_size, void* d_ws, size_t ws_size,
                              hipStream_t stream) {
  const float* x     = (const float*)d_in[0];
  const float* W     = (const float*)d_in[1];
  const float* b     = (const float*)d_in[2];
  const float* W_out = (const float*)d_in[3];
  const float* b_out = (const float*)d_in[4];
  const int*   erows = (const int*)d_in[5];
  const int*   ecols = (const int*)d_in[6];
  const float* evals = (const float*)d_in[7];
  float* out = (float*)d_out;

  // ws layout (bytes), total ~117e6 (<128e6 known-safe):
  //   slots: 5 x NNODES*NH bf16 = 64.0e6
  //   xb: NPAD*NF bf16 = 25.7e6  (REUSED as 25.6e6 staging after linear)
  //   Wt: 0.26e6 | ecsr: 25.6e6 | ints 1.6e6 | wot: 65.5e3
  unsigned short* slots = (unsigned short*)d_ws;
  unsigned short* xb = slots + (size_t)(NHOPS + 1) * NNODES * NH;
  unsigned short* Wt = xb + (size_t)NPAD * NF;
  unsigned long long* ecsr = (unsigned long long*)(Wt + (size_t)NHOPS * NH * NF);
  int* counts     = (int*)(ecsr + (size_t)NHOPS * NEDGES);
  int* offs       = counts + NHOPS * NNODES;
  int* bucketCur  = offs + NHOPS * (NNODES + 1);
  int* bucketBase = bucketCur + NHOPS * NB;
  unsigned short* wot = (unsigned short*)(bucketBase + NHOPS * (NB + 1));
  // staging aliases xb: xb is dead once linear_kernel has run.
  unsigned long long* staging = (unsigned long long*)xb;

  // bucketCur doubles as bucket-total accumulator for phaseA's hist1.
  hipMemsetAsync(bucketCur, 0, (size_t)NHOPS * NB * sizeof(int), stream);

  phaseA_kernel<<<CONVX_BLOCKS + CONVW_BLOCKS + HIST1_BLOCKS + WOT_BLOCKS,
                  256, 0, stream>>>(x, xb, W, Wt, erows, bucketCur, W_out, wot);
  scanB_kernel<<<NHOPS, 256, 0, stream>>>(bucketCur, bucketBase);
  linear_kernel<<<LIN_BLOCKS, 256, 0, stream>>>(xb, Wt, b, slots);
  bin_kernel<<<dim3(NB, NHOPS), 256, 0, stream>>>(
      erows, ecols, evals, bucketCur, staging);
  countscan_kernel<<<dim3(NB, NHOPS), 256, 0, stream>>>(
      bucketBase, staging, counts);
  scan_kernel<<<NHOPS, 1024, 0, stream>>>(counts, offs);
  place_kernel<<<dim3(NB, NHOPS), 256, 0, stream>>>(offs, staging, ecsr);

  for (int k = 0; k < NHOPS; ++k) {
    gather_kernel<<<NNODES / 4, 256, 0, stream>>>(
        offs + (size_t)k * (NNODES + 1), (const int2*)(ecsr + (size_t)k * NEDGES),
        slots + (size_t)(k + 1) * NNODES * NH,   // hb[k]
        slots + (size_t)k * NNODES * NH);        // agg[k]
  }

  out2_kernel<<<782, 256, 0, stream>>>(slots, wot, b_out, out);
}

// Round 13
// 440.445 us; speedup vs baseline: 2.0258x; 1.0032x over previous
//
#include <hip/hip_runtime.h>
#include <hip/hip_bf16.h>
#include <math.h>

#define NNODES 50000
#define NPAD   50176              // 392*128, padded rows for MFMA tile overrun
#define NEDGES 800000
#define NHOPS  4
#define NF     256
#define NH     128
#define NO     64
#define NB     196                // row buckets of 256 rows (50000/256 -> 196)
#define EPB    4096               // edges per bin block (256 thr x 16)

#define CONVX_BLOCKS 12500        // NNODES*NF/4/256
#define CONVW_BLOCKS 512          // NHOPS*NH*NF/256
#define HIST1_BLOCKS (NB * NHOPS) // 784: bucket-level LDS hist (R7)
#define WOT_BLOCKS   128          // 64*512/256 (Wout^T -> bf16)
#define LIN_PER_HOP  391          // ceil(NNODES/128)
#define LIN_BLOCKS   (LIN_PER_HOP * NHOPS)     // 1564
#define ASTR 40                   // A-stage LDS row stride (ushorts)
#define CPAD 132                  // epilogue LDS row stride (ushorts)

typedef __attribute__((ext_vector_type(8))) short bfrag_t;   // 8 x bf16
typedef __attribute__((ext_vector_type(4))) float facc_t;    // 4 x f32

static __device__ __forceinline__ unsigned short f2bf(float f) {
  unsigned int u = __float_as_uint(f);
  unsigned int r = (u + 0x7fffu + ((u >> 16) & 1u)) >> 16;
  return (unsigned short)r;
}
static __device__ __forceinline__ float bf2f_lo(unsigned int u) {
  return __uint_as_float(u << 16);
}
static __device__ __forceinline__ float bf2f_hi(unsigned int u) {
  return __uint_as_float(u & 0xffff0000u);
}

// ---------------------------------------------------------------------------
// Phase A (fused): convx | convw | hist1 | wot. All independent.
// hist1: bucket-level LDS histogram (R7) — 154K global atomics into 3KB.
// ---------------------------------------------------------------------------
__global__ __launch_bounds__(256) void phaseA_kernel(
    const float* __restrict__ x, unsigned short* __restrict__ xb,
    const float* __restrict__ W, unsigned short* __restrict__ Wt,
    const int* __restrict__ erows, int* __restrict__ bucketCur,
    const float* __restrict__ Wout, unsigned short* __restrict__ wot) {
  const int bx = blockIdx.x;
  const int t  = threadIdx.x;
  if (bx < CONVX_BLOCKS) {
    const size_t i = ((size_t)bx * 256 + t) * 4;
    float4 v = *(const float4*)&x[i];
    ushort4 o;
    o.x = f2bf(v.x); o.y = f2bf(v.y); o.z = f2bf(v.z); o.w = f2bf(v.w);
    *(ushort4*)&xb[i] = o;
  } else if (bx < CONVX_BLOCKS + CONVW_BLOCKS) {
    const int i = (bx - CONVX_BLOCKS) * 256 + t;
    const int k = i / (NH * NF);
    const int rem = i - k * NH * NF;
    const int n = rem / NF;
    const int f = rem - n * NF;
    Wt[i] = f2bf(W[(size_t)k * NF * NH + (size_t)f * NH + n]);
  } else if (bx < CONVX_BLOCKS + CONVW_BLOCKS + HIST1_BLOCKS) {
    const int id  = bx - (CONVX_BLOCKS + CONVW_BLOCKS);
    const int hop = id / NB;
    const int bb  = (id - hop * NB) * EPB;
    __shared__ int bh[NB];
    for (int i = t; i < NB; i += 256) bh[i] = 0;
    __syncthreads();
    const size_t g0 = (size_t)hop * NEDGES;
#pragma unroll
    for (int k = 0; k < 4; ++k) {
      const int e0 = bb + t * 4 + k * 1024;
      if (e0 + 3 < NEDGES) {
        const int4 rr = *(const int4*)&erows[g0 + e0];
        atomicAdd(&bh[rr.x >> 8], 1);
        atomicAdd(&bh[rr.y >> 8], 1);
        atomicAdd(&bh[rr.z >> 8], 1);
        atomicAdd(&bh[rr.w >> 8], 1);
      } else {
        for (int j = 0; j < 4; ++j)
          if (e0 + j < NEDGES) atomicAdd(&bh[erows[g0 + e0 + j] >> 8], 1);
      }
    }
    __syncthreads();
    for (int i = t; i < NB; i += 256)
      if (bh[i]) atomicAdd(&bucketCur[hop * NB + i], bh[i]);
  } else {
    // Wout^T -> bf16: wot[o][f] = bf16(Wout[f][o]); reads coalesced.
    const int i = (bx - (CONVX_BLOCKS + CONVW_BLOCKS + HIST1_BLOCKS)) * 256 + t;
    const int o = i & 63;
    const int f = i >> 6;
    wot[(size_t)o * 512 + f] = f2bf(Wout[(size_t)f * NO + o]);
  }
}

// ---------------------------------------------------------------------------
// Per-hop exclusive scan of 196 bucket totals. bucketCur -> bases (bin's
// allocator); bucketBase immutable (countscan). bucketBase[b] == offs[b*256].
// ---------------------------------------------------------------------------
__global__ __launch_bounds__(256) void scanB_kernel(
    int* __restrict__ bucketCur, int* __restrict__ bucketBase) {
  const int hop = blockIdx.x;
  const int t   = threadIdx.x;
  __shared__ int tot[NB];
  for (int i = t; i < NB; i += 256) tot[i] = bucketCur[hop * NB + i];
  __syncthreads();
  if (t == 0) {
    int run = 0;
    for (int i = 0; i < NB; ++i) { const int c = tot[i]; tot[i] = run; run += c; }
  }
  __syncthreads();
  for (int i = t; i < NB; i += 256) {
    bucketCur[hop * NB + i]        = tot[i];
    bucketBase[hop * (NB + 1) + i] = tot[i];
  }
  if (t == 0) bucketBase[hop * (NB + 1) + NB] = NEDGES;
}

// ---------------------------------------------------------------------------
// Linear via MFMA, all 4 hops in one dispatch (1564 blocks).
// R10: (a) A-tile LDS staging per k-step — R9 counters showed FETCH 52MB =
// 2x ideal because both N-waves (wn=0,64) re-read the same xb rows and the
// reuse distance exceeded L2 under ~100 streaming blocks/XCD. One shared
// stage -> xb read once. (b) half-tile epilogue (64 rows/pass) + LDS union
// with the A-stage -> LDS 33.8 -> 20.5KB -> more blocks/CU (was 2, 25.8%
// occupancy, 1.69 TB/s effective).
// ---------------------------------------------------------------------------
__global__ __launch_bounds__(256) void linear_kernel(
    const unsigned short* __restrict__ xb, const unsigned short* __restrict__ Wt,
    const float* __restrict__ b, unsigned short* __restrict__ slots) {
  const int lb  = blockIdx.x;
  const int hop = lb / LIN_PER_HOP;
  const int mb  = lb - hop * LIN_PER_HOP;
  const unsigned short* Wk = Wt + (size_t)hop * NH * NF;
  const float* bk = b + hop * NH;
  unsigned short* hb = slots + (size_t)(hop + 1) * NNODES * NH;

  const int t    = threadIdx.x;
  const int lane = t & 63;
  const int wave = t >> 6;
  const int wm   = (wave >> 1) * 64;
  const int wn   = (wave & 1) * 64;
  const int m0   = mb * 128;
  const int l15  = lane & 15;
  const int quad = lane >> 4;

  // union: as_[128][ASTR] during k-loop / cs[64][CPAD] epilogue
  __shared__ unsigned short smem[10240];
  unsigned short* as_ = smem;
  unsigned short* cs  = smem;

  facc_t acc[4][4];
#pragma unroll
  for (int i = 0; i < 4; ++i)
#pragma unroll
    for (int j = 0; j < 4; ++j) {
      facc_t z = {0.f, 0.f, 0.f, 0.f};
      acc[i][j] = z;
    }

#pragma unroll
  for (int k0 = 0; k0 < NF; k0 += 32) {
    __syncthreads();   // previous iteration's as_ reads complete
    // stage A: 128 rows x 32 cols (64B/row); thread t: row t>>2, 16B chunk t&3
#pragma unroll
    for (int it = 0; it < 2; ++it) {
      const int row = it * 64 + (t >> 2);
      const int ch  = t & 3;
      const uint4 v = *(const uint4*)&xb[(size_t)(m0 + row) * NF + k0 + ch * 8];
      *(uint4*)&as_[row * ASTR + ch * 8] = v;
    }
    __syncthreads();

    bfrag_t a[4], bb[4];
#pragma unroll
    for (int mi = 0; mi < 4; ++mi)
      a[mi] = *(const bfrag_t*)&as_[(wm + mi * 16 + l15) * ASTR + quad * 8];
#pragma unroll
    for (int ni = 0; ni < 4; ++ni) {
      const int n = wn + ni * 16 + l15;
      bb[ni] = *(const bfrag_t*)&Wk[(size_t)n * NF + k0 + quad * 8];
    }
#pragma unroll
    for (int mi = 0; mi < 4; ++mi)
#pragma unroll
      for (int ni = 0; ni < 4; ++ni)
        acc[mi][ni] = __builtin_amdgcn_mfma_f32_16x16x32_bf16(
            a[mi], bb[ni], acc[mi][ni], 0, 0, 0);
  }

  // ---- epilogue: two 64-row halves through cs[64][CPAD] ----
#pragma unroll
  for (int half = 0; half < 2; ++half) {
    __syncthreads();
    if ((wave >> 1) == half) {
#pragma unroll
      for (int ni = 0; ni < 4; ++ni) {
        const int nl = wn + ni * 16 + l15;
        const float bias = bk[nl];
#pragma unroll
        for (int mi = 0; mi < 4; ++mi) {
#pragma unroll
          for (int r = 0; r < 4; ++r) {
            const int ml = mi * 16 + quad * 4 + r;   // 0..63 within half
            cs[ml * CPAD + nl] = f2bf(acc[mi][ni][r] + bias);
          }
        }
      }
    }
    __syncthreads();
    const int chunk = t & 15;          // 16B chunk within a 256B row
    const int rowb  = t >> 4;          // 16 rows per iteration
#pragma unroll
    for (int it = 0; it < 4; ++it) {
      const int row = it * 16 + rowb;
      const int m   = m0 + half * 64 + row;
      const uint4 v = *(const uint4*)&cs[row * CPAD + chunk * 8];
      if (m < NNODES) *(uint4*)&hb[(size_t)m * NH + chunk * 8] = v;
    }
  }
}

// ---------------------------------------------------------------------------
// Bin pass: rank 4096 edges per block into 196 row-buckets via LDS hist;
// ONE global atomicAdd per (block,bucket) reserves space; edges written in
// ~21-entry contiguous runs into bucket-partitioned staging (aliases dead
// xb). pack: val(hi32) | rowlo<<16 | col. grid (196, NHOPS).
// ---------------------------------------------------------------------------
__global__ __launch_bounds__(256) void bin_kernel(
    const int* __restrict__ erows, const int* __restrict__ ecols,
    const float* __restrict__ evals, int* __restrict__ bucketCur,
    unsigned long long* __restrict__ staging) {
  const int hop = blockIdx.y;
  const int t   = threadIdx.x;
  const int bb  = blockIdx.x * EPB;
  __shared__ int lhist[NB];
  __shared__ int gbase[NB];
  for (int i = t; i < NB; i += 256) lhist[i] = 0;
  __syncthreads();

  unsigned long long pk[16];
  int bkt[16], rnk[16];
  const size_t g0 = (size_t)hop * NEDGES;
#pragma unroll
  for (int k = 0; k < 4; ++k) {
    const int e0 = bb + t * 4 + k * 1024;
    if (e0 + 3 < NEDGES) {
      const int4   rr = *(const int4*)&erows[g0 + e0];
      const int4   cc = *(const int4*)&ecols[g0 + e0];
      const float4 vv = *(const float4*)&evals[g0 + e0];
      const int r4[4] = {rr.x, rr.y, rr.z, rr.w};
      const int c4[4] = {cc.x, cc.y, cc.z, cc.w};
      const float v4[4] = {vv.x, vv.y, vv.z, vv.w};
#pragma unroll
      for (int j = 0; j < 4; ++j) {
        const int b = r4[j] >> 8;
        bkt[k * 4 + j] = b;
        rnk[k * 4 + j] = atomicAdd(&lhist[b], 1);
        pk[k * 4 + j] =
            ((unsigned long long)__float_as_uint(v4[j]) << 32) |
            ((unsigned)(r4[j] & 255) << 16) | (unsigned)c4[j];
      }
    } else {
#pragma unroll
      for (int j = 0; j < 4; ++j) {
        const int e = e0 + j;
        if (e < NEDGES) {
          const int r = erows[g0 + e];
          const int b = r >> 8;
          bkt[k * 4 + j] = b;
          rnk[k * 4 + j] = atomicAdd(&lhist[b], 1);
          pk[k * 4 + j] =
              ((unsigned long long)__float_as_uint(evals[g0 + e]) << 32) |
              ((unsigned)(r & 255) << 16) | (unsigned)ecols[g0 + e];
        } else {
          bkt[k * 4 + j] = -1;
        }
      }
    }
  }
  __syncthreads();
  for (int i = t; i < NB; i += 256) {
    const int c = lhist[i];
    gbase[i] = c ? atomicAdd(&bucketCur[hop * NB + i], c) : 0;
  }
  __syncthreads();
  unsigned long long* dst = staging + (size_t)hop * NEDGES;
#pragma unroll
  for (int q = 0; q < 16; ++q)
    if (bkt[q] >= 0) dst[gbase[bkt[q]] + rnk[q]] = pk[q];
}

// ---------------------------------------------------------------------------
// Per-row counts from staged edges: one block per (bucket,hop), LDS 256-bin
// histogram of rowlo, coalesced write to counts.
// ---------------------------------------------------------------------------
__global__ __launch_bounds__(256) void countscan_kernel(
    const int* __restrict__ bucketBase,
    const unsigned long long* __restrict__ staging, int* __restrict__ counts) {
  const int hop = blockIdx.y;
  const int b   = blockIdx.x;
  const int t   = threadIdx.x;
  const int s = bucketBase[hop * (NB + 1) + b];
  const int e = bucketBase[hop * (NB + 1) + b + 1];
  __shared__ int h[256];
  h[t] = 0;
  __syncthreads();
  const unsigned long long* src = staging + (size_t)hop * NEDGES;
  for (int i = s + t; i < e; i += 256) {
    const int rl = ((unsigned)src[i] >> 16) & 255;
    atomicAdd(&h[rl], 1);
  }
  __syncthreads();
  const int r0 = b * 256;
  if (r0 + t < NNODES) counts[hop * NNODES + r0 + t] = h[t];
}

// ---------------------------------------------------------------------------
// CSR build: exclusive scan per hop over per-row counts.
// ---------------------------------------------------------------------------
__global__ __launch_bounds__(1024) void scan_kernel(
    const int* __restrict__ counts, int* __restrict__ offs) {
  const int hop  = blockIdx.x;
  const int t    = threadIdx.x;
  const int lane = t & 63;
  const int wid  = t >> 6;
  __shared__ int wsum[16];
  __shared__ int carry_s;
  if (t == 0) carry_s = 0;
  __syncthreads();
  const int CH  = 8192;
  const int nch = (NNODES + CH - 1) / CH;     // 7
  for (int ch = 0; ch < nch; ++ch) {
    const int i0 = ch * CH + t * 8;
    int v[8];
    if (i0 + 7 < NNODES) {
      int4 a = *(const int4*)&counts[hop * NNODES + i0];
      int4 b = *(const int4*)&counts[hop * NNODES + i0 + 4];
      v[0]=a.x; v[1]=a.y; v[2]=a.z; v[3]=a.w;
      v[4]=b.x; v[5]=b.y; v[6]=b.z; v[7]=b.w;
    } else {
#pragma unroll
      for (int j = 0; j < 8; ++j)
        v[j] = (i0 + j < NNODES) ? counts[hop * NNODES + i0 + j] : 0;
    }
    int l[8];
    int run = 0;
#pragma unroll
    for (int j = 0; j < 8; ++j) { run += v[j]; l[j] = run; }   // inclusive
    int s = run;
#pragma unroll
    for (int d = 1; d < 64; d <<= 1) {
      int n = __shfl_up(s, d, 64);
      if (lane >= d) s += n;
    }
    if (lane == 63) wsum[wid] = s;
    __syncthreads();
    if (t < 16) {
      int ws = wsum[t];
#pragma unroll
      for (int d = 1; d < 16; d <<= 1) {
        int n = __shfl_up(ws, d, 16);
        if (t >= d) ws += n;
      }
      wsum[t] = ws;
    }
    __syncthreads();
    const int base = carry_s + (wid ? wsum[wid - 1] : 0) + (s - run);
    if (i0 + 7 < NNODES) {
      int4 o0 = make_int4(base, base + l[0], base + l[1], base + l[2]);
      int4 o1 = make_int4(base + l[3], base + l[4], base + l[5], base + l[6]);
      *(int4*)&offs[hop * (NNODES + 1) + i0]     = o0;
      *(int4*)&offs[hop * (NNODES + 1) + i0 + 4] = o1;
    } else {
#pragma unroll
      for (int j = 0; j < 8; ++j) {
        if (i0 + j < NNODES) {
          const int excl = base + (l[j] - v[j]);
          offs[hop * (NNODES + 1) + i0 + j] = excl;
        }
      }
    }
    __syncthreads();
    if (t == 0) carry_s += wsum[15];
    __syncthreads();
  }
  if (t == 0) offs[hop * (NNODES + 1) + NNODES] = carry_s;
}

// ---------------------------------------------------------------------------
// Place pass: one block per (bucket,hop). Sequential read of the bucket's
// staging segment; exact CSR position via LDS row cursors (no global
// atomics). All writes land in this block's own 32KB window.
// ---------------------------------------------------------------------------
__global__ __launch_bounds__(256) void place_kernel(
    const int* __restrict__ offs, const unsigned long long* __restrict__ staging,
    unsigned long long* __restrict__ ecsr) {
  const int hop = blockIdx.y;
  const int bk  = blockIdx.x;
  const int t   = threadIdx.x;
  const int r0  = bk * 256;
  const int nr  = (NNODES - r0 < 256) ? (NNODES - r0) : 256;
  const int* o = offs + (size_t)hop * (NNODES + 1);
  __shared__ int cur[257];
  for (int i = t; i <= nr; i += 256) cur[i] = o[r0 + i];
  __syncthreads();
  const int s = cur[0];
  const int e = cur[nr];          // never touched by atomics (rowlo < nr)
  __syncthreads();                // snapshot s,e before any cursor bumps
  const unsigned long long* src = staging + (size_t)hop * NEDGES;
  unsigned long long* dst       = ecsr + (size_t)hop * NEDGES;
  for (int i = s + t; i < e; i += 256) {
    const unsigned long long v = src[i];
    const unsigned lo = (unsigned)v;
    const int rl = (lo >> 16) & 255;
    const int d = atomicAdd(&cur[rl], 1);
    dst[d] = (v & 0xFFFFFFFF00000000ull) | (unsigned long long)(lo & 0xFFFFu);
  }
}

// ---------------------------------------------------------------------------
// Gather SpMM (ONE HOP per dispatch — sequential dispatches enforce the
// hb[k]/agg[k] slot-aliasing dependency).
// ---------------------------------------------------------------------------
__global__ __launch_bounds__(256) void gather_kernel(
    const int* __restrict__ offs, const int2* __restrict__ ecsr,
    const unsigned short* __restrict__ hb, unsigned short* __restrict__ aggb) {
  const int t    = threadIdx.x;
  const int lane = t & 63;
  const int wid  = t >> 6;
  const int r = blockIdx.x * 4 + wid;
  const int g  = lane >> 4;    // edge subgroup 0..3
  const int sl = lane & 15;    // feature slice: feats sl*8 .. sl*8+7
  const int s = offs[r];
  const int e = offs[r + 1];

  float acc[8];
#pragma unroll
  for (int j = 0; j < 8; ++j) acc[j] = 0.f;

  for (int p = s; p < e; p += 16) {
    int2 ed[4];
#pragma unroll
    for (int q = 0; q < 4; ++q) {
      const int idx = p + q * 4 + g;
      ed[q] = (idx < e) ? ecsr[idx] : make_int2(0, 0);
    }
    uint4 hv[4];
#pragma unroll
    for (int q = 0; q < 4; ++q)
      hv[q] = *(const uint4*)&hb[(size_t)ed[q].x * NH + sl * 8];
#pragma unroll
    for (int q = 0; q < 4; ++q) {
      const float v = __int_as_float(ed[q].y);
      acc[0] += v * bf2f_lo(hv[q].x);
      acc[1] += v * bf2f_hi(hv[q].x);
      acc[2] += v * bf2f_lo(hv[q].y);
      acc[3] += v * bf2f_hi(hv[q].y);
      acc[4] += v * bf2f_lo(hv[q].z);
      acc[5] += v * bf2f_hi(hv[q].z);
      acc[6] += v * bf2f_lo(hv[q].w);
      acc[7] += v * bf2f_hi(hv[q].w);
    }
  }

#pragma unroll
  for (int j = 0; j < 8; ++j) {
    acc[j] += __shfl_xor(acc[j], 16, 64);
    acc[j] += __shfl_xor(acc[j], 32, 64);
  }

  if (g == 0) {
    uint4 o;
    o.x = (unsigned)f2bf(acc[0]) | ((unsigned)f2bf(acc[1]) << 16);
    o.y = (unsigned)f2bf(acc[2]) | ((unsigned)f2bf(acc[3]) << 16);
    o.z = (unsigned)f2bf(acc[4]) | ((unsigned)f2bf(acc[5]) << 16);
    o.w = (unsigned)f2bf(acc[6]) | ((unsigned)f2bf(acc[7]) << 16);
    *(uint4*)&aggb[(size_t)r * NH + sl * 8] = o;
  }
}

// ---------------------------------------------------------------------------
// Output GEMM via MFMA: out[50000,64] = elu(concat) @ Wout + bout.
// 782 blocks x 4 waves, each wave 16 rows x 64 cols, K=512 in 16 steps.
// ---------------------------------------------------------------------------
__global__ __launch_bounds__(256) void out2_kernel(
    const unsigned short* __restrict__ aggb,   // slots base; concat slots 0..3
    const unsigned short* __restrict__ wot,    // [64][512] bf16 Wout^T
    const float* __restrict__ bout, float* __restrict__ out) {
  const int t    = threadIdx.x;
  const int lane = t & 63;
  const int wave = t >> 6;
  const int l15  = lane & 15;
  const int quad = lane >> 4;
  const int m0   = blockIdx.x * 64 + wave * 16;   // 16 rows per wave

  facc_t acc[4];
#pragma unroll
  for (int ni = 0; ni < 4; ++ni) { facc_t z = {0.f,0.f,0.f,0.f}; acc[ni] = z; }

  const int mrow  = m0 + l15;
  const int mload = mrow < NNODES ? mrow : NNODES - 1;  // clamp; masked at store

#pragma unroll
  for (int ks = 0; ks < 16; ++ks) {
    const int f0  = ks * 32 + quad * 8;            // feature index 0..511
    const int hop = f0 >> 7;
    const int j0  = f0 & 127;
    uint4 ua = *(const uint4*)&aggb[((size_t)hop * NNODES + mload) * NH + j0];
    const unsigned uu[4] = {ua.x, ua.y, ua.z, ua.w};
    unsigned pr[4];
#pragma unroll
    for (int q = 0; q < 4; ++q) {
      float lo = bf2f_lo(uu[q]);
      float hi = bf2f_hi(uu[q]);
      lo = lo > 0.f ? lo : (expf(lo) - 1.f);
      hi = hi > 0.f ? hi : (expf(hi) - 1.f);
      pr[q] = (unsigned)f2bf(lo) | ((unsigned)f2bf(hi) << 16);
    }
    uint4 ra; ra.x = pr[0]; ra.y = pr[1]; ra.z = pr[2]; ra.w = pr[3];
    bfrag_t af = *(bfrag_t*)&ra;
    bfrag_t bf[4];
#pragma unroll
    for (int ni = 0; ni < 4; ++ni) {
      const int n = ni * 16 + l15;
      bf[ni] = *(const bfrag_t*)&wot[(size_t)n * 512 + f0];
    }
#pragma unroll
    for (int ni = 0; ni < 4; ++ni)
      acc[ni] = __builtin_amdgcn_mfma_f32_16x16x32_bf16(af, bf[ni], acc[ni], 0, 0, 0);
  }

#pragma unroll
  for (int ni = 0; ni < 4; ++ni) {
    const int o = ni * 16 + l15;
    const float bo = bout[o];
#pragma unroll
    for (int r = 0; r < 4; ++r) {
      const int m = m0 + quad * 4 + r;
      if (m < NNODES) out[(size_t)m * NO + o] = acc[ni][r] + bo;
    }
  }
}

// ---------------------------------------------------------------------------
extern "C" void kernel_launch(void* const* d_in, const int* in_sizes, int n_in,
                              void* d_out, int out_size, void* d_ws, size_t ws_size,
                              hipStream_t stream) {
  const float* x     = (const float*)d_in[0];
  const float* W     = (const float*)d_in[1];
  const float* b     = (const float*)d_in[2];
  const float* W_out = (const float*)d_in[3];
  const float* b_out = (const float*)d_in[4];
  const int*   erows = (const int*)d_in[5];
  const int*   ecols = (const int*)d_in[6];
  const float* evals = (const float*)d_in[7];
  float* out = (float*)d_out;

  // ws layout (bytes), total ~117e6 (<128e6 known-safe):
  //   slots: 5 x NNODES*NH bf16 = 64.0e6
  //   xb: NPAD*NF bf16 = 25.7e6  (REUSED as 25.6e6 staging after linear)
  //   Wt: 0.26e6 | ecsr: 25.6e6 | ints 1.6e6 | wot: 65.5e3
  unsigned short* slots = (unsigned short*)d_ws;
  unsigned short* xb = slots + (size_t)(NHOPS + 1) * NNODES * NH;
  unsigned short* Wt = xb + (size_t)NPAD * NF;
  unsigned long long* ecsr = (unsigned long long*)(Wt + (size_t)NHOPS * NH * NF);
  int* counts     = (int*)(ecsr + (size_t)NHOPS * NEDGES);
  int* offs       = counts + NHOPS * NNODES;
  int* bucketCur  = offs + NHOPS * (NNODES + 1);
  int* bucketBase = bucketCur + NHOPS * NB;
  unsigned short* wot = (unsigned short*)(bucketBase + NHOPS * (NB + 1));
  // staging aliases xb: xb is dead once linear_kernel has run.
  unsigned long long* staging = (unsigned long long*)xb;

  // bucketCur doubles as bucket-total accumulator for phaseA's hist1.
  hipMemsetAsync(bucketCur, 0, (size_t)NHOPS * NB * sizeof(int), stream);

  phaseA_kernel<<<CONVX_BLOCKS + CONVW_BLOCKS + HIST1_BLOCKS + WOT_BLOCKS,
                  256, 0, stream>>>(x, xb, W, Wt, erows, bucketCur, W_out, wot);
  scanB_kernel<<<NHOPS, 256, 0, stream>>>(bucketCur, bucketBase);
  linear_kernel<<<LIN_BLOCKS, 256, 0, stream>>>(xb, Wt, b, slots);
  bin_kernel<<<dim3(NB, NHOPS), 256, 0, stream>>>(
      erows, ecols, evals, bucketCur, staging);
  countscan_kernel<<<dim3(NB, NHOPS), 256, 0, stream>>>(
      bucketBase, staging, counts);
  scan_kernel<<<NHOPS, 1024, 0, stream>>>(counts, offs);
  place_kernel<<<dim3(NB, NHOPS), 256, 0, stream>>>(offs, staging, ecsr);

  for (int k = 0; k < NHOPS; ++k) {
    gather_kernel<<<NNODES / 4, 256, 0, stream>>>(
        offs + (size_t)k * (NNODES + 1), (const int2*)(ecsr + (size_t)k * NEDGES),
        slots + (size_t)(k + 1) * NNODES * NH,   // hb[k]
        slots + (size_t)k * NNODES * NH);        // agg[k]
  }

  out2_kernel<<<782, 256, 0, stream>>>(slots, wot, b_out, out);
}

// Round 14
// 437.379 us; speedup vs baseline: 2.0400x; 1.0070x over previous
//
#include <hip/hip_runtime.h>
#include <hip/hip_bf16.h>
#include <math.h>

#define NNODES 50000
#define NPAD   50176              // 392*128, padded rows for MFMA tile overrun
#define NEDGES 800000
#define NHOPS  4
#define NF     256
#define NH     128
#define NO     64
#define NB     196                // row buckets of 256 rows (50000/256 -> 196)
#define EPB    4096               // edges per bin block (256 thr x 16)

#define CONVX_BLOCKS 12500        // NNODES*NF/4/256
#define CONVW_BLOCKS 512          // NHOPS*NH*NF/256
#define HIST1_BLOCKS (NB * NHOPS) // 784: bucket-level LDS hist (R7)
#define WOT_BLOCKS   128          // 64*512/256 (Wout^T -> bf16)
#define LIN_PER_HOP  391          // ceil(NNODES/128)
#define LIN_BLOCKS   1568         // 49 groups x 32 (R13 XCD-swizzled mapping)
#define ASTR 40                   // A-stage LDS row stride (ushorts)
#define CPAD 132                  // epilogue LDS row stride (ushorts)

typedef __attribute__((ext_vector_type(8))) short bfrag_t;   // 8 x bf16
typedef __attribute__((ext_vector_type(4))) float facc_t;    // 4 x f32

static __device__ __forceinline__ unsigned short f2bf(float f) {
  unsigned int u = __float_as_uint(f);
  unsigned int r = (u + 0x7fffu + ((u >> 16) & 1u)) >> 16;
  return (unsigned short)r;
}
static __device__ __forceinline__ float bf2f_lo(unsigned int u) {
  return __uint_as_float(u << 16);
}
static __device__ __forceinline__ float bf2f_hi(unsigned int u) {
  return __uint_as_float(u & 0xffff0000u);
}

// ---------------------------------------------------------------------------
// Phase A (fused): convx | convw | hist1 | wot. All independent.
// hist1: bucket-level LDS histogram (R7) — 154K global atomics into 3KB.
// ---------------------------------------------------------------------------
__global__ __launch_bounds__(256) void phaseA_kernel(
    const float* __restrict__ x, unsigned short* __restrict__ xb,
    const float* __restrict__ W, unsigned short* __restrict__ Wt,
    const int* __restrict__ erows, int* __restrict__ bucketCur,
    const float* __restrict__ Wout, unsigned short* __restrict__ wot) {
  const int bx = blockIdx.x;
  const int t  = threadIdx.x;
  if (bx < CONVX_BLOCKS) {
    const size_t i = ((size_t)bx * 256 + t) * 4;
    float4 v = *(const float4*)&x[i];
    ushort4 o;
    o.x = f2bf(v.x); o.y = f2bf(v.y); o.z = f2bf(v.z); o.w = f2bf(v.w);
    *(ushort4*)&xb[i] = o;
  } else if (bx < CONVX_BLOCKS + CONVW_BLOCKS) {
    const int i = (bx - CONVX_BLOCKS) * 256 + t;
    const int k = i / (NH * NF);
    const int rem = i - k * NH * NF;
    const int n = rem / NF;
    const int f = rem - n * NF;
    Wt[i] = f2bf(W[(size_t)k * NF * NH + (size_t)f * NH + n]);
  } else if (bx < CONVX_BLOCKS + CONVW_BLOCKS + HIST1_BLOCKS) {
    const int id  = bx - (CONVX_BLOCKS + CONVW_BLOCKS);
    const int hop = id / NB;
    const int bb  = (id - hop * NB) * EPB;
    __shared__ int bh[NB];
    for (int i = t; i < NB; i += 256) bh[i] = 0;
    __syncthreads();
    const size_t g0 = (size_t)hop * NEDGES;
#pragma unroll
    for (int k = 0; k < 4; ++k) {
      const int e0 = bb + t * 4 + k * 1024;
      if (e0 + 3 < NEDGES) {
        const int4 rr = *(const int4*)&erows[g0 + e0];
        atomicAdd(&bh[rr.x >> 8], 1);
        atomicAdd(&bh[rr.y >> 8], 1);
        atomicAdd(&bh[rr.z >> 8], 1);
        atomicAdd(&bh[rr.w >> 8], 1);
      } else {
        for (int j = 0; j < 4; ++j)
          if (e0 + j < NEDGES) atomicAdd(&bh[erows[g0 + e0 + j] >> 8], 1);
      }
    }
    __syncthreads();
    for (int i = t; i < NB; i += 256)
      if (bh[i]) atomicAdd(&bucketCur[hop * NB + i], bh[i]);
  } else {
    // Wout^T -> bf16: wot[o][f] = bf16(Wout[f][o]); reads coalesced.
    const int i = (bx - (CONVX_BLOCKS + CONVW_BLOCKS + HIST1_BLOCKS)) * 256 + t;
    const int o = i & 63;
    const int f = i >> 6;
    wot[(size_t)o * 512 + f] = f2bf(Wout[(size_t)f * NO + o]);
  }
}

// ---------------------------------------------------------------------------
// Per-hop exclusive scan of 196 bucket totals. bucketCur -> bases (bin's
// allocator); bucketBase immutable (countscan). bucketBase[b] == offs[b*256].
// ---------------------------------------------------------------------------
__global__ __launch_bounds__(256) void scanB_kernel(
    int* __restrict__ bucketCur, int* __restrict__ bucketBase) {
  const int hop = blockIdx.x;
  const int t   = threadIdx.x;
  __shared__ int tot[NB];
  for (int i = t; i < NB; i += 256) tot[i] = bucketCur[hop * NB + i];
  __syncthreads();
  if (t == 0) {
    int run = 0;
    for (int i = 0; i < NB; ++i) { const int c = tot[i]; tot[i] = run; run += c; }
  }
  __syncthreads();
  for (int i = t; i < NB; i += 256) {
    bucketCur[hop * NB + i]        = tot[i];
    bucketBase[hop * (NB + 1) + i] = tot[i];
  }
  if (t == 0) bucketBase[hop * (NB + 1) + NB] = NEDGES;
}

// ---------------------------------------------------------------------------
// Linear via MFMA, all 4 hops in one dispatch.
// R13: XCD-swizzled block mapping. R10's A-staging did NOT cut FETCH (still
// 52MB = 2x xb): the duplication is CROSS-HOP — hop-major block order puts
// the 4 readers of each xb row ~391 blocks apart, never co-resident in one
// XCD's 4MB L2. With round-robin XCD = lb%8, decode lb = g*32 + hop*8 + x,
// mb = g*8+x: the 4 hop-blocks of tile mb share XCD x and a 32-block time
// window -> xb fetched once, reused 3x in L2.
// ---------------------------------------------------------------------------
__global__ __launch_bounds__(256) void linear_kernel(
    const unsigned short* __restrict__ xb, const unsigned short* __restrict__ Wt,
    const float* __restrict__ b, unsigned short* __restrict__ slots) {
  const int lb  = blockIdx.x;
  const int g   = lb >> 5;
  const int rr_ = lb & 31;
  const int hop = rr_ >> 3;
  const int xx  = rr_ & 7;
  const int mb  = g * 8 + xx;
  if (mb >= LIN_PER_HOP) return;
  const unsigned short* Wk = Wt + (size_t)hop * NH * NF;
  const float* bk = b + hop * NH;
  unsigned short* hb = slots + (size_t)(hop + 1) * NNODES * NH;

  const int t    = threadIdx.x;
  const int lane = t & 63;
  const int wave = t >> 6;
  const int wm   = (wave >> 1) * 64;
  const int wn   = (wave & 1) * 64;
  const int m0   = mb * 128;
  const int l15  = lane & 15;
  const int quad = lane >> 4;

  // union: as_[128][ASTR] during k-loop / cs[64][CPAD] epilogue
  __shared__ unsigned short smem[10240];
  unsigned short* as_ = smem;
  unsigned short* cs  = smem;

  facc_t acc[4][4];
#pragma unroll
  for (int i = 0; i < 4; ++i)
#pragma unroll
    for (int j = 0; j < 4; ++j) {
      facc_t z = {0.f, 0.f, 0.f, 0.f};
      acc[i][j] = z;
    }

#pragma unroll
  for (int k0 = 0; k0 < NF; k0 += 32) {
    __syncthreads();   // previous iteration's as_ reads complete
    // stage A: 128 rows x 32 cols (64B/row); thread t: row t>>2, 16B chunk t&3
#pragma unroll
    for (int it = 0; it < 2; ++it) {
      const int row = it * 64 + (t >> 2);
      const int ch  = t & 3;
      const uint4 v = *(const uint4*)&xb[(size_t)(m0 + row) * NF + k0 + ch * 8];
      *(uint4*)&as_[row * ASTR + ch * 8] = v;
    }
    __syncthreads();

    bfrag_t a[4], bb[4];
#pragma unroll
    for (int mi = 0; mi < 4; ++mi)
      a[mi] = *(const bfrag_t*)&as_[(wm + mi * 16 + l15) * ASTR + quad * 8];
#pragma unroll
    for (int ni = 0; ni < 4; ++ni) {
      const int n = wn + ni * 16 + l15;
      bb[ni] = *(const bfrag_t*)&Wk[(size_t)n * NF + k0 + quad * 8];
    }
#pragma unroll
    for (int mi = 0; mi < 4; ++mi)
#pragma unroll
      for (int ni = 0; ni < 4; ++ni)
        acc[mi][ni] = __builtin_amdgcn_mfma_f32_16x16x32_bf16(
            a[mi], bb[ni], acc[mi][ni], 0, 0, 0);
  }

  // ---- epilogue: two 64-row halves through cs[64][CPAD] ----
#pragma unroll
  for (int half = 0; half < 2; ++half) {
    __syncthreads();
    if ((wave >> 1) == half) {
#pragma unroll
      for (int ni = 0; ni < 4; ++ni) {
        const int nl = wn + ni * 16 + l15;
        const float bias = bk[nl];
#pragma unroll
        for (int mi = 0; mi < 4; ++mi) {
#pragma unroll
          for (int r = 0; r < 4; ++r) {
            const int ml = mi * 16 + quad * 4 + r;   // 0..63 within half
            cs[ml * CPAD + nl] = f2bf(acc[mi][ni][r] + bias);
          }
        }
      }
    }
    __syncthreads();
    const int chunk = t & 15;          // 16B chunk within a 256B row
    const int rowb  = t >> 4;          // 16 rows per iteration
#pragma unroll
    for (int it = 0; it < 4; ++it) {
      const int row = it * 16 + rowb;
      const int m   = m0 + half * 64 + row;
      const uint4 v = *(const uint4*)&cs[row * CPAD + chunk * 8];
      if (m < NNODES) *(uint4*)&hb[(size_t)m * NH + chunk * 8] = v;
    }
  }
}

// ---------------------------------------------------------------------------
// Bin pass: rank 4096 edges per block into 196 row-buckets via LDS hist;
// ONE global atomicAdd per (block,bucket) reserves space; edges written in
// ~21-entry contiguous runs into bucket-partitioned staging (aliases dead
// xb). pack: val(hi32) | rowlo<<16 | col. grid (196, NHOPS).
// ---------------------------------------------------------------------------
__global__ __launch_bounds__(256) void bin_kernel(
    const int* __restrict__ erows, const int* __restrict__ ecols,
    const float* __restrict__ evals, int* __restrict__ bucketCur,
    unsigned long long* __restrict__ staging) {
  const int hop = blockIdx.y;
  const int t   = threadIdx.x;
  const int bb  = blockIdx.x * EPB;
  __shared__ int lhist[NB];
  __shared__ int gbase[NB];
  for (int i = t; i < NB; i += 256) lhist[i] = 0;
  __syncthreads();

  unsigned long long pk[16];
  int bkt[16], rnk[16];
  const size_t g0 = (size_t)hop * NEDGES;
#pragma unroll
  for (int k = 0; k < 4; ++k) {
    const int e0 = bb + t * 4 + k * 1024;
    if (e0 + 3 < NEDGES) {
      const int4   rr = *(const int4*)&erows[g0 + e0];
      const int4   cc = *(const int4*)&ecols[g0 + e0];
      const float4 vv = *(const float4*)&evals[g0 + e0];
      const int r4[4] = {rr.x, rr.y, rr.z, rr.w};
      const int c4[4] = {cc.x, cc.y, cc.z, cc.w};
      const float v4[4] = {vv.x, vv.y, vv.z, vv.w};
#pragma unroll
      for (int j = 0; j < 4; ++j) {
        const int b = r4[j] >> 8;
        bkt[k * 4 + j] = b;
        rnk[k * 4 + j] = atomicAdd(&lhist[b], 1);
        pk[k * 4 + j] =
            ((unsigned long long)__float_as_uint(v4[j]) << 32) |
            ((unsigned)(r4[j] & 255) << 16) | (unsigned)c4[j];
      }
    } else {
#pragma unroll
      for (int j = 0; j < 4; ++j) {
        const int e = e0 + j;
        if (e < NEDGES) {
          const int r = erows[g0 + e];
          const int b = r >> 8;
          bkt[k * 4 + j] = b;
          rnk[k * 4 + j] = atomicAdd(&lhist[b], 1);
          pk[k * 4 + j] =
              ((unsigned long long)__float_as_uint(evals[g0 + e]) << 32) |
              ((unsigned)(r & 255) << 16) | (unsigned)ecols[g0 + e];
        } else {
          bkt[k * 4 + j] = -1;
        }
      }
    }
  }
  __syncthreads();
  for (int i = t; i < NB; i += 256) {
    const int c = lhist[i];
    gbase[i] = c ? atomicAdd(&bucketCur[hop * NB + i], c) : 0;
  }
  __syncthreads();
  unsigned long long* dst = staging + (size_t)hop * NEDGES;
#pragma unroll
  for (int q = 0; q < 16; ++q)
    if (bkt[q] >= 0) dst[gbase[bkt[q]] + rnk[q]] = pk[q];
}

// ---------------------------------------------------------------------------
// Per-row counts from staged edges: one block per (bucket,hop), LDS 256-bin
// histogram of rowlo, coalesced write to counts.
// ---------------------------------------------------------------------------
__global__ __launch_bounds__(256) void countscan_kernel(
    const int* __restrict__ bucketBase,
    const unsigned long long* __restrict__ staging, int* __restrict__ counts) {
  const int hop = blockIdx.y;
  const int b   = blockIdx.x;
  const int t   = threadIdx.x;
  const int s = bucketBase[hop * (NB + 1) + b];
  const int e = bucketBase[hop * (NB + 1) + b + 1];
  __shared__ int h[256];
  h[t] = 0;
  __syncthreads();
  const unsigned long long* src = staging + (size_t)hop * NEDGES;
  for (int i = s + t; i < e; i += 256) {
    const int rl = ((unsigned)src[i] >> 16) & 255;
    atomicAdd(&h[rl], 1);
  }
  __syncthreads();
  const int r0 = b * 256;
  if (r0 + t < NNODES) counts[hop * NNODES + r0 + t] = h[t];
}

// ---------------------------------------------------------------------------
// CSR build: exclusive scan per hop over per-row counts.
// ---------------------------------------------------------------------------
__global__ __launch_bounds__(1024) void scan_kernel(
    const int* __restrict__ counts, int* __restrict__ offs) {
  const int hop  = blockIdx.x;
  const int t    = threadIdx.x;
  const int lane = t & 63;
  const int wid  = t >> 6;
  __shared__ int wsum[16];
  __shared__ int carry_s;
  if (t == 0) carry_s = 0;
  __syncthreads();
  const int CH  = 8192;
  const int nch = (NNODES + CH - 1) / CH;     // 7
  for (int ch = 0; ch < nch; ++ch) {
    const int i0 = ch * CH + t * 8;
    int v[8];
    if (i0 + 7 < NNODES) {
      int4 a = *(const int4*)&counts[hop * NNODES + i0];
      int4 b = *(const int4*)&counts[hop * NNODES + i0 + 4];
      v[0]=a.x; v[1]=a.y; v[2]=a.z; v[3]=a.w;
      v[4]=b.x; v[5]=b.y; v[6]=b.z; v[7]=b.w;
    } else {
#pragma unroll
      for (int j = 0; j < 8; ++j)
        v[j] = (i0 + j < NNODES) ? counts[hop * NNODES + i0 + j] : 0;
    }
    int l[8];
    int run = 0;
#pragma unroll
    for (int j = 0; j < 8; ++j) { run += v[j]; l[j] = run; }   // inclusive
    int s = run;
#pragma unroll
    for (int d = 1; d < 64; d <<= 1) {
      int n = __shfl_up(s, d, 64);
      if (lane >= d) s += n;
    }
    if (lane == 63) wsum[wid] = s;
    __syncthreads();
    if (t < 16) {
      int ws = wsum[t];
#pragma unroll
      for (int d = 1; d < 16; d <<= 1) {
        int n = __shfl_up(ws, d, 16);
        if (t >= d) ws += n;
      }
      wsum[t] = ws;
    }
    __syncthreads();
    const int base = carry_s + (wid ? wsum[wid - 1] : 0) + (s - run);
    if (i0 + 7 < NNODES) {
      int4 o0 = make_int4(base, base + l[0], base + l[1], base + l[2]);
      int4 o1 = make_int4(base + l[3], base + l[4], base + l[5], base + l[6]);
      *(int4*)&offs[hop * (NNODES + 1) + i0]     = o0;
      *(int4*)&offs[hop * (NNODES + 1) + i0 + 4] = o1;
    } else {
#pragma unroll
      for (int j = 0; j < 8; ++j) {
        if (i0 + j < NNODES) {
          const int excl = base + (l[j] - v[j]);
          offs[hop * (NNODES + 1) + i0 + j] = excl;
        }
      }
    }
    __syncthreads();
    if (t == 0) carry_s += wsum[15];
    __syncthreads();
  }
  if (t == 0) offs[hop * (NNODES + 1) + NNODES] = carry_s;
}

// ---------------------------------------------------------------------------
// Place pass: one block per (bucket,hop). Sequential read of the bucket's
// staging segment; exact CSR position via LDS row cursors (no global
// atomics). All writes land in this block's own 32KB window.
// ---------------------------------------------------------------------------
__global__ __launch_bounds__(256) void place_kernel(
    const int* __restrict__ offs, const unsigned long long* __restrict__ staging,
    unsigned long long* __restrict__ ecsr) {
  const int hop = blockIdx.y;
  const int bk  = blockIdx.x;
  const int t   = threadIdx.x;
  const int r0  = bk * 256;
  const int nr  = (NNODES - r0 < 256) ? (NNODES - r0) : 256;
  const int* o = offs + (size_t)hop * (NNODES + 1);
  __shared__ int cur[257];
  for (int i = t; i <= nr; i += 256) cur[i] = o[r0 + i];
  __syncthreads();
  const int s = cur[0];
  const int e = cur[nr];          // never touched by atomics (rowlo < nr)
  __syncthreads();                // snapshot s,e before any cursor bumps
  const unsigned long long* src = staging + (size_t)hop * NEDGES;
  unsigned long long* dst       = ecsr + (size_t)hop * NEDGES;
  for (int i = s + t; i < e; i += 256) {
    const unsigned long long v = src[i];
    const unsigned lo = (unsigned)v;
    const int rl = (lo >> 16) & 255;
    const int d = atomicAdd(&cur[rl], 1);
    dst[d] = (v & 0xFFFFFFFF00000000ull) | (unsigned long long)(lo & 0xFFFFu);
  }
}

// ---------------------------------------------------------------------------
// Gather SpMM (ONE HOP per dispatch — sequential dispatches enforce the
// hb[k]/agg[k] slot-aliasing dependency).
// ---------------------------------------------------------------------------
__global__ __launch_bounds__(256) void gather_kernel(
    const int* __restrict__ offs, const int2* __restrict__ ecsr,
    const unsigned short* __restrict__ hb, unsigned short* __restrict__ aggb) {
  const int t    = threadIdx.x;
  const int lane = t & 63;
  const int wid  = t >> 6;
  const int r = blockIdx.x * 4 + wid;
  const int g  = lane >> 4;    // edge subgroup 0..3
  const int sl = lane & 15;    // feature slice: feats sl*8 .. sl*8+7
  const int s = offs[r];
  const int e = offs[r + 1];

  float acc[8];
#pragma unroll
  for (int j = 0; j < 8; ++j) acc[j] = 0.f;

  for (int p = s; p < e; p += 16) {
    int2 ed[4];
#pragma unroll
    for (int q = 0; q < 4; ++q) {
      const int idx = p + q * 4 + g;
      ed[q] = (idx < e) ? ecsr[idx] : make_int2(0, 0);
    }
    uint4 hv[4];
#pragma unroll
    for (int q = 0; q < 4; ++q)
      hv[q] = *(const uint4*)&hb[(size_t)ed[q].x * NH + sl * 8];
#pragma unroll
    for (int q = 0; q < 4; ++q) {
      const float v = __int_as_float(ed[q].y);
      acc[0] += v * bf2f_lo(hv[q].x);
      acc[1] += v * bf2f_hi(hv[q].x);
      acc[2] += v * bf2f_lo(hv[q].y);
      acc[3] += v * bf2f_hi(hv[q].y);
      acc[4] += v * bf2f_lo(hv[q].z);
      acc[5] += v * bf2f_hi(hv[q].z);
      acc[6] += v * bf2f_lo(hv[q].w);
      acc[7] += v * bf2f_hi(hv[q].w);
    }
  }

#pragma unroll
  for (int j = 0; j < 8; ++j) {
    acc[j] += __shfl_xor(acc[j], 16, 64);
    acc[j] += __shfl_xor(acc[j], 32, 64);
  }

  if (g == 0) {
    uint4 o;
    o.x = (unsigned)f2bf(acc[0]) | ((unsigned)f2bf(acc[1]) << 16);
    o.y = (unsigned)f2bf(acc[2]) | ((unsigned)f2bf(acc[3]) << 16);
    o.z = (unsigned)f2bf(acc[4]) | ((unsigned)f2bf(acc[5]) << 16);
    o.w = (unsigned)f2bf(acc[6]) | ((unsigned)f2bf(acc[7]) << 16);
    *(uint4*)&aggb[(size_t)r * NH + sl * 8] = o;
  }
}

// ---------------------------------------------------------------------------
// Output GEMM via MFMA: out[50000,64] = elu(concat) @ Wout + bout.
// 782 blocks x 4 waves, each wave 16 rows x 64 cols, K=512 in 16 steps.
// ---------------------------------------------------------------------------
__global__ __launch_bounds__(256) void out2_kernel(
    const unsigned short* __restrict__ aggb,   // slots base; concat slots 0..3
    const unsigned short* __restrict__ wot,    // [64][512] bf16 Wout^T
    const float* __restrict__ bout, float* __restrict__ out) {
  const int t    = threadIdx.x;
  const int lane = t & 63;
  const int wave = t >> 6;
  const int l15  = lane & 15;
  const int quad = lane >> 4;
  const int m0   = blockIdx.x * 64 + wave * 16;   // 16 rows per wave

  facc_t acc[4];
#pragma unroll
  for (int ni = 0; ni < 4; ++ni) { facc_t z = {0.f,0.f,0.f,0.f}; acc[ni] = z; }

  const int mrow  = m0 + l15;
  const int mload = mrow < NNODES ? mrow : NNODES - 1;  // clamp; masked at store

#pragma unroll
  for (int ks = 0; ks < 16; ++ks) {
    const int f0  = ks * 32 + quad * 8;            // feature index 0..511
    const int hop = f0 >> 7;
    const int j0  = f0 & 127;
    uint4 ua = *(const uint4*)&aggb[((size_t)hop * NNODES + mload) * NH + j0];
    const unsigned uu[4] = {ua.x, ua.y, ua.z, ua.w};
    unsigned pr[4];
#pragma unroll
    for (int q = 0; q < 4; ++q) {
      float lo = bf2f_lo(uu[q]);
      float hi = bf2f_hi(uu[q]);
      lo = lo > 0.f ? lo : (expf(lo) - 1.f);
      hi = hi > 0.f ? hi : (expf(hi) - 1.f);
      pr[q] = (unsigned)f2bf(lo) | ((unsigned)f2bf(hi) << 16);
    }
    uint4 ra; ra.x = pr[0]; ra.y = pr[1]; ra.z = pr[2]; ra.w = pr[3];
    bfrag_t af = *(bfrag_t*)&ra;
    bfrag_t bf[4];
#pragma unroll
    for (int ni = 0; ni < 4; ++ni) {
      const int n = ni * 16 + l15;
      bf[ni] = *(const bfrag_t*)&wot[(size_t)n * 512 + f0];
    }
#pragma unroll
    for (int ni = 0; ni < 4; ++ni)
      acc[ni] = __builtin_amdgcn_mfma_f32_16x16x32_bf16(af, bf[ni], acc[ni], 0, 0, 0);
  }

#pragma unroll
  for (int ni = 0; ni < 4; ++ni) {
    const int o = ni * 16 + l15;
    const float bo = bout[o];
#pragma unroll
    for (int r = 0; r < 4; ++r) {
      const int m = m0 + quad * 4 + r;
      if (m < NNODES) out[(size_t)m * NO + o] = acc[ni][r] + bo;
    }
  }
}

// ---------------------------------------------------------------------------
extern "C" void kernel_launch(void* const* d_in, const int* in_sizes, int n_in,
                              void* d_out, int out_size, void* d_ws, size_t ws_size,
                              hipStream_t stream) {
  const float* x     = (const float*)d_in[0];
  const float* W     = (const float*)d_in[1];
  const float* b     = (const float*)d_in[2];
  const float* W_out = (const float*)d_in[3];
  const float* b_out = (const float*)d_in[4];
  const int*   erows = (const int*)d_in[5];
  const int*   ecols = (const int*)d_in[6];
  const float* evals = (const float*)d_in[7];
  float* out = (float*)d_out;

  // ws layout (bytes), total ~117e6 (<128e6 known-safe):
  //   slots: 5 x NNODES*NH bf16 = 64.0e6
  //   xb: NPAD*NF bf16 = 25.7e6  (REUSED as 25.6e6 staging after linear)
  //   Wt: 0.26e6 | ecsr: 25.6e6 | ints 1.6e6 | wot: 65.5e3
  unsigned short* slots = (unsigned short*)d_ws;
  unsigned short* xb = slots + (size_t)(NHOPS + 1) * NNODES * NH;
  unsigned short* Wt = xb + (size_t)NPAD * NF;
  unsigned long long* ecsr = (unsigned long long*)(Wt + (size_t)NHOPS * NH * NF);
  int* counts     = (int*)(ecsr + (size_t)NHOPS * NEDGES);
  int* offs       = counts + NHOPS * NNODES;
  int* bucketCur  = offs + NHOPS * (NNODES + 1);
  int* bucketBase = bucketCur + NHOPS * NB;
  unsigned short* wot = (unsigned short*)(bucketBase + NHOPS * (NB + 1));
  // staging aliases xb: xb is dead once linear_kernel has run.
  unsigned long long* staging = (unsigned long long*)xb;

  // bucketCur doubles as bucket-total accumulator for phaseA's hist1.
  hipMemsetAsync(bucketCur, 0, (size_t)NHOPS * NB * sizeof(int), stream);

  phaseA_kernel<<<CONVX_BLOCKS + CONVW_BLOCKS + HIST1_BLOCKS + WOT_BLOCKS,
                  256, 0, stream>>>(x, xb, W, Wt, erows, bucketCur, W_out, wot);
  scanB_kernel<<<NHOPS, 256, 0, stream>>>(bucketCur, bucketBase);
  linear_kernel<<<LIN_BLOCKS, 256, 0, stream>>>(xb, Wt, b, slots);
  bin_kernel<<<dim3(NB, NHOPS), 256, 0, stream>>>(
      erows, ecols, evals, bucketCur, staging);
  countscan_kernel<<<dim3(NB, NHOPS), 256, 0, stream>>>(
      bucketBase, staging, counts);
  scan_kernel<<<NHOPS, 1024, 0, stream>>>(counts, offs);
  place_kernel<<<dim3(NB, NHOPS), 256, 0, stream>>>(offs, staging, ecsr);

  for (int k = 0; k < NHOPS; ++k) {
    gather_kernel<<<NNODES / 4, 256, 0, stream>>>(
        offs + (size_t)k * (NNODES + 1), (const int2*)(ecsr + (size_t)k * NEDGES),
        slots + (size_t)(k + 1) * NNODES * NH,   // hb[k]
        slots + (size_t)k * NNODES * NH);        // agg[k]
  }

  out2_kernel<<<782, 256, 0, stream>>>(slots, wot, b_out, out);
}

// Round 16
// 435.060 us; speedup vs baseline: 2.0509x; 1.0053x over previous
//
#include <hip/hip_runtime.h>
#include <hip/hip_bf16.h>
#include <math.h>

#define NNODES 50000
#define NPAD   50176              // 392*128, padded rows for MFMA tile overrun
#define NEDGES 800000
#define NHOPS  4
#define NF     256
#define NH     128
#define NO     64
#define NB     196                // row buckets of 256 rows (50000/256 -> 196)
#define EPB    4096               // edges per bin block (256 thr x 16)

#define CONVX_BLOCKS 12500        // NNODES*NF/4/256
#define CONVW_BLOCKS 512          // NHOPS*NH*NF/256
#define HIST1_BLOCKS (NB * NHOPS) // 784: bucket-level LDS hist (R7)
#define WOT_BLOCKS   128          // 64*512/256 (Wout^T -> bf16)
#define LIN_PER_HOP  391          // ceil(NNODES/128)
#define LIN_BLOCKS   1568         // 49 groups x 32 (R13 XCD-swizzled mapping)
#define CPAD 132                  // epilogue LDS row stride (ushorts)

typedef __attribute__((ext_vector_type(8))) short bfrag_t;   // 8 x bf16
typedef __attribute__((ext_vector_type(4))) float facc_t;    // 4 x f32

static __device__ __forceinline__ unsigned short f2bf(float f) {
  unsigned int u = __float_as_uint(f);
  unsigned int r = (u + 0x7fffu + ((u >> 16) & 1u)) >> 16;
  return (unsigned short)r;
}
static __device__ __forceinline__ float bf2f_lo(unsigned int u) {
  return __uint_as_float(u << 16);
}
static __device__ __forceinline__ float bf2f_hi(unsigned int u) {
  return __uint_as_float(u & 0xffff0000u);
}

// ---------------------------------------------------------------------------
// Phase A (fused): convx | convw | hist1 | wot. All independent.
// ---------------------------------------------------------------------------
__global__ __launch_bounds__(256) void phaseA_kernel(
    const float* __restrict__ x, unsigned short* __restrict__ xb,
    const float* __restrict__ W, unsigned short* __restrict__ Wt,
    const int* __restrict__ erows, int* __restrict__ bucketCur,
    const float* __restrict__ Wout, unsigned short* __restrict__ wot) {
  const int bx = blockIdx.x;
  const int t  = threadIdx.x;
  if (bx < CONVX_BLOCKS) {
    const size_t i = ((size_t)bx * 256 + t) * 4;
    float4 v = *(const float4*)&x[i];
    ushort4 o;
    o.x = f2bf(v.x); o.y = f2bf(v.y); o.z = f2bf(v.z); o.w = f2bf(v.w);
    *(ushort4*)&xb[i] = o;
  } else if (bx < CONVX_BLOCKS + CONVW_BLOCKS) {
    const int i = (bx - CONVX_BLOCKS) * 256 + t;
    const int k = i / (NH * NF);
    const int rem = i - k * NH * NF;
    const int n = rem / NF;
    const int f = rem - n * NF;
    Wt[i] = f2bf(W[(size_t)k * NF * NH + (size_t)f * NH + n]);
  } else if (bx < CONVX_BLOCKS + CONVW_BLOCKS + HIST1_BLOCKS) {
    const int id  = bx - (CONVX_BLOCKS + CONVW_BLOCKS);
    const int hop = id / NB;
    const int bb  = (id - hop * NB) * EPB;
    __shared__ int bh[NB];
    for (int i = t; i < NB; i += 256) bh[i] = 0;
    __syncthreads();
    const size_t g0 = (size_t)hop * NEDGES;
#pragma unroll
    for (int k = 0; k < 4; ++k) {
      const int e0 = bb + t * 4 + k * 1024;
      if (e0 + 3 < NEDGES) {
        const int4 rr = *(const int4*)&erows[g0 + e0];
        atomicAdd(&bh[rr.x >> 8], 1);
        atomicAdd(&bh[rr.y >> 8], 1);
        atomicAdd(&bh[rr.z >> 8], 1);
        atomicAdd(&bh[rr.w >> 8], 1);
      } else {
        for (int j = 0; j < 4; ++j)
          if (e0 + j < NEDGES) atomicAdd(&bh[erows[g0 + e0 + j] >> 8], 1);
      }
    }
    __syncthreads();
    for (int i = t; i < NB; i += 256)
      if (bh[i]) atomicAdd(&bucketCur[hop * NB + i], bh[i]);
  } else {
    // Wout^T -> bf16: wot[o][f] = bf16(Wout[f][o]); reads coalesced.
    const int i = (bx - (CONVX_BLOCKS + CONVW_BLOCKS + HIST1_BLOCKS)) * 256 + t;
    const int o = i & 63;
    const int f = i >> 6;
    wot[(size_t)o * 512 + f] = f2bf(Wout[(size_t)f * NO + o]);
  }
}

// ---------------------------------------------------------------------------
// Per-hop exclusive scan of 196 bucket totals. bucketCur -> bases (bin's
// allocator); bucketBase immutable (countscan). bucketBase[b] == offs[b*256].
// ---------------------------------------------------------------------------
__global__ __launch_bounds__(256) void scanB_kernel(
    int* __restrict__ bucketCur, int* __restrict__ bucketBase) {
  const int hop = blockIdx.x;
  const int t   = threadIdx.x;
  __shared__ int tot[NB];
  for (int i = t; i < NB; i += 256) tot[i] = bucketCur[hop * NB + i];
  __syncthreads();
  if (t == 0) {
    int run = 0;
    for (int i = 0; i < NB; ++i) { const int c = tot[i]; tot[i] = run; run += c; }
  }
  __syncthreads();
  for (int i = t; i < NB; i += 256) {
    bucketCur[hop * NB + i]        = tot[i];
    bucketBase[hop * (NB + 1) + i] = tot[i];
  }
  if (t == 0) bucketBase[hop * (NB + 1) + NB] = NEDGES;
}

// ---------------------------------------------------------------------------
// Linear via MFMA, all 4 hops in one dispatch.
// R13 XCD swizzle kept (FETCH 52->14MB confirmed). R14: A-staging REVERTED
// to direct xb reads — staging added 32 barriers/block + 1.6M bank
// conflicts and dropped occupancy (latency-bound at 1.16 TB/s effective);
// the FETCH fix came from the swizzle alone. Half-tile LDS epilogue kept.
// ---------------------------------------------------------------------------
__global__ __launch_bounds__(256) void linear_kernel(
    const unsigned short* __restrict__ xb, const unsigned short* __restrict__ Wt,
    const float* __restrict__ b, unsigned short* __restrict__ slots) {
  const int lb  = blockIdx.x;
  const int g   = lb >> 5;
  const int rr_ = lb & 31;
  const int hop = rr_ >> 3;
  const int xx  = rr_ & 7;
  const int mb  = g * 8 + xx;
  if (mb >= LIN_PER_HOP) return;
  const unsigned short* Wk = Wt + (size_t)hop * NH * NF;
  const float* bk = b + hop * NH;
  unsigned short* hb = slots + (size_t)(hop + 1) * NNODES * NH;

  const int t    = threadIdx.x;
  const int lane = t & 63;
  const int wave = t >> 6;
  const int wm   = (wave >> 1) * 64;
  const int wn   = (wave & 1) * 64;
  const int m0   = mb * 128;
  const int l15  = lane & 15;
  const int quad = lane >> 4;

  __shared__ unsigned short cs[64 * CPAD];   // epilogue staging only

  facc_t acc[4][4];
#pragma unroll
  for (int i = 0; i < 4; ++i)
#pragma unroll
    for (int j = 0; j < 4; ++j) {
      facc_t z = {0.f, 0.f, 0.f, 0.f};
      acc[i][j] = z;
    }

#pragma unroll
  for (int k0 = 0; k0 < NF; k0 += 32) {
    bfrag_t a[4], bb[4];
#pragma unroll
    for (int mi = 0; mi < 4; ++mi) {
      const int m = m0 + wm + mi * 16 + l15;
      a[mi] = *(const bfrag_t*)&xb[(size_t)m * NF + k0 + quad * 8];
    }
#pragma unroll
    for (int ni = 0; ni < 4; ++ni) {
      const int n = wn + ni * 16 + l15;
      bb[ni] = *(const bfrag_t*)&Wk[(size_t)n * NF + k0 + quad * 8];
    }
#pragma unroll
    for (int mi = 0; mi < 4; ++mi)
#pragma unroll
      for (int ni = 0; ni < 4; ++ni)
        acc[mi][ni] = __builtin_amdgcn_mfma_f32_16x16x32_bf16(
            a[mi], bb[ni], acc[mi][ni], 0, 0, 0);
  }

  // ---- epilogue: two 64-row halves through cs[64][CPAD] ----
#pragma unroll
  for (int half = 0; half < 2; ++half) {
    __syncthreads();
    if ((wave >> 1) == half) {
#pragma unroll
      for (int ni = 0; ni < 4; ++ni) {
        const int nl = wn + ni * 16 + l15;
        const float bias = bk[nl];
#pragma unroll
        for (int mi = 0; mi < 4; ++mi) {
#pragma unroll
          for (int r = 0; r < 4; ++r) {
            const int ml = mi * 16 + quad * 4 + r;   // 0..63 within half
            cs[ml * CPAD + nl] = f2bf(acc[mi][ni][r] + bias);
          }
        }
      }
    }
    __syncthreads();
    const int chunk = t & 15;          // 16B chunk within a 256B row
    const int rowb  = t >> 4;          // 16 rows per iteration
#pragma unroll
    for (int it = 0; it < 4; ++it) {
      const int row = it * 16 + rowb;
      const int m   = m0 + half * 64 + row;
      const uint4 v = *(const uint4*)&cs[row * CPAD + chunk * 8];
      if (m < NNODES) *(uint4*)&hb[(size_t)m * NH + chunk * 8] = v;
    }
  }
}

// ---------------------------------------------------------------------------
// Bin pass: rank 4096 edges per block into 196 row-buckets via LDS hist;
// ONE global atomicAdd per (block,bucket) reserves space; edges written in
// ~21-entry contiguous runs into bucket-partitioned staging (aliases dead
// xb). pack: val(hi32) | rowlo<<16 | col. grid (196, NHOPS).
// ---------------------------------------------------------------------------
__global__ __launch_bounds__(256) void bin_kernel(
    const int* __restrict__ erows, const int* __restrict__ ecols,
    const float* __restrict__ evals, int* __restrict__ bucketCur,
    unsigned long long* __restrict__ staging) {
  const int hop = blockIdx.y;
  const int t   = threadIdx.x;
  const int bb  = blockIdx.x * EPB;
  __shared__ int lhist[NB];
  __shared__ int gbase[NB];
  for (int i = t; i < NB; i += 256) lhist[i] = 0;
  __syncthreads();

  unsigned long long pk[16];
  int bkt[16], rnk[16];
  const size_t g0 = (size_t)hop * NEDGES;
#pragma unroll
  for (int k = 0; k < 4; ++k) {
    const int e0 = bb + t * 4 + k * 1024;
    if (e0 + 3 < NEDGES) {
      const int4   rr = *(const int4*)&erows[g0 + e0];
      const int4   cc = *(const int4*)&ecols[g0 + e0];
      const float4 vv = *(const float4*)&evals[g0 + e0];
      const int r4[4] = {rr.x, rr.y, rr.z, rr.w};
      const int c4[4] = {cc.x, cc.y, cc.z, cc.w};
      const float v4[4] = {vv.x, vv.y, vv.z, vv.w};
#pragma unroll
      for (int j = 0; j < 4; ++j) {
        const int b = r4[j] >> 8;
        bkt[k * 4 + j] = b;
        rnk[k * 4 + j] = atomicAdd(&lhist[b], 1);
        pk[k * 4 + j] =
            ((unsigned long long)__float_as_uint(v4[j]) << 32) |
            ((unsigned)(r4[j] & 255) << 16) | (unsigned)c4[j];
      }
    } else {
#pragma unroll
      for (int j = 0; j < 4; ++j) {
        const int e = e0 + j;
        if (e < NEDGES) {
          const int r = erows[g0 + e];
          const int b = r >> 8;
          bkt[k * 4 + j] = b;
          rnk[k * 4 + j] = atomicAdd(&lhist[b], 1);
          pk[k * 4 + j] =
              ((unsigned long long)__float_as_uint(evals[g0 + e]) << 32) |
              ((unsigned)(r & 255) << 16) | (unsigned)ecols[g0 + e];
        } else {
          bkt[k * 4 + j] = -1;
        }
      }
    }
  }
  __syncthreads();
  for (int i = t; i < NB; i += 256) {
    const int c = lhist[i];
    gbase[i] = c ? atomicAdd(&bucketCur[hop * NB + i], c) : 0;
  }
  __syncthreads();
  unsigned long long* dst = staging + (size_t)hop * NEDGES;
#pragma unroll
  for (int q = 0; q < 16; ++q)
    if (bkt[q] >= 0) dst[gbase[bkt[q]] + rnk[q]] = pk[q];
}

// ---------------------------------------------------------------------------
// Per-row counts from staged edges: one block per (bucket,hop), LDS 256-bin
// histogram of rowlo, coalesced write to counts.
// ---------------------------------------------------------------------------
__global__ __launch_bounds__(256) void countscan_kernel(
    const int* __restrict__ bucketBase,
    const unsigned long long* __restrict__ staging, int* __restrict__ counts) {
  const int hop = blockIdx.y;
  const int b   = blockIdx.x;
  const int t   = threadIdx.x;
  const int s = bucketBase[hop * (NB + 1) + b];
  const int e = bucketBase[hop * (NB + 1) + b + 1];
  __shared__ int h[256];
  h[t] = 0;
  __syncthreads();
  const unsigned long long* src = staging + (size_t)hop * NEDGES;
  for (int i = s + t; i < e; i += 256) {
    const int rl = ((unsigned)src[i] >> 16) & 255;
    atomicAdd(&h[rl], 1);
  }
  __syncthreads();
  const int r0 = b * 256;
  if (r0 + t < NNODES) counts[hop * NNODES + r0 + t] = h[t];
}

// ---------------------------------------------------------------------------
// CSR build: exclusive scan per hop over per-row counts.
// ---------------------------------------------------------------------------
__global__ __launch_bounds__(1024) void scan_kernel(
    const int* __restrict__ counts, int* __restrict__ offs) {
  const int hop  = blockIdx.x;
  const int t    = threadIdx.x;
  const int lane = t & 63;
  const int wid  = t >> 6;
  __shared__ int wsum[16];
  __shared__ int carry_s;
  if (t == 0) carry_s = 0;
  __syncthreads();
  const int CH  = 8192;
  const int nch = (NNODES + CH - 1) / CH;     // 7
  for (int ch = 0; ch < nch; ++ch) {
    const int i0 = ch * CH + t * 8;
    int v[8];
    if (i0 + 7 < NNODES) {
      int4 a = *(const int4*)&counts[hop * NNODES + i0];
      int4 b = *(const int4*)&counts[hop * NNODES + i0 + 4];
      v[0]=a.x; v[1]=a.y; v[2]=a.z; v[3]=a.w;
      v[4]=b.x; v[5]=b.y; v[6]=b.z; v[7]=b.w;
    } else {
#pragma unroll
      for (int j = 0; j < 8; ++j)
        v[j] = (i0 + j < NNODES) ? counts[hop * NNODES + i0 + j] : 0;
    }
    int l[8];
    int run = 0;
#pragma unroll
    for (int j = 0; j < 8; ++j) { run += v[j]; l[j] = run; }   // inclusive
    int s = run;
#pragma unroll
    for (int d = 1; d < 64; d <<= 1) {
      int n = __shfl_up(s, d, 64);
      if (lane >= d) s += n;
    }
    if (lane == 63) wsum[wid] = s;
    __syncthreads();
    if (t < 16) {
      int ws = wsum[t];
#pragma unroll
      for (int d = 1; d < 16; d <<= 1) {
        int n = __shfl_up(ws, d, 16);
        if (t >= d) ws += n;
      }
      wsum[t] = ws;
    }
    __syncthreads();
    const int base = carry_s + (wid ? wsum[wid - 1] : 0) + (s - run);
    if (i0 + 7 < NNODES) {
      int4 o0 = make_int4(base, base + l[0], base + l[1], base + l[2]);
      int4 o1 = make_int4(base + l[3], base + l[4], base + l[5], base + l[6]);
      *(int4*)&offs[hop * (NNODES + 1) + i0]     = o0;
      *(int4*)&offs[hop * (NNODES + 1) + i0 + 4] = o1;
    } else {
#pragma unroll
      for (int j = 0; j < 8; ++j) {
        if (i0 + j < NNODES) {
          const int excl = base + (l[j] - v[j]);
          offs[hop * (NNODES + 1) + i0 + j] = excl;
        }
      }
    }
    __syncthreads();
    if (t == 0) carry_s += wsum[15];
    __syncthreads();
  }
  if (t == 0) offs[hop * (NNODES + 1) + NNODES] = carry_s;
}

// ---------------------------------------------------------------------------
// Place pass: one block per (bucket,hop). Sequential read of the bucket's
// staging segment; exact CSR position via LDS row cursors (no global
// atomics). All writes land in this block's own 32KB window.
// ---------------------------------------------------------------------------
__global__ __launch_bounds__(256) void place_kernel(
    const int* __restrict__ offs, const unsigned long long* __restrict__ staging,
    unsigned long long* __restrict__ ecsr) {
  const int hop = blockIdx.y;
  const int bk  = blockIdx.x;
  const int t   = threadIdx.x;
  const int r0  = bk * 256;
  const int nr  = (NNODES - r0 < 256) ? (NNODES - r0) : 256;
  const int* o = offs + (size_t)hop * (NNODES + 1);
  __shared__ int cur[257];
  for (int i = t; i <= nr; i += 256) cur[i] = o[r0 + i];
  __syncthreads();
  const int s = cur[0];
  const int e = cur[nr];          // never touched by atomics (rowlo < nr)
  __syncthreads();                // snapshot s,e before any cursor bumps
  const unsigned long long* src = staging + (size_t)hop * NEDGES;
  unsigned long long* dst       = ecsr + (size_t)hop * NEDGES;
  for (int i = s + t; i < e; i += 256) {
    const unsigned long long v = src[i];
    const unsigned lo = (unsigned)v;
    const int rl = (lo >> 16) & 255;
    const int d = atomicAdd(&cur[rl], 1);
    dst[d] = (v & 0xFFFFFFFF00000000ull) | (unsigned long long)(lo & 0xFFFFu);
  }
}

// ---------------------------------------------------------------------------
// Paired gather SpMM: TWO hops per dispatch (blockIdx.y picks hop).
// The 4 gathers were ordered only by WAR hazards (gather k+1 writes slot
// k+1 which gather k reads). Redirecting agg1/agg3 into dead staging makes
// {g0,g1} and {g2,g3} write-disjoint -> 2 dispatches, 2x resident
// parallelism for the L3-latency-bound random hb reads. Cross-pair WAR
// (g2 writes s2 read by g1) is ordered by the dispatch boundary.
// ---------------------------------------------------------------------------
__global__ __launch_bounds__(256) void gather2_kernel(
    const int* __restrict__ offs, const int2* __restrict__ ecsr,
    const unsigned short* __restrict__ slots,
    unsigned short* __restrict__ aggA, unsigned short* __restrict__ aggB,
    int hop0) {
  const int y    = blockIdx.y;
  const int hop  = hop0 + y;
  const int* off = offs + (size_t)hop * (NNODES + 1);
  const int2* ec = ecsr + (size_t)hop * NEDGES;
  const unsigned short* hb = slots + (size_t)(hop + 1) * NNODES * NH;
  unsigned short* aggb = y ? aggB : aggA;

  const int t    = threadIdx.x;
  const int lane = t & 63;
  const int wid  = t >> 6;
  const int r = blockIdx.x * 4 + wid;
  const int g  = lane >> 4;    // edge subgroup 0..3
  const int sl = lane & 15;    // feature slice: feats sl*8 .. sl*8+7
  const int s = off[r];
  const int e = off[r + 1];

  float acc[8];
#pragma unroll
  for (int j = 0; j < 8; ++j) acc[j] = 0.f;

  for (int p = s; p < e; p += 16) {
    int2 ed[4];
#pragma unroll
    for (int q = 0; q < 4; ++q) {
      const int idx = p + q * 4 + g;
      ed[q] = (idx < e) ? ec[idx] : make_int2(0, 0);
    }
    uint4 hv[4];
#pragma unroll
    for (int q = 0; q < 4; ++q)
      hv[q] = *(const uint4*)&hb[(size_t)ed[q].x * NH + sl * 8];
#pragma unroll
    for (int q = 0; q < 4; ++q) {
      const float v = __int_as_float(ed[q].y);
      acc[0] += v * bf2f_lo(hv[q].x);
      acc[1] += v * bf2f_hi(hv[q].x);
      acc[2] += v * bf2f_lo(hv[q].y);
      acc[3] += v * bf2f_hi(hv[q].y);
      acc[4] += v * bf2f_lo(hv[q].z);
      acc[5] += v * bf2f_hi(hv[q].z);
      acc[6] += v * bf2f_lo(hv[q].w);
      acc[7] += v * bf2f_hi(hv[q].w);
    }
  }

#pragma unroll
  for (int j = 0; j < 8; ++j) {
    acc[j] += __shfl_xor(acc[j], 16, 64);
    acc[j] += __shfl_xor(acc[j], 32, 64);
  }

  if (g == 0) {
    uint4 o;
    o.x = (unsigned)f2bf(acc[0]) | ((unsigned)f2bf(acc[1]) << 16);
    o.y = (unsigned)f2bf(acc[2]) | ((unsigned)f2bf(acc[3]) << 16);
    o.z = (unsigned)f2bf(acc[4]) | ((unsigned)f2bf(acc[5]) << 16);
    o.w = (unsigned)f2bf(acc[6]) | ((unsigned)f2bf(acc[7]) << 16);
    *(uint4*)&aggb[(size_t)r * NH + sl * 8] = o;
  }
}

// ---------------------------------------------------------------------------
// Output GEMM via MFMA: out[50000,64] = elu(concat) @ Wout + bout.
// 782 blocks x 4 waves, each wave 16 rows x 64 cols, K=512 in 16 steps.
// agg inputs come from 4 per-hop base pointers (agg1/agg3 in staging).
// ---------------------------------------------------------------------------
__global__ __launch_bounds__(256) void out2_kernel(
    const unsigned short* __restrict__ agg0, const unsigned short* __restrict__ agg1,
    const unsigned short* __restrict__ agg2, const unsigned short* __restrict__ agg3,
    const unsigned short* __restrict__ wot,    // [64][512] bf16 Wout^T
    const float* __restrict__ bout, float* __restrict__ out) {
  const int t    = threadIdx.x;
  const int lane = t & 63;
  const int wave = t >> 6;
  const int l15  = lane & 15;
  const int quad = lane >> 4;
  const int m0   = blockIdx.x * 64 + wave * 16;   // 16 rows per wave

  facc_t acc[4];
#pragma unroll
  for (int ni = 0; ni < 4; ++ni) { facc_t z = {0.f,0.f,0.f,0.f}; acc[ni] = z; }

  const int mrow  = m0 + l15;
  const int mload = mrow < NNODES ? mrow : NNODES - 1;  // clamp; masked at store

#pragma unroll
  for (int ks = 0; ks < 16; ++ks) {
    const int f0  = ks * 32 + quad * 8;            // feature index 0..511
    const int hop = f0 >> 7;
    const int j0  = f0 & 127;
    const unsigned short* ab =
        (hop == 0) ? agg0 : (hop == 1) ? agg1 : (hop == 2) ? agg2 : agg3;
    uint4 ua = *(const uint4*)&ab[(size_t)mload * NH + j0];
    const unsigned uu[4] = {ua.x, ua.y, ua.z, ua.w};
    unsigned pr[4];
#pragma unroll
    for (int q = 0; q < 4; ++q) {
      float lo = bf2f_lo(uu[q]);
      float hi = bf2f_hi(uu[q]);
      lo = lo > 0.f ? lo : (expf(lo) - 1.f);
      hi = hi > 0.f ? hi : (expf(hi) - 1.f);
      pr[q] = (unsigned)f2bf(lo) | ((unsigned)f2bf(hi) << 16);
    }
    uint4 ra; ra.x = pr[0]; ra.y = pr[1]; ra.z = pr[2]; ra.w = pr[3];
    bfrag_t af = *(bfrag_t*)&ra;
    bfrag_t bf[4];
#pragma unroll
    for (int ni = 0; ni < 4; ++ni) {
      const int n = ni * 16 + l15;
      bf[ni] = *(const bfrag_t*)&wot[(size_t)n * 512 + f0];
    }
#pragma unroll
    for (int ni = 0; ni < 4; ++ni)
      acc[ni] = __builtin_amdgcn_mfma_f32_16x16x32_bf16(af, bf[ni], acc[ni], 0, 0, 0);
  }

#pragma unroll
  for (int ni = 0; ni < 4; ++ni) {
    const int o = ni * 16 + l15;
    const float bo = bout[o];
#pragma unroll
    for (int r = 0; r < 4; ++r) {
      const int m = m0 + quad * 4 + r;
      if (m < NNODES) out[(size_t)m * NO + o] = acc[ni][r] + bo;
    }
  }
}

// ---------------------------------------------------------------------------
extern "C" void kernel_launch(void* const* d_in, const int* in_sizes, int n_in,
                              void* d_out, int out_size, void* d_ws, size_t ws_size,
                              hipStream_t stream) {
  const float* x     = (const float*)d_in[0];
  const float* W     = (const float*)d_in[1];
  const float* b     = (const float*)d_in[2];
  const float* W_out = (const float*)d_in[3];
  const float* b_out = (const float*)d_in[4];
  const int*   erows = (const int*)d_in[5];
  const int*   ecols = (const int*)d_in[6];
  const float* evals = (const float*)d_in[7];
  float* out = (float*)d_out;

  // ws layout (bytes), total ~117e6 (<128e6 known-safe):
  //   slots: 5 x NNODES*NH bf16 = 64.0e6
  //   xb: NPAD*NF bf16 = 25.7e6 (REUSED: bin staging; then agg1/agg3 bufs)
  //   Wt: 0.26e6 | ecsr: 25.6e6 | ints 1.6e6 | wot: 65.5e3
  unsigned short* slots = (unsigned short*)d_ws;
  unsigned short* xb = slots + (size_t)(NHOPS + 1) * NNODES * NH;
  unsigned short* Wt = xb + (size_t)NPAD * NF;
  unsigned long long* ecsr = (unsigned long long*)(Wt + (size_t)NHOPS * NH * NF);
  int* counts     = (int*)(ecsr + (size_t)NHOPS * NEDGES);
  int* offs       = counts + NHOPS * NNODES;
  int* bucketCur  = offs + NHOPS * (NNODES + 1);
  int* bucketBase = bucketCur + NHOPS * NB;
  unsigned short* wot = (unsigned short*)(bucketBase + NHOPS * (NB + 1));
  // staging aliases xb: xb dead after linear; staging dead after place.
  unsigned long long* staging = (unsigned long long*)xb;
  unsigned short* agg1buf = xb;                              // 12.8 MB
  unsigned short* agg3buf = xb + (size_t)NNODES * NH;        // 12.8 MB (fits 25.7)

  // bucketCur doubles as bucket-total accumulator for phaseA's hist1.
  hipMemsetAsync(bucketCur, 0, (size_t)NHOPS * NB * sizeof(int), stream);

  phaseA_kernel<<<CONVX_BLOCKS + CONVW_BLOCKS + HIST1_BLOCKS + WOT_BLOCKS,
                  256, 0, stream>>>(x, xb, W, Wt, erows, bucketCur, W_out, wot);
  scanB_kernel<<<NHOPS, 256, 0, stream>>>(bucketCur, bucketBase);
  linear_kernel<<<LIN_BLOCKS, 256, 0, stream>>>(xb, Wt, b, slots);
  bin_kernel<<<dim3(NB, NHOPS), 256, 0, stream>>>(
      erows, ecols, evals, bucketCur, staging);
  countscan_kernel<<<dim3(NB, NHOPS), 256, 0, stream>>>(
      bucketBase, staging, counts);
  scan_kernel<<<NHOPS, 1024, 0, stream>>>(counts, offs);
  place_kernel<<<dim3(NB, NHOPS), 256, 0, stream>>>(offs, staging, ecsr);

  // Pair A: g0 (R slot1, W slot0) || g1 (R slot2, W agg1buf) — disjoint.
  gather2_kernel<<<dim3(NNODES / 4, 2), 256, 0, stream>>>(
      offs, (const int2*)ecsr, slots, slots /*agg0 = slot0*/, agg1buf, 0);
  // Pair B: g2 (R slot3, W slot2) || g3 (R slot4, W agg3buf) — disjoint.
  // g2's write of slot2 is ordered after pair A's g1 read by the dispatch.
  gather2_kernel<<<dim3(NNODES / 4, 2), 256, 0, stream>>>(
      offs, (const int2*)ecsr, slots, slots + (size_t)2 * NNODES * NH, agg3buf, 2);

  out2_kernel<<<782, 256, 0, stream>>>(
      slots, agg1buf, slots + (size_t)2 * NNODES * NH, agg3buf,
      wot, b_out, out);
}

// Round 17
// 424.618 us; speedup vs baseline: 2.1014x; 1.0246x over previous
//
#include <hip/hip_runtime.h>
#include <hip/hip_bf16.h>
#include <math.h>

#define NNODES 50000
#define NPAD   50176              // 392*128, padded rows for MFMA tile overrun
#define NEDGES 800000
#define NHOPS  4
#define NF     256
#define NH     128
#define NO     64
#define NB     196                // row buckets of 256 rows (50000/256 -> 196)
#define EPB    4096               // edges per bin block (256 thr x 16)

#define CONVX_BLOCKS 12500        // NNODES*NF/4/256
#define CONVW_BLOCKS 512          // NHOPS*NH*NF/256
#define HIST1_BLOCKS (NB * NHOPS) // 784: bucket-level LDS hist (R7)
#define WOT_BLOCKS   128          // 64*512/256 (Wout^T -> bf16)
#define LIN_PER_HOP  391          // ceil(NNODES/128)
#define LIN_BLOCKS   1568         // 49 groups x 32 (R13 XCD-swizzled mapping)
#define ASTR 40                   // A-stage LDS row stride (ushorts)
#define CPAD 132                  // epilogue LDS row stride (ushorts)

typedef __attribute__((ext_vector_type(8))) short bfrag_t;   // 8 x bf16
typedef __attribute__((ext_vector_type(4))) float facc_t;    // 4 x f32

static __device__ __forceinline__ unsigned short f2bf(float f) {
  unsigned int u = __float_as_uint(f);
  unsigned int r = (u + 0x7fffu + ((u >> 16) & 1u)) >> 16;
  return (unsigned short)r;
}
static __device__ __forceinline__ float bf2f_lo(unsigned int u) {
  return __uint_as_float(u << 16);
}
static __device__ __forceinline__ float bf2f_hi(unsigned int u) {
  return __uint_as_float(u & 0xffff0000u);
}

// ---------------------------------------------------------------------------
// Phase A (fused): convx | convw | hist1 | wot. All independent.
// ---------------------------------------------------------------------------
__global__ __launch_bounds__(256) void phaseA_kernel(
    const float* __restrict__ x, unsigned short* __restrict__ xb,
    const float* __restrict__ W, unsigned short* __restrict__ Wt,
    const int* __restrict__ erows, int* __restrict__ bucketCur,
    const float* __restrict__ Wout, unsigned short* __restrict__ wot) {
  const int bx = blockIdx.x;
  const int t  = threadIdx.x;
  if (bx < CONVX_BLOCKS) {
    const size_t i = ((size_t)bx * 256 + t) * 4;
    float4 v = *(const float4*)&x[i];
    ushort4 o;
    o.x = f2bf(v.x); o.y = f2bf(v.y); o.z = f2bf(v.z); o.w = f2bf(v.w);
    *(ushort4*)&xb[i] = o;
  } else if (bx < CONVX_BLOCKS + CONVW_BLOCKS) {
    const int i = (bx - CONVX_BLOCKS) * 256 + t;
    const int k = i / (NH * NF);
    const int rem = i - k * NH * NF;
    const int n = rem / NF;
    const int f = rem - n * NF;
    Wt[i] = f2bf(W[(size_t)k * NF * NH + (size_t)f * NH + n]);
  } else if (bx < CONVX_BLOCKS + CONVW_BLOCKS + HIST1_BLOCKS) {
    const int id  = bx - (CONVX_BLOCKS + CONVW_BLOCKS);
    const int hop = id / NB;
    const int bb  = (id - hop * NB) * EPB;
    __shared__ int bh[NB];
    for (int i = t; i < NB; i += 256) bh[i] = 0;
    __syncthreads();
    const size_t g0 = (size_t)hop * NEDGES;
#pragma unroll
    for (int k = 0; k < 4; ++k) {
      const int e0 = bb + t * 4 + k * 1024;
      if (e0 + 3 < NEDGES) {
        const int4 rr = *(const int4*)&erows[g0 + e0];
        atomicAdd(&bh[rr.x >> 8], 1);
        atomicAdd(&bh[rr.y >> 8], 1);
        atomicAdd(&bh[rr.z >> 8], 1);
        atomicAdd(&bh[rr.w >> 8], 1);
      } else {
        for (int j = 0; j < 4; ++j)
          if (e0 + j < NEDGES) atomicAdd(&bh[erows[g0 + e0 + j] >> 8], 1);
      }
    }
    __syncthreads();
    for (int i = t; i < NB; i += 256)
      if (bh[i]) atomicAdd(&bucketCur[hop * NB + i], bh[i]);
  } else {
    // Wout^T -> bf16: wot[o][f] = bf16(Wout[f][o]); reads coalesced.
    const int i = (bx - (CONVX_BLOCKS + CONVW_BLOCKS + HIST1_BLOCKS)) * 256 + t;
    const int o = i & 63;
    const int f = i >> 6;
    wot[(size_t)o * 512 + f] = f2bf(Wout[(size_t)f * NO + o]);
  }
}

// ---------------------------------------------------------------------------
// Per-hop exclusive scan of 196 bucket totals. bucketCur -> bases (bin's
// allocator); bucketBase immutable (countscan). bucketBase[b] == offs[b*256].
// ---------------------------------------------------------------------------
__global__ __launch_bounds__(256) void scanB_kernel(
    int* __restrict__ bucketCur, int* __restrict__ bucketBase) {
  const int hop = blockIdx.x;
  const int t   = threadIdx.x;
  __shared__ int tot[NB];
  for (int i = t; i < NB; i += 256) tot[i] = bucketCur[hop * NB + i];
  __syncthreads();
  if (t == 0) {
    int run = 0;
    for (int i = 0; i < NB; ++i) { const int c = tot[i]; tot[i] = run; run += c; }
  }
  __syncthreads();
  for (int i = t; i < NB; i += 256) {
    bucketCur[hop * NB + i]        = tot[i];
    bucketBase[hop * (NB + 1) + i] = tot[i];
  }
  if (t == 0) bucketBase[hop * (NB + 1) + NB] = NEDGES;
}

// ---------------------------------------------------------------------------
// Linear via MFMA, all 4 hops in one dispatch.
// R16: RESTORED R13 body (A-tile LDS staging + union epilogue + XCD
// swizzle) — measured 56us. R14's revert to direct xb reads regressed to
// 77us: at 17% occupancy the staged cooperative-coalesced loads + LDS
// reads hide L2-hit latency far better than per-lane scattered bfrag
// gathers; the barriers/conflicts I blamed cost only ~2-3us. (R13 XCD
// swizzle keeps FETCH at 14MB = cross-hop L2 reuse.)
// ---------------------------------------------------------------------------
__global__ __launch_bounds__(256) void linear_kernel(
    const unsigned short* __restrict__ xb, const unsigned short* __restrict__ Wt,
    const float* __restrict__ b, unsigned short* __restrict__ slots) {
  const int lb  = blockIdx.x;
  const int g   = lb >> 5;
  const int rr_ = lb & 31;
  const int hop = rr_ >> 3;
  const int xx  = rr_ & 7;
  const int mb  = g * 8 + xx;
  if (mb >= LIN_PER_HOP) return;
  const unsigned short* Wk = Wt + (size_t)hop * NH * NF;
  const float* bk = b + hop * NH;
  unsigned short* hb = slots + (size_t)(hop + 1) * NNODES * NH;

  const int t    = threadIdx.x;
  const int lane = t & 63;
  const int wave = t >> 6;
  const int wm   = (wave >> 1) * 64;
  const int wn   = (wave & 1) * 64;
  const int m0   = mb * 128;
  const int l15  = lane & 15;
  const int quad = lane >> 4;

  // union: as_[128][ASTR] during k-loop / cs[64][CPAD] epilogue
  __shared__ unsigned short smem[10240];
  unsigned short* as_ = smem;
  unsigned short* cs  = smem;

  facc_t acc[4][4];
#pragma unroll
  for (int i = 0; i < 4; ++i)
#pragma unroll
    for (int j = 0; j < 4; ++j) {
      facc_t z = {0.f, 0.f, 0.f, 0.f};
      acc[i][j] = z;
    }

#pragma unroll
  for (int k0 = 0; k0 < NF; k0 += 32) {
    __syncthreads();   // previous iteration's as_ reads complete
    // stage A: 128 rows x 32 cols (64B/row); thread t: row t>>2, 16B chunk t&3
#pragma unroll
    for (int it = 0; it < 2; ++it) {
      const int row = it * 64 + (t >> 2);
      const int ch  = t & 3;
      const uint4 v = *(const uint4*)&xb[(size_t)(m0 + row) * NF + k0 + ch * 8];
      *(uint4*)&as_[row * ASTR + ch * 8] = v;
    }
    __syncthreads();

    bfrag_t a[4], bb[4];
#pragma unroll
    for (int mi = 0; mi < 4; ++mi)
      a[mi] = *(const bfrag_t*)&as_[(wm + mi * 16 + l15) * ASTR + quad * 8];
#pragma unroll
    for (int ni = 0; ni < 4; ++ni) {
      const int n = wn + ni * 16 + l15;
      bb[ni] = *(const bfrag_t*)&Wk[(size_t)n * NF + k0 + quad * 8];
    }
#pragma unroll
    for (int mi = 0; mi < 4; ++mi)
#pragma unroll
      for (int ni = 0; ni < 4; ++ni)
        acc[mi][ni] = __builtin_amdgcn_mfma_f32_16x16x32_bf16(
            a[mi], bb[ni], acc[mi][ni], 0, 0, 0);
  }

  // ---- epilogue: two 64-row halves through cs[64][CPAD] ----
#pragma unroll
  for (int half = 0; half < 2; ++half) {
    __syncthreads();
    if ((wave >> 1) == half) {
#pragma unroll
      for (int ni = 0; ni < 4; ++ni) {
        const int nl = wn + ni * 16 + l15;
        const float bias = bk[nl];
#pragma unroll
        for (int mi = 0; mi < 4; ++mi) {
#pragma unroll
          for (int r = 0; r < 4; ++r) {
            const int ml = mi * 16 + quad * 4 + r;   // 0..63 within half
            cs[ml * CPAD + nl] = f2bf(acc[mi][ni][r] + bias);
          }
        }
      }
    }
    __syncthreads();
    const int chunk = t & 15;          // 16B chunk within a 256B row
    const int rowb  = t >> 4;          // 16 rows per iteration
#pragma unroll
    for (int it = 0; it < 4; ++it) {
      const int row = it * 16 + rowb;
      const int m   = m0 + half * 64 + row;
      const uint4 v = *(const uint4*)&cs[row * CPAD + chunk * 8];
      if (m < NNODES) *(uint4*)&hb[(size_t)m * NH + chunk * 8] = v;
    }
  }
}

// ---------------------------------------------------------------------------
// Bin pass: rank 4096 edges per block into 196 row-buckets via LDS hist;
// ONE global atomicAdd per (block,bucket) reserves space; edges written in
// ~21-entry contiguous runs into bucket-partitioned staging (aliases dead
// xb). pack: val(hi32) | rowlo<<16 | col. grid (196, NHOPS).
// ---------------------------------------------------------------------------
__global__ __launch_bounds__(256) void bin_kernel(
    const int* __restrict__ erows, const int* __restrict__ ecols,
    const float* __restrict__ evals, int* __restrict__ bucketCur,
    unsigned long long* __restrict__ staging) {
  const int hop = blockIdx.y;
  const int t   = threadIdx.x;
  const int bb  = blockIdx.x * EPB;
  __shared__ int lhist[NB];
  __shared__ int gbase[NB];
  for (int i = t; i < NB; i += 256) lhist[i] = 0;
  __syncthreads();

  unsigned long long pk[16];
  int bkt[16], rnk[16];
  const size_t g0 = (size_t)hop * NEDGES;
#pragma unroll
  for (int k = 0; k < 4; ++k) {
    const int e0 = bb + t * 4 + k * 1024;
    if (e0 + 3 < NEDGES) {
      const int4   rr = *(const int4*)&erows[g0 + e0];
      const int4   cc = *(const int4*)&ecols[g0 + e0];
      const float4 vv = *(const float4*)&evals[g0 + e0];
      const int r4[4] = {rr.x, rr.y, rr.z, rr.w};
      const int c4[4] = {cc.x, cc.y, cc.z, cc.w};
      const float v4[4] = {vv.x, vv.y, vv.z, vv.w};
#pragma unroll
      for (int j = 0; j < 4; ++j) {
        const int b = r4[j] >> 8;
        bkt[k * 4 + j] = b;
        rnk[k * 4 + j] = atomicAdd(&lhist[b], 1);
        pk[k * 4 + j] =
            ((unsigned long long)__float_as_uint(v4[j]) << 32) |
            ((unsigned)(r4[j] & 255) << 16) | (unsigned)c4[j];
      }
    } else {
#pragma unroll
      for (int j = 0; j < 4; ++j) {
        const int e = e0 + j;
        if (e < NEDGES) {
          const int r = erows[g0 + e];
          const int b = r >> 8;
          bkt[k * 4 + j] = b;
          rnk[k * 4 + j] = atomicAdd(&lhist[b], 1);
          pk[k * 4 + j] =
              ((unsigned long long)__float_as_uint(evals[g0 + e]) << 32) |
              ((unsigned)(r & 255) << 16) | (unsigned)ecols[g0 + e];
        } else {
          bkt[k * 4 + j] = -1;
        }
      }
    }
  }
  __syncthreads();
  for (int i = t; i < NB; i += 256) {
    const int c = lhist[i];
    gbase[i] = c ? atomicAdd(&bucketCur[hop * NB + i], c) : 0;
  }
  __syncthreads();
  unsigned long long* dst = staging + (size_t)hop * NEDGES;
#pragma unroll
  for (int q = 0; q < 16; ++q)
    if (bkt[q] >= 0) dst[gbase[bkt[q]] + rnk[q]] = pk[q];
}

// ---------------------------------------------------------------------------
// Per-row counts from staged edges: one block per (bucket,hop), LDS 256-bin
// histogram of rowlo, coalesced write to counts.
// ---------------------------------------------------------------------------
__global__ __launch_bounds__(256) void countscan_kernel(
    const int* __restrict__ bucketBase,
    const unsigned long long* __restrict__ staging, int* __restrict__ counts) {
  const int hop = blockIdx.y;
  const int b   = blockIdx.x;
  const int t   = threadIdx.x;
  const int s = bucketBase[hop * (NB + 1) + b];
  const int e = bucketBase[hop * (NB + 1) + b + 1];
  __shared__ int h[256];
  h[t] = 0;
  __syncthreads();
  const unsigned long long* src = staging + (size_t)hop * NEDGES;
  for (int i = s + t; i < e; i += 256) {
    const int rl = ((unsigned)src[i] >> 16) & 255;
    atomicAdd(&h[rl], 1);
  }
  __syncthreads();
  const int r0 = b * 256;
  if (r0 + t < NNODES) counts[hop * NNODES + r0 + t] = h[t];
}

// ---------------------------------------------------------------------------
// CSR build: exclusive scan per hop over per-row counts.
// ---------------------------------------------------------------------------
__global__ __launch_bounds__(1024) void scan_kernel(
    const int* __restrict__ counts, int* __restrict__ offs) {
  const int hop  = blockIdx.x;
  const int t    = threadIdx.x;
  const int lane = t & 63;
  const int wid  = t >> 6;
  __shared__ int wsum[16];
  __shared__ int carry_s;
  if (t == 0) carry_s = 0;
  __syncthreads();
  const int CH  = 8192;
  const int nch = (NNODES + CH - 1) / CH;     // 7
  for (int ch = 0; ch < nch; ++ch) {
    const int i0 = ch * CH + t * 8;
    int v[8];
    if (i0 + 7 < NNODES) {
      int4 a = *(const int4*)&counts[hop * NNODES + i0];
      int4 b = *(const int4*)&counts[hop * NNODES + i0 + 4];
      v[0]=a.x; v[1]=a.y; v[2]=a.z; v[3]=a.w;
      v[4]=b.x; v[5]=b.y; v[6]=b.z; v[7]=b.w;
    } else {
#pragma unroll
      for (int j = 0; j < 8; ++j)
        v[j] = (i0 + j < NNODES) ? counts[hop * NNODES + i0 + j] : 0;
    }
    int l[8];
    int run = 0;
#pragma unroll
    for (int j = 0; j < 8; ++j) { run += v[j]; l[j] = run; }   // inclusive
    int s = run;
#pragma unroll
    for (int d = 1; d < 64; d <<= 1) {
      int n = __shfl_up(s, d, 64);
      if (lane >= d) s += n;
    }
    if (lane == 63) wsum[wid] = s;
    __syncthreads();
    if (t < 16) {
      int ws = wsum[t];
#pragma unroll
      for (int d = 1; d < 16; d <<= 1) {
        int n = __shfl_up(ws, d, 16);
        if (t >= d) ws += n;
      }
      wsum[t] = ws;
    }
    __syncthreads();
    const int base = carry_s + (wid ? wsum[wid - 1] : 0) + (s - run);
    if (i0 + 7 < NNODES) {
      int4 o0 = make_int4(base, base + l[0], base + l[1], base + l[2]);
      int4 o1 = make_int4(base + l[3], base + l[4], base + l[5], base + l[6]);
      *(int4*)&offs[hop * (NNODES + 1) + i0]     = o0;
      *(int4*)&offs[hop * (NNODES + 1) + i0 + 4] = o1;
    } else {
#pragma unroll
      for (int j = 0; j < 8; ++j) {
        if (i0 + j < NNODES) {
          const int excl = base + (l[j] - v[j]);
          offs[hop * (NNODES + 1) + i0 + j] = excl;
        }
      }
    }
    __syncthreads();
    if (t == 0) carry_s += wsum[15];
    __syncthreads();
  }
  if (t == 0) offs[hop * (NNODES + 1) + NNODES] = carry_s;
}

// ---------------------------------------------------------------------------
// Place pass: one block per (bucket,hop). Sequential read of the bucket's
// staging segment; exact CSR position via LDS row cursors (no global
// atomics). All writes land in this block's own 32KB window.
// ---------------------------------------------------------------------------
__global__ __launch_bounds__(256) void place_kernel(
    const int* __restrict__ offs, const unsigned long long* __restrict__ staging,
    unsigned long long* __restrict__ ecsr) {
  const int hop = blockIdx.y;
  const int bk  = blockIdx.x;
  const int t   = threadIdx.x;
  const int r0  = bk * 256;
  const int nr  = (NNODES - r0 < 256) ? (NNODES - r0) : 256;
  const int* o = offs + (size_t)hop * (NNODES + 1);
  __shared__ int cur[257];
  for (int i = t; i <= nr; i += 256) cur[i] = o[r0 + i];
  __syncthreads();
  const int s = cur[0];
  const int e = cur[nr];          // never touched by atomics (rowlo < nr)
  __syncthreads();                // snapshot s,e before any cursor bumps
  const unsigned long long* src = staging + (size_t)hop * NEDGES;
  unsigned long long* dst       = ecsr + (size_t)hop * NEDGES;
  for (int i = s + t; i < e; i += 256) {
    const unsigned long long v = src[i];
    const unsigned lo = (unsigned)v;
    const int rl = (lo >> 16) & 255;
    const int d = atomicAdd(&cur[rl], 1);
    dst[d] = (v & 0xFFFFFFFF00000000ull) | (unsigned long long)(lo & 0xFFFFu);
  }
}

// ---------------------------------------------------------------------------
// Paired gather SpMM: TWO hops per dispatch (blockIdx.y picks hop).
// {g0,g1} and {g2,g3} are write-disjoint (agg1/agg3 into dead staging);
// cross-pair WAR ordered by the dispatch boundary. R14-measured: pairing
// saved ~20-25us vs 4 sequential dispatches.
// ---------------------------------------------------------------------------
__global__ __launch_bounds__(256) void gather2_kernel(
    const int* __restrict__ offs, const int2* __restrict__ ecsr,
    const unsigned short* __restrict__ slots,
    unsigned short* __restrict__ aggA, unsigned short* __restrict__ aggB,
    int hop0) {
  const int y    = blockIdx.y;
  const int hop  = hop0 + y;
  const int* off = offs + (size_t)hop * (NNODES + 1);
  const int2* ec = ecsr + (size_t)hop * NEDGES;
  const unsigned short* hb = slots + (size_t)(hop + 1) * NNODES * NH;
  unsigned short* aggb = y ? aggB : aggA;

  const int t    = threadIdx.x;
  const int lane = t & 63;
  const int wid  = t >> 6;
  const int r = blockIdx.x * 4 + wid;
  const int g  = lane >> 4;    // edge subgroup 0..3
  const int sl = lane & 15;    // feature slice: feats sl*8 .. sl*8+7
  const int s = off[r];
  const int e = off[r + 1];

  float acc[8];
#pragma unroll
  for (int j = 0; j < 8; ++j) acc[j] = 0.f;

  for (int p = s; p < e; p += 16) {
    int2 ed[4];
#pragma unroll
    for (int q = 0; q < 4; ++q) {
      const int idx = p + q * 4 + g;
      ed[q] = (idx < e) ? ec[idx] : make_int2(0, 0);
    }
    uint4 hv[4];
#pragma unroll
    for (int q = 0; q < 4; ++q)
      hv[q] = *(const uint4*)&hb[(size_t)ed[q].x * NH + sl * 8];
#pragma unroll
    for (int q = 0; q < 4; ++q) {
      const float v = __int_as_float(ed[q].y);
      acc[0] += v * bf2f_lo(hv[q].x);
      acc[1] += v * bf2f_hi(hv[q].x);
      acc[2] += v * bf2f_lo(hv[q].y);
      acc[3] += v * bf2f_hi(hv[q].y);
      acc[4] += v * bf2f_lo(hv[q].z);
      acc[5] += v * bf2f_hi(hv[q].z);
      acc[6] += v * bf2f_lo(hv[q].w);
      acc[7] += v * bf2f_hi(hv[q].w);
    }
  }

#pragma unroll
  for (int j = 0; j < 8; ++j) {
    acc[j] += __shfl_xor(acc[j], 16, 64);
    acc[j] += __shfl_xor(acc[j], 32, 64);
  }

  if (g == 0) {
    uint4 o;
    o.x = (unsigned)f2bf(acc[0]) | ((unsigned)f2bf(acc[1]) << 16);
    o.y = (unsigned)f2bf(acc[2]) | ((unsigned)f2bf(acc[3]) << 16);
    o.z = (unsigned)f2bf(acc[4]) | ((unsigned)f2bf(acc[5]) << 16);
    o.w = (unsigned)f2bf(acc[6]) | ((unsigned)f2bf(acc[7]) << 16);
    *(uint4*)&aggb[(size_t)r * NH + sl * 8] = o;
  }
}

// ---------------------------------------------------------------------------
// Output GEMM via MFMA: out[50000,64] = elu(concat) @ Wout + bout.
// 782 blocks x 4 waves, each wave 16 rows x 64 cols, K=512 in 16 steps.
// agg inputs come from 4 per-hop base pointers (agg1/agg3 in staging).
// ---------------------------------------------------------------------------
__global__ __launch_bounds__(256) void out2_kernel(
    const unsigned short* __restrict__ agg0, const unsigned short* __restrict__ agg1,
    const unsigned short* __restrict__ agg2, const unsigned short* __restrict__ agg3,
    const unsigned short* __restrict__ wot,    // [64][512] bf16 Wout^T
    const float* __restrict__ bout, float* __restrict__ out) {
  const int t    = threadIdx.x;
  const int lane = t & 63;
  const int wave = t >> 6;
  const int l15  = lane & 15;
  const int quad = lane >> 4;
  const int m0   = blockIdx.x * 64 + wave * 16;   // 16 rows per wave

  facc_t acc[4];
#pragma unroll
  for (int ni = 0; ni < 4; ++ni) { facc_t z = {0.f,0.f,0.f,0.f}; acc[ni] = z; }

  const int mrow  = m0 + l15;
  const int mload = mrow < NNODES ? mrow : NNODES - 1;  // clamp; masked at store

#pragma unroll
  for (int ks = 0; ks < 16; ++ks) {
    const int f0  = ks * 32 + quad * 8;            // feature index 0..511
    const int hop = f0 >> 7;
    const int j0  = f0 & 127;
    const unsigned short* ab =
        (hop == 0) ? agg0 : (hop == 1) ? agg1 : (hop == 2) ? agg2 : agg3;
    uint4 ua = *(const uint4*)&ab[(size_t)mload * NH + j0];
    const unsigned uu[4] = {ua.x, ua.y, ua.z, ua.w};
    unsigned pr[4];
#pragma unroll
    for (int q = 0; q < 4; ++q) {
      float lo = bf2f_lo(uu[q]);
      float hi = bf2f_hi(uu[q]);
      lo = lo > 0.f ? lo : (expf(lo) - 1.f);
      hi = hi > 0.f ? hi : (expf(hi) - 1.f);
      pr[q] = (unsigned)f2bf(lo) | ((unsigned)f2bf(hi) << 16);
    }
    uint4 ra; ra.x = pr[0]; ra.y = pr[1]; ra.z = pr[2]; ra.w = pr[3];
    bfrag_t af = *(bfrag_t*)&ra;
    bfrag_t bf[4];
#pragma unroll
    for (int ni = 0; ni < 4; ++ni) {
      const int n = ni * 16 + l15;
      bf[ni] = *(const bfrag_t*)&wot[(size_t)n * 512 + f0];
    }
#pragma unroll
    for (int ni = 0; ni < 4; ++ni)
      acc[ni] = __builtin_amdgcn_mfma_f32_16x16x32_bf16(af, bf[ni], acc[ni], 0, 0, 0);
  }

#pragma unroll
  for (int ni = 0; ni < 4; ++ni) {
    const int o = ni * 16 + l15;
    const float bo = bout[o];
#pragma unroll
    for (int r = 0; r < 4; ++r) {
      const int m = m0 + quad * 4 + r;
      if (m < NNODES) out[(size_t)m * NO + o] = acc[ni][r] + bo;
    }
  }
}

// ---------------------------------------------------------------------------
extern "C" void kernel_launch(void* const* d_in, const int* in_sizes, int n_in,
                              void* d_out, int out_size, void* d_ws, size_t ws_size,
                              hipStream_t stream) {
  const float* x     = (const float*)d_in[0];
  const float* W     = (const float*)d_in[1];
  const float* b     = (const float*)d_in[2];
  const float* W_out = (const float*)d_in[3];
  const float* b_out = (const float*)d_in[4];
  const int*   erows = (const int*)d_in[5];
  const int*   ecols = (const int*)d_in[6];
  const float* evals = (const float*)d_in[7];
  float* out = (float*)d_out;

  // ws layout (bytes), total ~117e6 (<128e6 known-safe):
  //   slots: 5 x NNODES*NH bf16 = 64.0e6
  //   xb: NPAD*NF bf16 = 25.7e6 (REUSED: bin staging; then agg1/agg3 bufs)
  //   Wt: 0.26e6 | ecsr: 25.6e6 | ints 1.6e6 | wot: 65.5e3
  unsigned short* slots = (unsigned short*)d_ws;
  unsigned short* xb = slots + (size_t)(NHOPS + 1) * NNODES * NH;
  unsigned short* Wt = xb + (size_t)NPAD * NF;
  unsigned long long* ecsr = (unsigned long long*)(Wt + (size_t)NHOPS * NH * NF);
  int* counts     = (int*)(ecsr + (size_t)NHOPS * NEDGES);
  int* offs       = counts + NHOPS * NNODES;
  int* bucketCur  = offs + NHOPS * (NNODES + 1);
  int* bucketBase = bucketCur + NHOPS * NB;
  unsigned short* wot = (unsigned short*)(bucketBase + NHOPS * (NB + 1));
  // staging aliases xb: xb dead after linear; staging dead after place.
  unsigned long long* staging = (unsigned long long*)xb;
  unsigned short* agg1buf = xb;                              // 12.8 MB
  unsigned short* agg3buf = xb + (size_t)NNODES * NH;        // 12.8 MB (fits 25.7)

  // bucketCur doubles as bucket-total accumulator for phaseA's hist1.
  hipMemsetAsync(bucketCur, 0, (size_t)NHOPS * NB * sizeof(int), stream);

  phaseA_kernel<<<CONVX_BLOCKS + CONVW_BLOCKS + HIST1_BLOCKS + WOT_BLOCKS,
                  256, 0, stream>>>(x, xb, W, Wt, erows, bucketCur, W_out, wot);
  scanB_kernel<<<NHOPS, 256, 0, stream>>>(bucketCur, bucketBase);
  linear_kernel<<<LIN_BLOCKS, 256, 0, stream>>>(xb, Wt, b, slots);
  bin_kernel<<<dim3(NB, NHOPS), 256, 0, stream>>>(
      erows, ecols, evals, bucketCur, staging);
  countscan_kernel<<<dim3(NB, NHOPS), 256, 0, stream>>>(
      bucketBase, staging, counts);
  scan_kernel<<<NHOPS, 1024, 0, stream>>>(counts, offs);
  place_kernel<<<dim3(NB, NHOPS), 256, 0, stream>>>(offs, staging, ecsr);

  // Pair A: g0 (R slot1, W slot0) || g1 (R slot2, W agg1buf) — disjoint.
  gather2_kernel<<<dim3(NNODES / 4, 2), 256, 0, stream>>>(
      offs, (const int2*)ecsr, slots, slots /*agg0 = slot0*/, agg1buf, 0);
  // Pair B: g2 (R slot3, W slot2) || g3 (R slot4, W agg3buf) — disjoint.
  // g2's write of slot2 is ordered after pair A's g1 read by the dispatch.
  gather2_kernel<<<dim3(NNODES / 4, 2), 256, 0, stream>>>(
      offs, (const int2*)ecsr, slots, slots + (size_t)2 * NNODES * NH, agg3buf, 2);

  out2_kernel<<<782, 256, 0, stream>>>(
      slots, agg1buf, slots + (size_t)2 * NNODES * NH, agg3buf,
      wot, b_out, out);
}

// Round 21
// 424.273 us; speedup vs baseline: 2.1031x; 1.0008x over previous
//
#include <hip/hip_runtime.h>
#include <hip/hip_bf16.h>
#include <math.h>

#define NNODES 50000
#define NPAD   50176              // 392*128, padded rows for MFMA tile overrun
#define NEDGES 800000
#define NHOPS  4
#define NF     256
#define NH     128
#define NO     64
#define NB     196                // row buckets of 256 rows (50000/256 -> 196)
#define EPB    4096               // edges per bin block (256 thr x 16)

#define CONVX_BLOCKS 12500        // NNODES*NF/4/256
#define CONVW_BLOCKS 512          // NHOPS*NH*NF/256
#define HIST1_BLOCKS (NB * NHOPS) // 784: bucket-level LDS hist (R7)
#define WOT_BLOCKS   128          // 64*512/256 (Wout^T -> bf16)
#define LIN_PER_HOP  391          // ceil(NNODES/128)
#define LIN_BLOCKS   1568         // 49 groups x 32 (R13 XCD-swizzled mapping)
#define ASTR 40                   // A-stage LDS row stride (ushorts)
#define CPAD 132                  // epilogue LDS row stride (ushorts)

typedef __attribute__((ext_vector_type(8))) short bfrag_t;   // 8 x bf16
typedef __attribute__((ext_vector_type(4))) float facc_t;    // 4 x f32

static __device__ __forceinline__ unsigned short f2bf(float f) {
  unsigned int u = __float_as_uint(f);
  unsigned int r = (u + 0x7fffu + ((u >> 16) & 1u)) >> 16;
  return (unsigned short)r;
}
static __device__ __forceinline__ float bf2f_lo(unsigned int u) {
  return __uint_as_float(u << 16);
}
static __device__ __forceinline__ float bf2f_hi(unsigned int u) {
  return __uint_as_float(u & 0xffff0000u);
}

// ---------------------------------------------------------------------------
// Phase A (fused): convx | convw | hist1 | wot. All independent.
// ---------------------------------------------------------------------------
__global__ __launch_bounds__(256) void phaseA_kernel(
    const float* __restrict__ x, unsigned short* __restrict__ xb,
    const float* __restrict__ W, unsigned short* __restrict__ Wt,
    const int* __restrict__ erows, int* __restrict__ bucketCur,
    const float* __restrict__ Wout, unsigned short* __restrict__ wot) {
  const int bx = blockIdx.x;
  const int t  = threadIdx.x;
  if (bx < CONVX_BLOCKS) {
    const size_t i = ((size_t)bx * 256 + t) * 4;
    float4 v = *(const float4*)&x[i];
    ushort4 o;
    o.x = f2bf(v.x); o.y = f2bf(v.y); o.z = f2bf(v.z); o.w = f2bf(v.w);
    *(ushort4*)&xb[i] = o;
  } else if (bx < CONVX_BLOCKS + CONVW_BLOCKS) {
    const int i = (bx - CONVX_BLOCKS) * 256 + t;
    const int k = i / (NH * NF);
    const int rem = i - k * NH * NF;
    const int n = rem / NF;
    const int f = rem - n * NF;
    Wt[i] = f2bf(W[(size_t)k * NF * NH + (size_t)f * NH + n]);
  } else if (bx < CONVX_BLOCKS + CONVW_BLOCKS + HIST1_BLOCKS) {
    const int id  = bx - (CONVX_BLOCKS + CONVW_BLOCKS);
    const int hop = id / NB;
    const int bb  = (id - hop * NB) * EPB;
    __shared__ int bh[NB];
    for (int i = t; i < NB; i += 256) bh[i] = 0;
    __syncthreads();
    const size_t g0 = (size_t)hop * NEDGES;
#pragma unroll
    for (int k = 0; k < 4; ++k) {
      const int e0 = bb + t * 4 + k * 1024;
      if (e0 + 3 < NEDGES) {
        const int4 rr = *(const int4*)&erows[g0 + e0];
        atomicAdd(&bh[rr.x >> 8], 1);
        atomicAdd(&bh[rr.y >> 8], 1);
        atomicAdd(&bh[rr.z >> 8], 1);
        atomicAdd(&bh[rr.w >> 8], 1);
      } else {
        for (int j = 0; j < 4; ++j)
          if (e0 + j < NEDGES) atomicAdd(&bh[erows[g0 + e0 + j] >> 8], 1);
      }
    }
    __syncthreads();
    for (int i = t; i < NB; i += 256)
      if (bh[i]) atomicAdd(&bucketCur[hop * NB + i], bh[i]);
  } else {
    // Wout^T -> bf16: wot[o][f] = bf16(Wout[f][o]); reads coalesced.
    const int i = (bx - (CONVX_BLOCKS + CONVW_BLOCKS + HIST1_BLOCKS)) * 256 + t;
    const int o = i & 63;
    const int f = i >> 6;
    wot[(size_t)o * 512 + f] = f2bf(Wout[(size_t)f * NO + o]);
  }
}

// ---------------------------------------------------------------------------
// Per-hop exclusive scan of 196 bucket totals. bucketCur -> bases (bin's
// allocator); bucketBase immutable (countscan). bucketBase[b] == offs[b*256].
// ---------------------------------------------------------------------------
__global__ __launch_bounds__(256) void scanB_kernel(
    int* __restrict__ bucketCur, int* __restrict__ bucketBase) {
  const int hop = blockIdx.x;
  const int t   = threadIdx.x;
  __shared__ int tot[NB];
  for (int i = t; i < NB; i += 256) tot[i] = bucketCur[hop * NB + i];
  __syncthreads();
  if (t == 0) {
    int run = 0;
    for (int i = 0; i < NB; ++i) { const int c = tot[i]; tot[i] = run; run += c; }
  }
  __syncthreads();
  for (int i = t; i < NB; i += 256) {
    bucketCur[hop * NB + i]        = tot[i];
    bucketBase[hop * (NB + 1) + i] = tot[i];
  }
  if (t == 0) bucketBase[hop * (NB + 1) + NB] = NEDGES;
}

// ---------------------------------------------------------------------------
// Linear via MFMA, all 4 hops in one dispatch. R13 body: A-tile LDS staging
// + union epilogue + XCD swizzle (FETCH 14MB, 56us measured).
// ---------------------------------------------------------------------------
__global__ __launch_bounds__(256) void linear_kernel(
    const unsigned short* __restrict__ xb, const unsigned short* __restrict__ Wt,
    const float* __restrict__ b, unsigned short* __restrict__ slots) {
  const int lb  = blockIdx.x;
  const int g   = lb >> 5;
  const int rr_ = lb & 31;
  const int hop = rr_ >> 3;
  const int xx  = rr_ & 7;
  const int mb  = g * 8 + xx;
  if (mb >= LIN_PER_HOP) return;
  const unsigned short* Wk = Wt + (size_t)hop * NH * NF;
  const float* bk = b + hop * NH;
  unsigned short* hb = slots + (size_t)(hop + 1) * NNODES * NH;

  const int t    = threadIdx.x;
  const int lane = t & 63;
  const int wave = t >> 6;
  const int wm   = (wave >> 1) * 64;
  const int wn   = (wave & 1) * 64;
  const int m0   = mb * 128;
  const int l15  = lane & 15;
  const int quad = lane >> 4;

  // union: as_[128][ASTR] during k-loop / cs[64][CPAD] epilogue
  __shared__ unsigned short smem[10240];
  unsigned short* as_ = smem;
  unsigned short* cs  = smem;

  facc_t acc[4][4];
#pragma unroll
  for (int i = 0; i < 4; ++i)
#pragma unroll
    for (int j = 0; j < 4; ++j) {
      facc_t z = {0.f, 0.f, 0.f, 0.f};
      acc[i][j] = z;
    }

#pragma unroll
  for (int k0 = 0; k0 < NF; k0 += 32) {
    __syncthreads();   // previous iteration's as_ reads complete
    // stage A: 128 rows x 32 cols (64B/row); thread t: row t>>2, 16B chunk t&3
#pragma unroll
    for (int it = 0; it < 2; ++it) {
      const int row = it * 64 + (t >> 2);
      const int ch  = t & 3;
      const uint4 v = *(const uint4*)&xb[(size_t)(m0 + row) * NF + k0 + ch * 8];
      *(uint4*)&as_[row * ASTR + ch * 8] = v;
    }
    __syncthreads();

    bfrag_t a[4], bb[4];
#pragma unroll
    for (int mi = 0; mi < 4; ++mi)
      a[mi] = *(const bfrag_t*)&as_[(wm + mi * 16 + l15) * ASTR + quad * 8];
#pragma unroll
    for (int ni = 0; ni < 4; ++ni) {
      const int n = wn + ni * 16 + l15;
      bb[ni] = *(const bfrag_t*)&Wk[(size_t)n * NF + k0 + quad * 8];
    }
#pragma unroll
    for (int mi = 0; mi < 4; ++mi)
#pragma unroll
      for (int ni = 0; ni < 4; ++ni)
        acc[mi][ni] = __builtin_amdgcn_mfma_f32_16x16x32_bf16(
            a[mi], bb[ni], acc[mi][ni], 0, 0, 0);
  }

  // ---- epilogue: two 64-row halves through cs[64][CPAD] ----
#pragma unroll
  for (int half = 0; half < 2; ++half) {
    __syncthreads();
    if ((wave >> 1) == half) {
#pragma unroll
      for (int ni = 0; ni < 4; ++ni) {
        const int nl = wn + ni * 16 + l15;
        const float bias = bk[nl];
#pragma unroll
        for (int mi = 0; mi < 4; ++mi) {
#pragma unroll
          for (int r = 0; r < 4; ++r) {
            const int ml = mi * 16 + quad * 4 + r;   // 0..63 within half
            cs[ml * CPAD + nl] = f2bf(acc[mi][ni][r] + bias);
          }
        }
      }
    }
    __syncthreads();
    const int chunk = t & 15;          // 16B chunk within a 256B row
    const int rowb  = t >> 4;          // 16 rows per iteration
#pragma unroll
    for (int it = 0; it < 4; ++it) {
      const int row = it * 16 + rowb;
      const int m   = m0 + half * 64 + row;
      const uint4 v = *(const uint4*)&cs[row * CPAD + chunk * 8];
      if (m < NNODES) *(uint4*)&hb[(size_t)m * NH + chunk * 8] = v;
    }
  }
}

// ---------------------------------------------------------------------------
// Bin pass: rank 4096 edges per block into 196 row-buckets via LDS hist;
// ONE global atomicAdd per (block,bucket) reserves space; edges written in
// ~21-entry contiguous runs into bucket-partitioned staging (aliases dead
// xb). pack: val(hi32) | rowlo<<16 | col. grid (196, NHOPS).
// ---------------------------------------------------------------------------
__global__ __launch_bounds__(256) void bin_kernel(
    const int* __restrict__ erows, const int* __restrict__ ecols,
    const float* __restrict__ evals, int* __restrict__ bucketCur,
    unsigned long long* __restrict__ staging) {
  const int hop = blockIdx.y;
  const int t   = threadIdx.x;
  const int bb  = blockIdx.x * EPB;
  __shared__ int lhist[NB];
  __shared__ int gbase[NB];
  for (int i = t; i < NB; i += 256) lhist[i] = 0;
  __syncthreads();

  unsigned long long pk[16];
  int bkt[16], rnk[16];
  const size_t g0 = (size_t)hop * NEDGES;
#pragma unroll
  for (int k = 0; k < 4; ++k) {
    const int e0 = bb + t * 4 + k * 1024;
    if (e0 + 3 < NEDGES) {
      const int4   rr = *(const int4*)&erows[g0 + e0];
      const int4   cc = *(const int4*)&ecols[g0 + e0];
      const float4 vv = *(const float4*)&evals[g0 + e0];
      const int r4[4] = {rr.x, rr.y, rr.z, rr.w};
      const int c4[4] = {cc.x, cc.y, cc.z, cc.w};
      const float v4[4] = {vv.x, vv.y, vv.z, vv.w};
#pragma unroll
      for (int j = 0; j < 4; ++j) {
        const int b = r4[j] >> 8;
        bkt[k * 4 + j] = b;
        rnk[k * 4 + j] = atomicAdd(&lhist[b], 1);
        pk[k * 4 + j] =
            ((unsigned long long)__float_as_uint(v4[j]) << 32) |
            ((unsigned)(r4[j] & 255) << 16) | (unsigned)c4[j];
      }
    } else {
#pragma unroll
      for (int j = 0; j < 4; ++j) {
        const int e = e0 + j;
        if (e < NEDGES) {
          const int r = erows[g0 + e];
          const int b = r >> 8;
          bkt[k * 4 + j] = b;
          rnk[k * 4 + j] = atomicAdd(&lhist[b], 1);
          pk[k * 4 + j] =
              ((unsigned long long)__float_as_uint(evals[g0 + e]) << 32) |
              ((unsigned)(r & 255) << 16) | (unsigned)ecols[g0 + e];
        } else {
          bkt[k * 4 + j] = -1;
        }
      }
    }
  }
  __syncthreads();
  for (int i = t; i < NB; i += 256) {
    const int c = lhist[i];
    gbase[i] = c ? atomicAdd(&bucketCur[hop * NB + i], c) : 0;
  }
  __syncthreads();
  unsigned long long* dst = staging + (size_t)hop * NEDGES;
#pragma unroll
  for (int q = 0; q < 16; ++q)
    if (bkt[q] >= 0) dst[gbase[bkt[q]] + rnk[q]] = pk[q];
}

// ---------------------------------------------------------------------------
// Per-row counts from staged edges: one block per (bucket,hop), LDS 256-bin
// histogram of rowlo, coalesced write to counts.
// ---------------------------------------------------------------------------
__global__ __launch_bounds__(256) void countscan_kernel(
    const int* __restrict__ bucketBase,
    const unsigned long long* __restrict__ staging, int* __restrict__ counts) {
  const int hop = blockIdx.y;
  const int b   = blockIdx.x;
  const int t   = threadIdx.x;
  const int s = bucketBase[hop * (NB + 1) + b];
  const int e = bucketBase[hop * (NB + 1) + b + 1];
  __shared__ int h[256];
  h[t] = 0;
  __syncthreads();
  const unsigned long long* src = staging + (size_t)hop * NEDGES;
  for (int i = s + t; i < e; i += 256) {
    const int rl = ((unsigned)src[i] >> 16) & 255;
    atomicAdd(&h[rl], 1);
  }
  __syncthreads();
  const int r0 = b * 256;
  if (r0 + t < NNODES) counts[hop * NNODES + r0 + t] = h[t];
}

// ---------------------------------------------------------------------------
// CSR build: exclusive scan per hop over per-row counts.
// ---------------------------------------------------------------------------
__global__ __launch_bounds__(1024) void scan_kernel(
    const int* __restrict__ counts, int* __restrict__ offs) {
  const int hop  = blockIdx.x;
  const int t    = threadIdx.x;
  const int lane = t & 63;
  const int wid  = t >> 6;
  __shared__ int wsum[16];
  __shared__ int carry_s;
  if (t == 0) carry_s = 0;
  __syncthreads();
  const int CH  = 8192;
  const int nch = (NNODES + CH - 1) / CH;     // 7
  for (int ch = 0; ch < nch; ++ch) {
    const int i0 = ch * CH + t * 8;
    int v[8];
    if (i0 + 7 < NNODES) {
      int4 a = *(const int4*)&counts[hop * NNODES + i0];
      int4 b = *(const int4*)&counts[hop * NNODES + i0 + 4];
      v[0]=a.x; v[1]=a.y; v[2]=a.z; v[3]=a.w;
      v[4]=b.x; v[5]=b.y; v[6]=b.z; v[7]=b.w;
    } else {
#pragma unroll
      for (int j = 0; j < 8; ++j)
        v[j] = (i0 + j < NNODES) ? counts[hop * NNODES + i0 + j] : 0;
    }
    int l[8];
    int run = 0;
#pragma unroll
    for (int j = 0; j < 8; ++j) { run += v[j]; l[j] = run; }   // inclusive
    int s = run;
#pragma unroll
    for (int d = 1; d < 64; d <<= 1) {
      int n = __shfl_up(s, d, 64);
      if (lane >= d) s += n;
    }
    if (lane == 63) wsum[wid] = s;
    __syncthreads();
    if (t < 16) {
      int ws = wsum[t];
#pragma unroll
      for (int d = 1; d < 16; d <<= 1) {
        int n = __shfl_up(ws, d, 16);
        if (t >= d) ws += n;
      }
      wsum[t] = ws;
    }
    __syncthreads();
    const int base = carry_s + (wid ? wsum[wid - 1] : 0) + (s - run);
    if (i0 + 7 < NNODES) {
      int4 o0 = make_int4(base, base + l[0], base + l[1], base + l[2]);
      int4 o1 = make_int4(base + l[3], base + l[4], base + l[5], base + l[6]);
      *(int4*)&offs[hop * (NNODES + 1) + i0]     = o0;
      *(int4*)&offs[hop * (NNODES + 1) + i0 + 4] = o1;
    } else {
#pragma unroll
      for (int j = 0; j < 8; ++j) {
        if (i0 + j < NNODES) {
          const int excl = base + (l[j] - v[j]);
          offs[hop * (NNODES + 1) + i0 + j] = excl;
        }
      }
    }
    __syncthreads();
    if (t == 0) carry_s += wsum[15];
    __syncthreads();
  }
  if (t == 0) offs[hop * (NNODES + 1) + NNODES] = carry_s;
}

// ---------------------------------------------------------------------------
// Place pass: one block per (bucket,hop). Sequential read of the bucket's
// staging segment; exact CSR position via LDS row cursors.
// R17: output pack stores col<<8 (byte offset into hb, col*NH*2 <= 12.8M
// fits 32b) so gather needs no per-load multiply/64-bit address chain.
// ---------------------------------------------------------------------------
__global__ __launch_bounds__(256) void place_kernel(
    const int* __restrict__ offs, const unsigned long long* __restrict__ staging,
    unsigned long long* __restrict__ ecsr) {
  const int hop = blockIdx.y;
  const int bk  = blockIdx.x;
  const int t   = threadIdx.x;
  const int r0  = bk * 256;
  const int nr  = (NNODES - r0 < 256) ? (NNODES - r0) : 256;
  const int* o = offs + (size_t)hop * (NNODES + 1);
  __shared__ int cur[257];
  for (int i = t; i <= nr; i += 256) cur[i] = o[r0 + i];
  __syncthreads();
  const int s = cur[0];
  const int e = cur[nr];          // never touched by atomics (rowlo < nr)
  __syncthreads();                // snapshot s,e before any cursor bumps
  const unsigned long long* src = staging + (size_t)hop * NEDGES;
  unsigned long long* dst       = ecsr + (size_t)hop * NEDGES;
  for (int i = s + t; i < e; i += 256) {
    const unsigned long long v = src[i];
    const unsigned lo = (unsigned)v;
    const int rl = (lo >> 16) & 255;
    const int d = atomicAdd(&cur[rl], 1);
    dst[d] = (v & 0xFFFFFFFF00000000ull) |
             ((unsigned long long)(lo & 0xFFFFu) << 8);   // R17: col*256
  }
}

// ---------------------------------------------------------------------------
// Paired gather SpMM: TWO hops per dispatch (blockIdx.y picks hop).
// R17: (a) ecsr.x is now a prescaled BYTE offset (col*256) -> hv address is
// one 32-bit add off the hb base (no per-load mul / 64-bit chain);
// (b) ed-prefetch software pipeline: next iteration's ecsr entries load
// during current FMA, breaking the serial ecsr->hv->FMA chain.
// ---------------------------------------------------------------------------
__global__ __launch_bounds__(256) void gather2_kernel(
    const int* __restrict__ offs, const int2* __restrict__ ecsr,
    const unsigned short* __restrict__ slots,
    unsigned short* __restrict__ aggA, unsigned short* __restrict__ aggB,
    int hop0) {
  const int y    = blockIdx.y;
  const int hop  = hop0 + y;
  const int* off = offs + (size_t)hop * (NNODES + 1);
  const int2* ec = ecsr + (size_t)hop * NEDGES;
  const char* hbB = (const char*)(slots + (size_t)(hop + 1) * NNODES * NH);
  unsigned short* aggb = y ? aggB : aggA;

  const int t    = threadIdx.x;
  const int lane = t & 63;
  const int wid  = t >> 6;
  const int r = blockIdx.x * 4 + wid;
  const int g  = lane >> 4;    // edge subgroup 0..3
  const int sl = lane & 15;    // feature slice: feats sl*8 .. sl*8+7
  const int slb = sl * 16;     // byte offset of slice within a 256B row
  const int s = off[r];
  const int e = off[r + 1];

  float acc[8];
#pragma unroll
  for (int j = 0; j < 8; ++j) acc[j] = 0.f;

  // prefetch first edge block
  int2 ed[4];
#pragma unroll
  for (int q = 0; q < 4; ++q) {
    const int idx = s + q * 4 + g;
    ed[q] = (idx < e) ? ec[idx] : make_int2(0, 0);
  }

  for (int p = s; p < e; p += 16) {
    int2 edc[4];
#pragma unroll
    for (int q = 0; q < 4; ++q) edc[q] = ed[q];
    const int pn = p + 16;
    if (pn < e) {
#pragma unroll
      for (int q = 0; q < 4; ++q) {
        const int idx = pn + q * 4 + g;
        ed[q] = (idx < e) ? ec[idx] : make_int2(0, 0);
      }
    }
    uint4 hv[4];
#pragma unroll
    for (int q = 0; q < 4; ++q)
      hv[q] = *(const uint4*)(hbB + (unsigned)(edc[q].x + slb));
#pragma unroll
    for (int q = 0; q < 4; ++q) {
      const float v = __int_as_float(edc[q].y);
      acc[0] += v * bf2f_lo(hv[q].x);
      acc[1] += v * bf2f_hi(hv[q].x);
      acc[2] += v * bf2f_lo(hv[q].y);
      acc[3] += v * bf2f_hi(hv[q].y);
      acc[4] += v * bf2f_lo(hv[q].z);
      acc[5] += v * bf2f_hi(hv[q].z);
      acc[6] += v * bf2f_lo(hv[q].w);
      acc[7] += v * bf2f_hi(hv[q].w);
    }
  }

#pragma unroll
  for (int j = 0; j < 8; ++j) {
    acc[j] += __shfl_xor(acc[j], 16, 64);
    acc[j] += __shfl_xor(acc[j], 32, 64);
  }

  if (g == 0) {
    uint4 o;
    o.x = (unsigned)f2bf(acc[0]) | ((unsigned)f2bf(acc[1]) << 16);
    o.y = (unsigned)f2bf(acc[2]) | ((unsigned)f2bf(acc[3]) << 16);
    o.z = (unsigned)f2bf(acc[4]) | ((unsigned)f2bf(acc[5]) << 16);
    o.w = (unsigned)f2bf(acc[6]) | ((unsigned)f2bf(acc[7]) << 16);
    *(uint4*)&aggb[(size_t)r * NH + sl * 8] = o;
  }
}

// ---------------------------------------------------------------------------
// Output GEMM via MFMA: out[50000,64] = elu(concat) @ Wout + bout.
// 782 blocks x 4 waves, each wave 16 rows x 64 cols, K=512 in 16 steps.
// ---------------------------------------------------------------------------
__global__ __launch_bounds__(256) void out2_kernel(
    const unsigned short* __restrict__ agg0, const unsigned short* __restrict__ agg1,
    const unsigned short* __restrict__ agg2, const unsigned short* __restrict__ agg3,
    const unsigned short* __restrict__ wot,    // [64][512] bf16 Wout^T
    const float* __restrict__ bout, float* __restrict__ out) {
  const int t    = threadIdx.x;
  const int lane = t & 63;
  const int wave = t >> 6;
  const int l15  = lane & 15;
  const int quad = lane >> 4;
  const int m0   = blockIdx.x * 64 + wave * 16;   // 16 rows per wave

  facc_t acc[4];
#pragma unroll
  for (int ni = 0; ni < 4; ++ni) { facc_t z = {0.f,0.f,0.f,0.f}; acc[ni] = z; }

  const int mrow  = m0 + l15;
  const int mload = mrow < NNODES ? mrow : NNODES - 1;  // clamp; masked at store

#pragma unroll
  for (int ks = 0; ks < 16; ++ks) {
    const int f0  = ks * 32 + quad * 8;            // feature index 0..511
    const int hop = f0 >> 7;
    const int j0  = f0 & 127;
    const unsigned short* ab =
        (hop == 0) ? agg0 : (hop == 1) ? agg1 : (hop == 2) ? agg2 : agg3;
    uint4 ua = *(const uint4*)&ab[(size_t)mload * NH + j0];
    const unsigned uu[4] = {ua.x, ua.y, ua.z, ua.w};
    unsigned pr[4];
#pragma unroll
    for (int q = 0; q < 4; ++q) {
      float lo = bf2f_lo(uu[q]);
      float hi = bf2f_hi(uu[q]);
      lo = lo > 0.f ? lo : (expf(lo) - 1.f);
      hi = hi > 0.f ? hi : (expf(hi) - 1.f);
      pr[q] = (unsigned)f2bf(lo) | ((unsigned)f2bf(hi) << 16);
    }
    uint4 ra; ra.x = pr[0]; ra.y = pr[1]; ra.z = pr[2]; ra.w = pr[3];
    bfrag_t af = *(bfrag_t*)&ra;
    bfrag_t bf[4];
#pragma unroll
    for (int ni = 0; ni < 4; ++ni) {
      const int n = ni * 16 + l15;
      bf[ni] = *(const bfrag_t*)&wot[(size_t)n * 512 + f0];
    }
#pragma unroll
    for (int ni = 0; ni < 4; ++ni)
      acc[ni] = __builtin_amdgcn_mfma_f32_16x16x32_bf16(af, bf[ni], acc[ni], 0, 0, 0);
  }

#pragma unroll
  for (int ni = 0; ni < 4; ++ni) {
    const int o = ni * 16 + l15;
    const float bo = bout[o];
#pragma unroll
    for (int r = 0; r < 4; ++r) {
      const int m = m0 + quad * 4 + r;
      if (m < NNODES) out[(size_t)m * NO + o] = acc[ni][r] + bo;
    }
  }
}

// ---------------------------------------------------------------------------
extern "C" void kernel_launch(void* const* d_in, const int* in_sizes, int n_in,
                              void* d_out, int out_size, void* d_ws, size_t ws_size,
                              hipStream_t stream) {
  const float* x     = (const float*)d_in[0];
  const float* W     = (const float*)d_in[1];
  const float* b     = (const float*)d_in[2];
  const float* W_out = (const float*)d_in[3];
  const float* b_out = (const float*)d_in[4];
  const int*   erows = (const int*)d_in[5];
  const int*   ecols = (const int*)d_in[6];
  const float* evals = (const float*)d_in[7];
  float* out = (float*)d_out;

  // ws layout (bytes), total ~117e6 (<128e6 known-safe):
  //   slots: 5 x NNODES*NH bf16 = 64.0e6
  //   xb: NPAD*NF bf16 = 25.7e6 (REUSED: bin staging; then agg1/agg3 bufs)
  //   Wt: 0.26e6 | ecsr: 25.6e6 | ints 1.6e6 | wot: 65.5e3
  unsigned short* slots = (unsigned short*)d_ws;
  unsigned short* xb = slots + (size_t)(NHOPS + 1) * NNODES * NH;
  unsigned short* Wt = xb + (size_t)NPAD * NF;
  unsigned long long* ecsr = (unsigned long long*)(Wt + (size_t)NHOPS * NH * NF);
  int* counts     = (int*)(ecsr + (size_t)NHOPS * NEDGES);
  int* offs       = counts + NHOPS * NNODES;
  int* bucketCur  = offs + NHOPS * (NNODES + 1);
  int* bucketBase = bucketCur + NHOPS * NB;
  unsigned short* wot = (unsigned short*)(bucketBase + NHOPS * (NB + 1));
  // staging aliases xb: xb dead after linear; staging dead after place.
  unsigned long long* staging = (unsigned long long*)xb;
  unsigned short* agg1buf = xb;                              // 12.8 MB
  unsigned short* agg3buf = xb + (size_t)NNODES * NH;        // 12.8 MB (fits 25.7)

  // bucketCur doubles as bucket-total accumulator for phaseA's hist1.
  hipMemsetAsync(bucketCur, 0, (size_t)NHOPS * NB * sizeof(int), stream);

  phaseA_kernel<<<CONVX_BLOCKS + CONVW_BLOCKS + HIST1_BLOCKS + WOT_BLOCKS,
                  256, 0, stream>>>(x, xb, W, Wt, erows, bucketCur, W_out, wot);
  scanB_kernel<<<NHOPS, 256, 0, stream>>>(bucketCur, bucketBase);
  linear_kernel<<<LIN_BLOCKS, 256, 0, stream>>>(xb, Wt, b, slots);
  bin_kernel<<<dim3(NB, NHOPS), 256, 0, stream>>>(
      erows, ecols, evals, bucketCur, staging);
  countscan_kernel<<<dim3(NB, NHOPS), 256, 0, stream>>>(
      bucketBase, staging, counts);
  scan_kernel<<<NHOPS, 1024, 0, stream>>>(counts, offs);
  place_kernel<<<dim3(NB, NHOPS), 256, 0, stream>>>(offs, staging, ecsr);

  // Pair A: g0 (R slot1, W slot0) || g1 (R slot2, W agg1buf) — disjoint.
  gather2_kernel<<<dim3(NNODES / 4, 2), 256, 0, stream>>>(
      offs, (const int2*)ecsr, slots, slots /*agg0 = slot0*/, agg1buf, 0);
  // Pair B: g2 (R slot3, W slot2) || g3 (R slot4, W agg3buf) — disjoint.
  // g2's write of slot2 is ordered after pair A's g1 read by the dispatch.
  gather2_kernel<<<dim3(NNODES / 4, 2), 256, 0, stream>>>(
      offs, (const int2*)ecsr, slots, slots + (size_t)2 * NNODES * NH, agg3buf, 2);

  out2_kernel<<<782, 256, 0, stream>>>(
      slots, agg1buf, slots + (size_t)2 * NNODES * NH, agg3buf,
      wot, b_out, out);
}

// Round 22
// 413.674 us; speedup vs baseline: 2.1569x; 1.0256x over previous
//
#include <hip/hip_runtime.h>
#include <hip/hip_bf16.h>
#include <math.h>

#define NNODES 50000
#define NPAD   50176              // 392*128, padded rows for MFMA tile overrun
#define NEDGES 800000
#define NHOPS  4
#define NF     256
#define NH     128
#define NO     64
#define NB     196                // row buckets of 256 rows (50000/256 -> 196)
#define EPB    4096               // edges per bin block (256 thr x 16)

#define CONVX_BLOCKS 12500        // NNODES*NF/4/256
#define CONVW_BLOCKS 512          // NHOPS*NH*NF/256
#define HIST1_BLOCKS (NB * NHOPS) // 784: bucket-level LDS hist (R7)
#define WOT_BLOCKS   128          // 64*512/256 (Wout^T -> bf16)
#define LIN_PER_HOP  391          // ceil(NNODES/128)
#define LIN_BLOCKS   1568         // 49 groups x 32 (R13 XCD-swizzled mapping)
#define ASTR 40                   // A-stage LDS row stride (ushorts)
#define CPAD 132                  // epilogue LDS row stride (ushorts)

typedef __attribute__((ext_vector_type(8))) short bfrag_t;   // 8 x bf16
typedef __attribute__((ext_vector_type(4))) float facc_t;    // 4 x f32

static __device__ __forceinline__ unsigned short f2bf(float f) {
  unsigned int u = __float_as_uint(f);
  unsigned int r = (u + 0x7fffu + ((u >> 16) & 1u)) >> 16;
  return (unsigned short)r;
}
static __device__ __forceinline__ float bf2f_lo(unsigned int u) {
  return __uint_as_float(u << 16);
}
static __device__ __forceinline__ float bf2f_hi(unsigned int u) {
  return __uint_as_float(u & 0xffff0000u);
}

// ---------------------------------------------------------------------------
// Phase A (fused): convx | convw | hist1 | wot. All independent.
// ---------------------------------------------------------------------------
__global__ __launch_bounds__(256) void phaseA_kernel(
    const float* __restrict__ x, unsigned short* __restrict__ xb,
    const float* __restrict__ W, unsigned short* __restrict__ Wt,
    const int* __restrict__ erows, int* __restrict__ bucketCur,
    const float* __restrict__ Wout, unsigned short* __restrict__ wot) {
  const int bx = blockIdx.x;
  const int t  = threadIdx.x;
  if (bx < CONVX_BLOCKS) {
    const size_t i = ((size_t)bx * 256 + t) * 4;
    float4 v = *(const float4*)&x[i];
    ushort4 o;
    o.x = f2bf(v.x); o.y = f2bf(v.y); o.z = f2bf(v.z); o.w = f2bf(v.w);
    *(ushort4*)&xb[i] = o;
  } else if (bx < CONVX_BLOCKS + CONVW_BLOCKS) {
    const int i = (bx - CONVX_BLOCKS) * 256 + t;
    const int k = i / (NH * NF);
    const int rem = i - k * NH * NF;
    const int n = rem / NF;
    const int f = rem - n * NF;
    Wt[i] = f2bf(W[(size_t)k * NF * NH + (size_t)f * NH + n]);
  } else if (bx < CONVX_BLOCKS + CONVW_BLOCKS + HIST1_BLOCKS) {
    const int id  = bx - (CONVX_BLOCKS + CONVW_BLOCKS);
    const int hop = id / NB;
    const int bb  = (id - hop * NB) * EPB;
    __shared__ int bh[NB];
    for (int i = t; i < NB; i += 256) bh[i] = 0;
    __syncthreads();
    const size_t g0 = (size_t)hop * NEDGES;
#pragma unroll
    for (int k = 0; k < 4; ++k) {
      const int e0 = bb + t * 4 + k * 1024;
      if (e0 + 3 < NEDGES) {
        const int4 rr = *(const int4*)&erows[g0 + e0];
        atomicAdd(&bh[rr.x >> 8], 1);
        atomicAdd(&bh[rr.y >> 8], 1);
        atomicAdd(&bh[rr.z >> 8], 1);
        atomicAdd(&bh[rr.w >> 8], 1);
      } else {
        for (int j = 0; j < 4; ++j)
          if (e0 + j < NEDGES) atomicAdd(&bh[erows[g0 + e0 + j] >> 8], 1);
      }
    }
    __syncthreads();
    for (int i = t; i < NB; i += 256)
      if (bh[i]) atomicAdd(&bucketCur[hop * NB + i], bh[i]);
  } else {
    // Wout^T -> bf16: wot[o][f] = bf16(Wout[f][o]); reads coalesced.
    const int i = (bx - (CONVX_BLOCKS + CONVW_BLOCKS + HIST1_BLOCKS)) * 256 + t;
    const int o = i & 63;
    const int f = i >> 6;
    wot[(size_t)o * 512 + f] = f2bf(Wout[(size_t)f * NO + o]);
  }
}

// ---------------------------------------------------------------------------
// Per-hop exclusive scan of 196 bucket totals. bucketCur -> bases (bin's
// allocator); bucketBase immutable (countscan). bucketBase[b] == offs[b*256].
// ---------------------------------------------------------------------------
__global__ __launch_bounds__(256) void scanB_kernel(
    int* __restrict__ bucketCur, int* __restrict__ bucketBase) {
  const int hop = blockIdx.x;
  const int t   = threadIdx.x;
  __shared__ int tot[NB];
  for (int i = t; i < NB; i += 256) tot[i] = bucketCur[hop * NB + i];
  __syncthreads();
  if (t == 0) {
    int run = 0;
    for (int i = 0; i < NB; ++i) { const int c = tot[i]; tot[i] = run; run += c; }
  }
  __syncthreads();
  for (int i = t; i < NB; i += 256) {
    bucketCur[hop * NB + i]        = tot[i];
    bucketBase[hop * (NB + 1) + i] = tot[i];
  }
  if (t == 0) bucketBase[hop * (NB + 1) + NB] = NEDGES;
}

// ---------------------------------------------------------------------------
// Linear via MFMA, all 4 hops in one dispatch. R13 body: A-tile LDS staging
// + union epilogue + XCD swizzle (FETCH 14MB, 56us measured).
// ---------------------------------------------------------------------------
__global__ __launch_bounds__(256) void linear_kernel(
    const unsigned short* __restrict__ xb, const unsigned short* __restrict__ Wt,
    const float* __restrict__ b, unsigned short* __restrict__ slots) {
  const int lb  = blockIdx.x;
  const int g   = lb >> 5;
  const int rr_ = lb & 31;
  const int hop = rr_ >> 3;
  const int xx  = rr_ & 7;
  const int mb  = g * 8 + xx;
  if (mb >= LIN_PER_HOP) return;
  const unsigned short* Wk = Wt + (size_t)hop * NH * NF;
  const float* bk = b + hop * NH;
  unsigned short* hb = slots + (size_t)(hop + 1) * NNODES * NH;

  const int t    = threadIdx.x;
  const int lane = t & 63;
  const int wave = t >> 6;
  const int wm   = (wave >> 1) * 64;
  const int wn   = (wave & 1) * 64;
  const int m0   = mb * 128;
  const int l15  = lane & 15;
  const int quad = lane >> 4;

  // union: as_[128][ASTR] during k-loop / cs[64][CPAD] epilogue
  __shared__ unsigned short smem[10240];
  unsigned short* as_ = smem;
  unsigned short* cs  = smem;

  facc_t acc[4][4];
#pragma unroll
  for (int i = 0; i < 4; ++i)
#pragma unroll
    for (int j = 0; j < 4; ++j) {
      facc_t z = {0.f, 0.f, 0.f, 0.f};
      acc[i][j] = z;
    }

#pragma unroll
  for (int k0 = 0; k0 < NF; k0 += 32) {
    __syncthreads();   // previous iteration's as_ reads complete
    // stage A: 128 rows x 32 cols (64B/row); thread t: row t>>2, 16B chunk t&3
#pragma unroll
    for (int it = 0; it < 2; ++it) {
      const int row = it * 64 + (t >> 2);
      const int ch  = t & 3;
      const uint4 v = *(const uint4*)&xb[(size_t)(m0 + row) * NF + k0 + ch * 8];
      *(uint4*)&as_[row * ASTR + ch * 8] = v;
    }
    __syncthreads();

    bfrag_t a[4], bb[4];
#pragma unroll
    for (int mi = 0; mi < 4; ++mi)
      a[mi] = *(const bfrag_t*)&as_[(wm + mi * 16 + l15) * ASTR + quad * 8];
#pragma unroll
    for (int ni = 0; ni < 4; ++ni) {
      const int n = wn + ni * 16 + l15;
      bb[ni] = *(const bfrag_t*)&Wk[(size_t)n * NF + k0 + quad * 8];
    }
#pragma unroll
    for (int mi = 0; mi < 4; ++mi)
#pragma unroll
      for (int ni = 0; ni < 4; ++ni)
        acc[mi][ni] = __builtin_amdgcn_mfma_f32_16x16x32_bf16(
            a[mi], bb[ni], acc[mi][ni], 0, 0, 0);
  }

  // ---- epilogue: two 64-row halves through cs[64][CPAD] ----
#pragma unroll
  for (int half = 0; half < 2; ++half) {
    __syncthreads();
    if ((wave >> 1) == half) {
#pragma unroll
      for (int ni = 0; ni < 4; ++ni) {
        const int nl = wn + ni * 16 + l15;
        const float bias = bk[nl];
#pragma unroll
        for (int mi = 0; mi < 4; ++mi) {
#pragma unroll
          for (int r = 0; r < 4; ++r) {
            const int ml = mi * 16 + quad * 4 + r;   // 0..63 within half
            cs[ml * CPAD + nl] = f2bf(acc[mi][ni][r] + bias);
          }
        }
      }
    }
    __syncthreads();
    const int chunk = t & 15;          // 16B chunk within a 256B row
    const int rowb  = t >> 4;          // 16 rows per iteration
#pragma unroll
    for (int it = 0; it < 4; ++it) {
      const int row = it * 16 + rowb;
      const int m   = m0 + half * 64 + row;
      const uint4 v = *(const uint4*)&cs[row * CPAD + chunk * 8];
      if (m < NNODES) *(uint4*)&hb[(size_t)m * NH + chunk * 8] = v;
    }
  }
}

// ---------------------------------------------------------------------------
// Bin pass: rank 4096 edges per block into 196 row-buckets via LDS hist;
// ONE global atomicAdd per (block,bucket) reserves space; edges written in
// ~21-entry contiguous runs into bucket-partitioned staging (aliases dead
// xb). pack: val(hi32) | rowlo<<16 | col. grid (196, NHOPS).
// ---------------------------------------------------------------------------
__global__ __launch_bounds__(256) void bin_kernel(
    const int* __restrict__ erows, const int* __restrict__ ecols,
    const float* __restrict__ evals, int* __restrict__ bucketCur,
    unsigned long long* __restrict__ staging) {
  const int hop = blockIdx.y;
  const int t   = threadIdx.x;
  const int bb  = blockIdx.x * EPB;
  __shared__ int lhist[NB];
  __shared__ int gbase[NB];
  for (int i = t; i < NB; i += 256) lhist[i] = 0;
  __syncthreads();

  unsigned long long pk[16];
  int bkt[16], rnk[16];
  const size_t g0 = (size_t)hop * NEDGES;
#pragma unroll
  for (int k = 0; k < 4; ++k) {
    const int e0 = bb + t * 4 + k * 1024;
    if (e0 + 3 < NEDGES) {
      const int4   rr = *(const int4*)&erows[g0 + e0];
      const int4   cc = *(const int4*)&ecols[g0 + e0];
      const float4 vv = *(const float4*)&evals[g0 + e0];
      const int r4[4] = {rr.x, rr.y, rr.z, rr.w};
      const int c4[4] = {cc.x, cc.y, cc.z, cc.w};
      const float v4[4] = {vv.x, vv.y, vv.z, vv.w};
#pragma unroll
      for (int j = 0; j < 4; ++j) {
        const int b = r4[j] >> 8;
        bkt[k * 4 + j] = b;
        rnk[k * 4 + j] = atomicAdd(&lhist[b], 1);
        pk[k * 4 + j] =
            ((unsigned long long)__float_as_uint(v4[j]) << 32) |
            ((unsigned)(r4[j] & 255) << 16) | (unsigned)c4[j];
      }
    } else {
#pragma unroll
      for (int j = 0; j < 4; ++j) {
        const int e = e0 + j;
        if (e < NEDGES) {
          const int r = erows[g0 + e];
          const int b = r >> 8;
          bkt[k * 4 + j] = b;
          rnk[k * 4 + j] = atomicAdd(&lhist[b], 1);
          pk[k * 4 + j] =
              ((unsigned long long)__float_as_uint(evals[g0 + e]) << 32) |
              ((unsigned)(r & 255) << 16) | (unsigned)ecols[g0 + e];
        } else {
          bkt[k * 4 + j] = -1;
        }
      }
    }
  }
  __syncthreads();
  for (int i = t; i < NB; i += 256) {
    const int c = lhist[i];
    gbase[i] = c ? atomicAdd(&bucketCur[hop * NB + i], c) : 0;
  }
  __syncthreads();
  unsigned long long* dst = staging + (size_t)hop * NEDGES;
#pragma unroll
  for (int q = 0; q < 16; ++q)
    if (bkt[q] >= 0) dst[gbase[bkt[q]] + rnk[q]] = pk[q];
}

// ---------------------------------------------------------------------------
// R21 — FUSED countscan+scan: one block per (bucket,hop). LDS 256-bin
// histogram of rowlo, then block-level exclusive scan + bucketBase[b]
// writes offs[r0..r0+255] DIRECTLY (offs[b*256] == bucketBase[b] by
// construction). scan_kernel dispatch eliminated; counts array unused.
// Block (NB-1) also writes offs[NNODES] = NEDGES.
// ---------------------------------------------------------------------------
__global__ __launch_bounds__(256) void countscan_kernel(
    const int* __restrict__ bucketBase,
    const unsigned long long* __restrict__ staging, int* __restrict__ offs) {
  const int hop = blockIdx.y;
  const int b   = blockIdx.x;
  const int t   = threadIdx.x;
  const int s = bucketBase[hop * (NB + 1) + b];
  const int e = bucketBase[hop * (NB + 1) + b + 1];
  __shared__ int h[256];
  __shared__ int wsum[4];
  h[t] = 0;
  __syncthreads();
  const unsigned long long* src = staging + (size_t)hop * NEDGES;
  for (int i = s + t; i < e; i += 256) {
    const int rl = ((unsigned)src[i] >> 16) & 255;
    atomicAdd(&h[rl], 1);
  }
  __syncthreads();
  // block exclusive scan of h[256]
  const int lane = t & 63;
  const int wid  = t >> 6;
  const int v = h[t];
  int sc = v;
#pragma unroll
  for (int d = 1; d < 64; d <<= 1) {
    int n = __shfl_up(sc, d, 64);
    if (lane >= d) sc += n;
  }
  if (lane == 63) wsum[wid] = sc;
  __syncthreads();
  int wadd = 0;
  for (int j = 0; j < wid; ++j) wadd += wsum[j];
  const int excl = s + wadd + (sc - v);
  const int r = b * 256 + t;
  if (r < NNODES) offs[hop * (NNODES + 1) + r] = excl;
  if (b == NB - 1 && t == 0) offs[hop * (NNODES + 1) + NNODES] = NEDGES;
}

// ---------------------------------------------------------------------------
// Place pass: one block per (bucket,hop). Sequential read of the bucket's
// staging segment; exact CSR position via LDS row cursors.
// R17: output pack stores col<<8 (byte offset into hb) so gather needs no
// per-load multiply/64-bit address chain.
// ---------------------------------------------------------------------------
__global__ __launch_bounds__(256) void place_kernel(
    const int* __restrict__ offs, const unsigned long long* __restrict__ staging,
    unsigned long long* __restrict__ ecsr) {
  const int hop = blockIdx.y;
  const int bk  = blockIdx.x;
  const int t   = threadIdx.x;
  const int r0  = bk * 256;
  const int nr  = (NNODES - r0 < 256) ? (NNODES - r0) : 256;
  const int* o = offs + (size_t)hop * (NNODES + 1);
  __shared__ int cur[257];
  for (int i = t; i <= nr; i += 256) cur[i] = o[r0 + i];
  __syncthreads();
  const int s = cur[0];
  const int e = cur[nr];          // never touched by atomics (rowlo < nr)
  __syncthreads();                // snapshot s,e before any cursor bumps
  const unsigned long long* src = staging + (size_t)hop * NEDGES;
  unsigned long long* dst       = ecsr + (size_t)hop * NEDGES;
  for (int i = s + t; i < e; i += 256) {
    const unsigned long long v = src[i];
    const unsigned lo = (unsigned)v;
    const int rl = (lo >> 16) & 255;
    const int d = atomicAdd(&cur[rl], 1);
    dst[d] = (v & 0xFFFFFFFF00000000ull) |
             ((unsigned long long)(lo & 0xFFFFu) << 8);   // col*256 bytes
  }
}

// ---------------------------------------------------------------------------
// Paired gather SpMM: TWO hops per dispatch (blockIdx.y picks hop).
// ecsr.x is a prescaled BYTE offset; ed-prefetch software pipeline.
// R21 note: measured plateau — FETCH 156MB at ~3.07 TB/s LLC path = 51us
// floor, running at 60.5us (84%), co-limited by unpack VALU (59%).
// ---------------------------------------------------------------------------
__global__ __launch_bounds__(256) void gather2_kernel(
    const int* __restrict__ offs, const int2* __restrict__ ecsr,
    const unsigned short* __restrict__ slots,
    unsigned short* __restrict__ aggA, unsigned short* __restrict__ aggB,
    int hop0) {
  const int y    = blockIdx.y;
  const int hop  = hop0 + y;
  const int* off = offs + (size_t)hop * (NNODES + 1);
  const int2* ec = ecsr + (size_t)hop * NEDGES;
  const char* hbB = (const char*)(slots + (size_t)(hop + 1) * NNODES * NH);
  unsigned short* aggb = y ? aggB : aggA;

  const int t    = threadIdx.x;
  const int lane = t & 63;
  const int wid  = t >> 6;
  const int r = blockIdx.x * 4 + wid;
  const int g  = lane >> 4;    // edge subgroup 0..3
  const int sl = lane & 15;    // feature slice: feats sl*8 .. sl*8+7
  const int slb = sl * 16;     // byte offset of slice within a 256B row
  const int s = off[r];
  const int e = off[r + 1];

  float acc[8];
#pragma unroll
  for (int j = 0; j < 8; ++j) acc[j] = 0.f;

  // prefetch first edge block
  int2 ed[4];
#pragma unroll
  for (int q = 0; q < 4; ++q) {
    const int idx = s + q * 4 + g;
    ed[q] = (idx < e) ? ec[idx] : make_int2(0, 0);
  }

  for (int p = s; p < e; p += 16) {
    int2 edc[4];
#pragma unroll
    for (int q = 0; q < 4; ++q) edc[q] = ed[q];
    const int pn = p + 16;
    if (pn < e) {
#pragma unroll
      for (int q = 0; q < 4; ++q) {
        const int idx = pn + q * 4 + g;
        ed[q] = (idx < e) ? ec[idx] : make_int2(0, 0);
      }
    }
    uint4 hv[4];
#pragma unroll
    for (int q = 0; q < 4; ++q)
      hv[q] = *(const uint4*)(hbB + (unsigned)(edc[q].x + slb));
#pragma unroll
    for (int q = 0; q < 4; ++q) {
      const float v = __int_as_float(edc[q].y);
      acc[0] += v * bf2f_lo(hv[q].x);
      acc[1] += v * bf2f_hi(hv[q].x);
      acc[2] += v * bf2f_lo(hv[q].y);
      acc[3] += v * bf2f_hi(hv[q].y);
      acc[4] += v * bf2f_lo(hv[q].z);
      acc[5] += v * bf2f_hi(hv[q].z);
      acc[6] += v * bf2f_lo(hv[q].w);
      acc[7] += v * bf2f_hi(hv[q].w);
    }
  }

#pragma unroll
  for (int j = 0; j < 8; ++j) {
    acc[j] += __shfl_xor(acc[j], 16, 64);
    acc[j] += __shfl_xor(acc[j], 32, 64);
  }

  if (g == 0) {
    uint4 o;
    o.x = (unsigned)f2bf(acc[0]) | ((unsigned)f2bf(acc[1]) << 16);
    o.y = (unsigned)f2bf(acc[2]) | ((unsigned)f2bf(acc[3]) << 16);
    o.z = (unsigned)f2bf(acc[4]) | ((unsigned)f2bf(acc[5]) << 16);
    o.w = (unsigned)f2bf(acc[6]) | ((unsigned)f2bf(acc[7]) << 16);
    *(uint4*)&aggb[(size_t)r * NH + sl * 8] = o;
  }
}

// ---------------------------------------------------------------------------
// Output GEMM via MFMA: out[50000,64] = elu(concat) @ Wout + bout.
// 782 blocks x 4 waves, each wave 16 rows x 64 cols, K=512 in 16 steps.
// ---------------------------------------------------------------------------
__global__ __launch_bounds__(256) void out2_kernel(
    const unsigned short* __restrict__ agg0, const unsigned short* __restrict__ agg1,
    const unsigned short* __restrict__ agg2, const unsigned short* __restrict__ agg3,
    const unsigned short* __restrict__ wot,    // [64][512] bf16 Wout^T
    const float* __restrict__ bout, float* __restrict__ out) {
  const int t    = threadIdx.x;
  const int lane = t & 63;
  const int wave = t >> 6;
  const int l15  = lane & 15;
  const int quad = lane >> 4;
  const int m0   = blockIdx.x * 64 + wave * 16;   // 16 rows per wave

  facc_t acc[4];
#pragma unroll
  for (int ni = 0; ni < 4; ++ni) { facc_t z = {0.f,0.f,0.f,0.f}; acc[ni] = z; }

  const int mrow  = m0 + l15;
  const int mload = mrow < NNODES ? mrow : NNODES - 1;  // clamp; masked at store

#pragma unroll
  for (int ks = 0; ks < 16; ++ks) {
    const int f0  = ks * 32 + quad * 8;            // feature index 0..511
    const int hop = f0 >> 7;
    const int j0  = f0 & 127;
    const unsigned short* ab =
        (hop == 0) ? agg0 : (hop == 1) ? agg1 : (hop == 2) ? agg2 : agg3;
    uint4 ua = *(const uint4*)&ab[(size_t)mload * NH + j0];
    const unsigned uu[4] = {ua.x, ua.y, ua.z, ua.w};
    unsigned pr[4];
#pragma unroll
    for (int q = 0; q < 4; ++q) {
      float lo = bf2f_lo(uu[q]);
      float hi = bf2f_hi(uu[q]);
      lo = lo > 0.f ? lo : (expf(lo) - 1.f);
      hi = hi > 0.f ? hi : (expf(hi) - 1.f);
      pr[q] = (unsigned)f2bf(lo) | ((unsigned)f2bf(hi) << 16);
    }
    uint4 ra; ra.x = pr[0]; ra.y = pr[1]; ra.z = pr[2]; ra.w = pr[3];
    bfrag_t af = *(bfrag_t*)&ra;
    bfrag_t bf[4];
#pragma unroll
    for (int ni = 0; ni < 4; ++ni) {
      const int n = ni * 16 + l15;
      bf[ni] = *(const bfrag_t*)&wot[(size_t)n * 512 + f0];
    }
#pragma unroll
    for (int ni = 0; ni < 4; ++ni)
      acc[ni] = __builtin_amdgcn_mfma_f32_16x16x32_bf16(af, bf[ni], acc[ni], 0, 0, 0);
  }

#pragma unroll
  for (int ni = 0; ni < 4; ++ni) {
    const int o = ni * 16 + l15;
    const float bo = bout[o];
#pragma unroll
    for (int r = 0; r < 4; ++r) {
      const int m = m0 + quad * 4 + r;
      if (m < NNODES) out[(size_t)m * NO + o] = acc[ni][r] + bo;
    }
  }
}

// ---------------------------------------------------------------------------
extern "C" void kernel_launch(void* const* d_in, const int* in_sizes, int n_in,
                              void* d_out, int out_size, void* d_ws, size_t ws_size,
                              hipStream_t stream) {
  const float* x     = (const float*)d_in[0];
  const float* W     = (const float*)d_in[1];
  const float* b     = (const float*)d_in[2];
  const float* W_out = (const float*)d_in[3];
  const float* b_out = (const float*)d_in[4];
  const int*   erows = (const int*)d_in[5];
  const int*   ecols = (const int*)d_in[6];
  const float* evals = (const float*)d_in[7];
  float* out = (float*)d_out;

  // ws layout (bytes), total ~117e6 (<128e6 known-safe):
  //   slots: 5 x NNODES*NH bf16 = 64.0e6
  //   xb: NPAD*NF bf16 = 25.7e6 (REUSED: bin staging; then agg1/agg3 bufs)
  //   Wt: 0.26e6 | ecsr: 25.6e6 | ints 1.6e6 (counts region now unused) | wot
  unsigned short* slots = (unsigned short*)d_ws;
  unsigned short* xb = slots + (size_t)(NHOPS + 1) * NNODES * NH;
  unsigned short* Wt = xb + (size_t)NPAD * NF;
  unsigned long long* ecsr = (unsigned long long*)(Wt + (size_t)NHOPS * NH * NF);
  int* counts     = (int*)(ecsr + (size_t)NHOPS * NEDGES);   // unused (R21)
  int* offs       = counts + NHOPS * NNODES;
  int* bucketCur  = offs + NHOPS * (NNODES + 1);
  int* bucketBase = bucketCur + NHOPS * NB;
  unsigned short* wot = (unsigned short*)(bucketBase + NHOPS * (NB + 1));
  // staging aliases xb: xb dead after linear; staging dead after place.
  unsigned long long* staging = (unsigned long long*)xb;
  unsigned short* agg1buf = xb;                              // 12.8 MB
  unsigned short* agg3buf = xb + (size_t)NNODES * NH;        // 12.8 MB (fits 25.7)

  // bucketCur doubles as bucket-total accumulator for phaseA's hist1.
  hipMemsetAsync(bucketCur, 0, (size_t)NHOPS * NB * sizeof(int), stream);

  phaseA_kernel<<<CONVX_BLOCKS + CONVW_BLOCKS + HIST1_BLOCKS + WOT_BLOCKS,
                  256, 0, stream>>>(x, xb, W, Wt, erows, bucketCur, W_out, wot);
  scanB_kernel<<<NHOPS, 256, 0, stream>>>(bucketCur, bucketBase);
  linear_kernel<<<LIN_BLOCKS, 256, 0, stream>>>(xb, Wt, b, slots);
  bin_kernel<<<dim3(NB, NHOPS), 256, 0, stream>>>(
      erows, ecols, evals, bucketCur, staging);
  countscan_kernel<<<dim3(NB, NHOPS), 256, 0, stream>>>(
      bucketBase, staging, offs);            // R21: writes offs directly
  place_kernel<<<dim3(NB, NHOPS), 256, 0, stream>>>(offs, staging, ecsr);

  // Pair A: g0 (R slot1, W slot0) || g1 (R slot2, W agg1buf) — disjoint.
  gather2_kernel<<<dim3(NNODES / 4, 2), 256, 0, stream>>>(
      offs, (const int2*)ecsr, slots, slots /*agg0 = slot0*/, agg1buf, 0);
  // Pair B: g2 (R slot3, W slot2) || g3 (R slot4, W agg3buf) — disjoint.
  // g2's write of slot2 is ordered after pair A's g1 read by the dispatch.
  gather2_kernel<<<dim3(NNODES / 4, 2), 256, 0, stream>>>(
      offs, (const int2*)ecsr, slots, slots + (size_t)2 * NNODES * NH, agg3buf, 2);

  out2_kernel<<<782, 256, 0, stream>>>(
      slots, agg1buf, slots + (size_t)2 * NNODES * NH, agg3buf,
      wot, b_out, out);
}